// Round 1
// baseline (1503.139 us; speedup 1.0000x reference)
//
#include <hip/hip_runtime.h>

// TemporalGAT on MI355X — round 0: correct f32 baseline.
// B=16, L=1024, F=128, H=4, D=64, HD=256, N=B*L=16384
// Outputs (flat, in order): out[B,L,D], gat_att[H,B,L,L], t_att[B,L,L], temporal_out[B,L,HD]

constexpr int Bc = 16, Lc = 1024, Fc = 128, Hc = 4, Dc = 64, HDc = 256;
constexpr int Nrows = Bc * Lc;  // 16384
#define ALPHA_SLOPE 0.2f

enum { EPI_NONE = 0, EPI_BIAS = 1, EPI_SCALE = 2, EPI_WH = 3, EPI_GAT = 4 };

__device__ __forceinline__ float lrelu(float x) { return x > 0.f ? x : ALPHA_SLOPE * x; }

// Generic 64x64 f32 tiled GEMM: C = op(A@B) ; A row-major [M,K], B row-major [K,Ncols]
// (or [Ncols,K] if TRANS_B). Batched via blockIdx.z with strides sA/sB/sC.
// EPI_WH additionally computes si/sj = Wh·a1 / Wh·a2 (fused row reductions).
// EPI_GAT writes C into the head-concat layout gat_out[b, l, h*64+d].
template <int BK, bool TRANS_B, int EPI>
__global__ __launch_bounds__(256) void gemm_k(
    const float* __restrict__ A, const float* __restrict__ Bm,
    const float* __restrict__ bias, float* __restrict__ C,
    int M, int Ncols, int K, int lda, int ldb, int ldc,
    long long sA, long long sB, long long sC, float alpha,
    const float* __restrict__ a1, const float* __restrict__ a2,
    float* __restrict__ si, float* __restrict__ sj)
{
    constexpr int BM = 64, BN = 64;
    __shared__ float As[BK][BM + 1];   // stored K-major (transposed on store)
    __shared__ float Bs[BK][BN + 1];
    const int z = blockIdx.z;
    A += (long long)z * sA;
    Bm += (long long)z * sB;
    if (EPI == EPI_GAT) {
        // z = h*16 + b ; C base = gat_out + b*L*HD + h*D
        C += (long long)(z & 15) * Lc * HDc + (long long)(z >> 4) * Dc;
    } else {
        C += (long long)z * sC;
    }
    const int row0 = blockIdx.x * BM;
    const int col0 = blockIdx.y * BN;
    const int t  = threadIdx.x;
    const int tr = t >> 4, tc = t & 15;
    const int r0 = tr * 4, c0 = tc * 4;

    float acc[4][4] = {};

    for (int k0 = 0; k0 < K; k0 += BK) {
        // A tile: BM x BK -> As[k][r]
        #pragma unroll
        for (int idx = t; idx < BM * BK / 4; idx += 256) {
            const int r  = idx / (BK / 4);
            const int kc = (idx % (BK / 4)) * 4;
            const float4 v = *(const float4*)(A + (long long)(row0 + r) * lda + k0 + kc);
            As[kc + 0][r] = v.x; As[kc + 1][r] = v.y;
            As[kc + 2][r] = v.z; As[kc + 3][r] = v.w;
        }
        if (!TRANS_B) {
            #pragma unroll
            for (int idx = t; idx < BK * BN / 4; idx += 256) {
                const int kk = idx / (BN / 4);
                const int cc = (idx % (BN / 4)) * 4;
                const float4 v = *(const float4*)(Bm + (long long)(k0 + kk) * ldb + col0 + cc);
                Bs[kk][cc + 0] = v.x; Bs[kk][cc + 1] = v.y;
                Bs[kk][cc + 2] = v.z; Bs[kk][cc + 3] = v.w;
            }
        } else {
            #pragma unroll
            for (int idx = t; idx < BN * BK / 4; idx += 256) {
                const int c  = idx / (BK / 4);
                const int kc = (idx % (BK / 4)) * 4;
                const float4 v = *(const float4*)(Bm + (long long)(col0 + c) * ldb + k0 + kc);
                Bs[kc + 0][c] = v.x; Bs[kc + 1][c] = v.y;
                Bs[kc + 2][c] = v.z; Bs[kc + 3][c] = v.w;
            }
        }
        __syncthreads();
        #pragma unroll
        for (int kk = 0; kk < BK; ++kk) {
            float a[4], b[4];
            #pragma unroll
            for (int i = 0; i < 4; ++i) a[i] = As[kk][r0 + i];
            #pragma unroll
            for (int j = 0; j < 4; ++j) b[j] = Bs[kk][c0 + j];
            #pragma unroll
            for (int i = 0; i < 4; ++i)
                #pragma unroll
                for (int j = 0; j < 4; ++j) acc[i][j] = fmaf(a[i], b[j], acc[i][j]);
        }
        __syncthreads();
    }

    float bv[4];
    if (EPI == EPI_BIAS) {
        #pragma unroll
        for (int j = 0; j < 4; ++j) bv[j] = bias[col0 + c0 + j];
    }
    #pragma unroll
    for (int i = 0; i < 4; ++i) {
        float4 o;
        float* po = (float*)&o;
        #pragma unroll
        for (int j = 0; j < 4; ++j) {
            float v = acc[i][j];
            if (EPI == EPI_SCALE) v *= alpha;
            if (EPI == EPI_BIAS)  v += bv[j];
            po[j] = v;
        }
        *(float4*)(C + (long long)(row0 + r0 + i) * ldc + col0 + c0) = o;
    }

    if (EPI == EPI_WH) {
        // head = z; Ncols==64, col0==0. si/sj layout: [H][N]
        float a1v[4], a2v[4];
        #pragma unroll
        for (int j = 0; j < 4; ++j) {
            a1v[j] = a1[z * Dc + c0 + j];
            a2v[j] = a2[z * Dc + c0 + j];
        }
        #pragma unroll
        for (int i = 0; i < 4; ++i) {
            float p1 = 0.f, p2 = 0.f;
            #pragma unroll
            for (int j = 0; j < 4; ++j) {
                p1 = fmaf(acc[i][j], a1v[j], p1);
                p2 = fmaf(acc[i][j], a2v[j], p2);
            }
            #pragma unroll
            for (int ofs = 1; ofs < 16; ofs <<= 1) {
                p1 += __shfl_xor(p1, ofs, 64);
                p2 += __shfl_xor(p2, ofs, 64);
            }
            if (tc == 0) {
                si[(long long)z * M + row0 + r0 + i] = p1;
                sj[(long long)z * M + row0 + r0 + i] = p2;
            }
        }
    }
}

// max over each 1024-row of sj -> sjmax[hb]
__global__ __launch_bounds__(256) void sjmax_k(const float* __restrict__ sj,
                                               float* __restrict__ out)
{
    __shared__ float red[4];
    const int hb = blockIdx.x;
    const int t  = threadIdx.x;
    const float4 v = ((const float4*)(sj + (long long)hb * Lc))[t];
    float m = fmaxf(fmaxf(v.x, v.y), fmaxf(v.z, v.w));
    #pragma unroll
    for (int ofs = 32; ofs >= 1; ofs >>= 1) m = fmaxf(m, __shfl_xor(m, ofs, 64));
    if ((t & 63) == 0) red[t >> 6] = m;
    __syncthreads();
    if (t == 0) out[hb] = fmaxf(fmaxf(red[0], red[1]), fmaxf(red[2], red[3]));
}

// GAT attention softmax. Row max is analytic: lrelu monotone => max_j lrelu(si+sj) =
// lrelu(si + max_j sj). Single pass per row: exp, block-reduce sum, scaled write.
__global__ __launch_bounds__(256) void gatt_k(const float* __restrict__ si,
                                              const float* __restrict__ sj,
                                              const float* __restrict__ sjmax,
                                              float* __restrict__ att)
{
    __shared__ __align__(16) float sjs[Lc];
    __shared__ float red[4];
    const int hb    = blockIdx.y;
    const int chunk = blockIdx.x;  // 16 rows per block
    const int t     = threadIdx.x;
    ((float4*)sjs)[t] = ((const float4*)(sj + (long long)hb * Lc))[t];
    const float smax = sjmax[hb];
    __syncthreads();
    const float* sip = si + (long long)hb * Lc + chunk * 16;
    float* attp = att + ((long long)hb * Lc + (long long)chunk * 16) * Lc;
    const float4 sv = ((const float4*)sjs)[t];
    for (int r = 0; r < 16; ++r) {
        const float siv = sip[r];
        const float m = lrelu(siv + smax);
        float4 p;
        p.x = __expf(lrelu(siv + sv.x) - m);
        p.y = __expf(lrelu(siv + sv.y) - m);
        p.z = __expf(lrelu(siv + sv.z) - m);
        p.w = __expf(lrelu(siv + sv.w) - m);
        float s = p.x + p.y + p.z + p.w;
        #pragma unroll
        for (int ofs = 32; ofs >= 1; ofs >>= 1) s += __shfl_xor(s, ofs, 64);
        if ((t & 63) == 0) red[t >> 6] = s;
        __syncthreads();
        const float tot = red[0] + red[1] + red[2] + red[3];
        const float inv = 1.0f / tot;
        float4 o = { p.x * inv, p.y * inv, p.z * inv, p.w * inv };
        ((float4*)(attp + (long long)r * Lc))[t] = o;
        __syncthreads();
    }
}

// temporal softmax, in place over scores already stored in the t_att output region
__global__ __launch_bounds__(256) void tsm_k(float* __restrict__ att)
{
    __shared__ float redm[4];
    __shared__ float reds[4];
    const int b     = blockIdx.y;
    const int chunk = blockIdx.x;  // 16 rows per block
    const int t     = threadIdx.x;
    float* base = att + ((long long)b * Lc + (long long)chunk * 16) * Lc;
    for (int r = 0; r < 16; ++r) {
        float4 v = ((float4*)(base + (long long)r * Lc))[t];
        float m = fmaxf(fmaxf(v.x, v.y), fmaxf(v.z, v.w));
        #pragma unroll
        for (int ofs = 32; ofs >= 1; ofs >>= 1) m = fmaxf(m, __shfl_xor(m, ofs, 64));
        if ((t & 63) == 0) redm[t >> 6] = m;
        __syncthreads();
        m = fmaxf(fmaxf(redm[0], redm[1]), fmaxf(redm[2], redm[3]));
        float4 p;
        p.x = __expf(v.x - m); p.y = __expf(v.y - m);
        p.z = __expf(v.z - m); p.w = __expf(v.w - m);
        float s = p.x + p.y + p.z + p.w;
        #pragma unroll
        for (int ofs = 32; ofs >= 1; ofs >>= 1) s += __shfl_xor(s, ofs, 64);
        if ((t & 63) == 0) reds[t >> 6] = s;
        __syncthreads();
        s = reds[0] + reds[1] + reds[2] + reds[3];
        const float inv = 1.0f / s;
        float4 o = { p.x * inv, p.y * inv, p.z * inv, p.w * inv };
        ((float4*)(base + (long long)r * Lc))[t] = o;
        __syncthreads();
    }
}

extern "C" void kernel_launch(void* const* d_in, const int* in_sizes, int n_in,
                              void* d_out, int out_size, void* d_ws, size_t ws_size,
                              hipStream_t stream)
{
    const float* x   = (const float*)d_in[0];
    const float* W   = (const float*)d_in[1];
    const float* a1  = (const float*)d_in[2];
    const float* a2  = (const float*)d_in[3];
    const float* Wq  = (const float*)d_in[4];
    const float* bq  = (const float*)d_in[5];
    const float* Wk  = (const float*)d_in[6];
    const float* bk  = (const float*)d_in[7];
    const float* Wv  = (const float*)d_in[8];
    const float* bv  = (const float*)d_in[9];
    const float* Wfc = (const float*)d_in[10];
    const float* bfc = (const float*)d_in[11];

    float* outp    = (float*)d_out;
    float* gat_att = outp + (long long)Bc * Lc * Dc;         // +1,048,576
    float* t_att   = gat_att + (long long)Hc * Bc * Lc * Lc; // +67,108,864
    float* t_out   = t_att + (long long)Bc * Lc * Lc;        // +16,777,216

    float* ws   = (float*)d_ws;
    float* Wh   = ws;                                   // H*N*D = 4,194,304 f32
    float* si   = Wh + (long long)Hc * Nrows * Dc;      // 65,536
    float* sj   = si + Hc * Nrows;                      // 65,536
    float* sjm  = sj + Hc * Nrows;                      // 64
    float* gout = sjm + 64;                             // N*HD = 4,194,304
    float* Q    = gout + (long long)Nrows * HDc;
    float* Km   = Q + (long long)Nrows * HDc;
    float* V    = Km + (long long)Nrows * HDc;          // total ~84.4 MB

    const dim3 blk(256);
    const float qk_scale = 0.0625f;  // 1/sqrt(256)

    // 1. Wh[h] = x @ W[h]  (+ fused si = Wh·a1, sj = Wh·a2)
    gemm_k<64, false, EPI_WH><<<dim3(Nrows / 64, 1, Hc), blk, 0, stream>>>(
        x, W, nullptr, Wh, Nrows, Dc, Fc, Fc, Dc, Dc,
        0LL, (long long)Fc * Dc, (long long)Nrows * Dc, 1.f, a1, a2, si, sj);

    // 2. per-(h,b) max of sj
    sjmax_k<<<dim3(Hc * Bc), blk, 0, stream>>>(sj, sjm);

    // 3. gat_att = softmax(lrelu(si_i + sj_j))
    gatt_k<<<dim3(Lc / 16, Hc * Bc), blk, 0, stream>>>(si, sj, sjm, gat_att);

    // 4. h = gat_att @ Wh -> gout in concat layout [b,l,h*64+d]
    gemm_k<64, false, EPI_GAT><<<dim3(Lc / 64, 1, Hc * Bc), blk, 0, stream>>>(
        gat_att, Wh, nullptr, gout, Lc, Dc, Lc, Lc, Dc, HDc,
        (long long)Lc * Lc, (long long)Lc * Dc, 0LL, 1.f,
        nullptr, nullptr, nullptr, nullptr);

    // 5. Q/K/V projections
    gemm_k<64, false, EPI_BIAS><<<dim3(Nrows / 64, HDc / 64, 1), blk, 0, stream>>>(
        gout, Wq, bq, Q, Nrows, HDc, HDc, HDc, HDc, HDc,
        0LL, 0LL, 0LL, 1.f, nullptr, nullptr, nullptr, nullptr);
    gemm_k<64, false, EPI_BIAS><<<dim3(Nrows / 64, HDc / 64, 1), blk, 0, stream>>>(
        gout, Wk, bk, Km, Nrows, HDc, HDc, HDc, HDc, HDc,
        0LL, 0LL, 0LL, 1.f, nullptr, nullptr, nullptr, nullptr);
    gemm_k<64, false, EPI_BIAS><<<dim3(Nrows / 64, HDc / 64, 1), blk, 0, stream>>>(
        gout, Wv, bv, V, Nrows, HDc, HDc, HDc, HDc, HDc,
        0LL, 0LL, 0LL, 1.f, nullptr, nullptr, nullptr, nullptr);

    // 6. scores = Q @ K^T * scale  -> t_att region (pre-softmax)
    gemm_k<64, true, EPI_SCALE><<<dim3(Lc / 64, Lc / 64, Bc), blk, 0, stream>>>(
        Q, Km, nullptr, t_att, Lc, Lc, HDc, HDc, HDc, Lc,
        (long long)Lc * HDc, (long long)Lc * HDc, (long long)Lc * Lc, qk_scale,
        nullptr, nullptr, nullptr, nullptr);

    // 7. softmax in place
    tsm_k<<<dim3(Lc / 16, Bc), blk, 0, stream>>>(t_att);

    // 8. temporal_out = t_att @ V
    gemm_k<64, false, EPI_NONE><<<dim3(Lc / 64, HDc / 64, Bc), blk, 0, stream>>>(
        t_att, V, nullptr, t_out, Lc, HDc, Lc, Lc, HDc, HDc,
        (long long)Lc * Lc, (long long)Lc * HDc, (long long)Lc * HDc, 1.f,
        nullptr, nullptr, nullptr, nullptr);

    // 9. out = temporal_out @ Wfc + bfc
    gemm_k<64, false, EPI_BIAS><<<dim3(Nrows / 64, 1, 1), blk, 0, stream>>>(
        t_out, Wfc, bfc, outp, Nrows, Dc, HDc, HDc, Dc, Dc,
        0LL, 0LL, 0LL, 1.f, nullptr, nullptr, nullptr, nullptr);
}

// Round 2
// 491.043 us; speedup vs baseline: 3.0611x; 3.0611x over previous
//
#include <hip/hip_runtime.h>

// TemporalGAT on MI355X — round 2: MFMA bf16-split GEMMs.
// B=16, L=1024, F=128, H=4, D=64, HD=256, N=B*L=16384
// Outputs: out[B,L,D], gat_att[H,B,L,L], t_att[B,L,L], temporal_out[B,L,HD]

constexpr int Bc = 16, Lc = 1024, Fc = 128, Hc = 4, Dc = 64, HDc = 256;
constexpr int Nrows = Bc * Lc;  // 16384
#define ALPHA_SLOPE 0.2f

typedef __attribute__((ext_vector_type(8))) short bf16x8;
typedef __attribute__((ext_vector_type(4))) float f32x4;

enum { EPI_NONE = 0, EPI_BIAS = 1, EPI_SCALE = 2, EPI_GAT = 3 };

__device__ __forceinline__ float lrelu(float x) { return x > 0.f ? x : ALPHA_SLOPE * x; }

// ---------------------------------------------------------------------------
// MFMA GEMM: C[M,N] = A[M,K] @ Bt[N,K]^T  (both A and Bt row-major, K-contig).
// f32 in/out; internally split each f32 into hi/lo bf16 (x ~= hi + lo), and
// accumulate hi*hi + lo*hi + hi*lo in fp32 MFMA -> ~2^-15 relative error.
// Block 256 = 4 waves in 2x2 grid; wave tile (BM/2)x(BN/2); 16x16x32 frags.
// ---------------------------------------------------------------------------
template <int BM, int BN, int EPI>
__global__ __launch_bounds__(256, 2) void mm_k(
    const float* __restrict__ A, const float* __restrict__ Bt,
    const float* __restrict__ bias, float* __restrict__ C,
    int K, int lda, int ldb, int ldc,
    long long sA, long long sB, long long sC, float alpha)
{
    constexpr int LDK = 40;  // 32 bf16 + 8 pad: row stride 80 B -> conflict-free b128 reads
    __shared__ unsigned short Ah[BM * LDK], Al[BM * LDK];
    __shared__ unsigned short Bh[BN * LDK], Bl[BN * LDK];

    const int z = blockIdx.z;
    A  += (long long)z * sA;
    Bt += (long long)z * sB;
    if (EPI == EPI_GAT) {
        // z = h*16 + b ; C base = gat_out + b*L*HD + h*D  (head-concat layout)
        C += (long long)(z & 15) * Lc * HDc + (long long)(z >> 4) * Dc;
    } else {
        C += (long long)z * sC;
    }

    const int row0 = blockIdx.x * BM;
    const int col0 = blockIdx.y * BN;
    const int t    = threadIdx.x;
    const int lane = t & 63;
    const int wid  = t >> 6;
    constexpr int WM = BM / 2, WN = BN / 2, MF = WM / 16, NF = WN / 16;
    const int wrow = (wid >> 1) * WM;
    const int wcol = (wid & 1) * WN;
    const int fr = lane & 15;          // fragment row/col within 16
    const int fk = (lane >> 4) * 8;    // fragment k-offset

    f32x4 acc[MF][NF] = {};

    constexpr int NLOAD = (BM + BN) / 32;  // float4 loads per thread per k-step

    for (int k0 = 0; k0 < K; k0 += 32) {
        #pragma unroll
        for (int it = 0; it < NLOAD; ++it) {
            const int idx = it * 256 + t;
            const int row = idx >> 3;
            const int kc  = (idx & 7) * 4;
            const float* src = (row < BM)
                ? (A  + (long long)(row0 + row) * lda + k0 + kc)
                : (Bt + (long long)(col0 + row - BM) * ldb + k0 + kc);
            const float4 v = *(const float4*)src;
            const unsigned ux = __float_as_uint(v.x), uy = __float_as_uint(v.y);
            const unsigned uz = __float_as_uint(v.z), uw = __float_as_uint(v.w);
            const unsigned h01 = __byte_perm(ux, uy, 0x7632);
            const unsigned h23 = __byte_perm(uz, uw, 0x7632);
            const float lx = v.x - __uint_as_float(ux & 0xffff0000u);
            const float ly = v.y - __uint_as_float(uy & 0xffff0000u);
            const float lz = v.z - __uint_as_float(uz & 0xffff0000u);
            const float lw = v.w - __uint_as_float(uw & 0xffff0000u);
            const unsigned l01 = __byte_perm(__float_as_uint(lx), __float_as_uint(ly), 0x7632);
            const unsigned l23 = __byte_perm(__float_as_uint(lz), __float_as_uint(lw), 0x7632);
            unsigned short *ph, *pl;
            if (row < BM) { ph = Ah + row * LDK + kc;        pl = Al + row * LDK + kc; }
            else          { ph = Bh + (row - BM) * LDK + kc; pl = Bl + (row - BM) * LDK + kc; }
            uint2 hv; hv.x = h01; hv.y = h23;
            uint2 lv; lv.x = l01; lv.y = l23;
            *(uint2*)ph = hv;
            *(uint2*)pl = lv;
        }
        __syncthreads();

        bf16x8 ah[MF], al[MF];
        #pragma unroll
        for (int mf = 0; mf < MF; ++mf) {
            const int ar = wrow + mf * 16 + fr;
            ah[mf] = *(const bf16x8*)(Ah + ar * LDK + fk);
            al[mf] = *(const bf16x8*)(Al + ar * LDK + fk);
        }
        #pragma unroll
        for (int nf = 0; nf < NF; ++nf) {
            const int br = wcol + nf * 16 + fr;
            const bf16x8 bh = *(const bf16x8*)(Bh + br * LDK + fk);
            const bf16x8 bl = *(const bf16x8*)(Bl + br * LDK + fk);
            #pragma unroll
            for (int mf = 0; mf < MF; ++mf) {
                acc[mf][nf] = __builtin_amdgcn_mfma_f32_16x16x32_bf16(ah[mf], bh, acc[mf][nf], 0, 0, 0);
                acc[mf][nf] = __builtin_amdgcn_mfma_f32_16x16x32_bf16(al[mf], bh, acc[mf][nf], 0, 0, 0);
                acc[mf][nf] = __builtin_amdgcn_mfma_f32_16x16x32_bf16(ah[mf], bl, acc[mf][nf], 0, 0, 0);
            }
        }
        __syncthreads();
    }

    // epilogue: C/D layout col = lane&15, row = (lane>>4)*4 + i  [m89]
    #pragma unroll
    for (int mf = 0; mf < MF; ++mf) {
        const long long rbase = row0 + wrow + mf * 16 + (lane >> 4) * 4;
        #pragma unroll
        for (int i = 0; i < 4; ++i) {
            float* cp = C + (rbase + i) * ldc + col0 + wcol + fr;
            #pragma unroll
            for (int nf = 0; nf < NF; ++nf) {
                float v = acc[mf][nf][i];
                if (EPI == EPI_SCALE) v *= alpha;
                if (EPI == EPI_BIAS)  v += bias[col0 + wcol + nf * 16 + fr];
                cp[nf * 16] = v;
            }
        }
    }
}

// ---------------------------------------------------------------------------
// Batched tiled transpose: dst[z][C][R] = src[z][R][C]   (R, C multiples of 32)
// ---------------------------------------------------------------------------
__global__ __launch_bounds__(256) void tr_k(const float* __restrict__ src,
                                            float* __restrict__ dst,
                                            int R, int C, long long sS, long long sD)
{
    __shared__ float tile[32][33];
    const int z = blockIdx.z;
    src += (long long)z * sS;
    dst += (long long)z * sD;
    const int c0 = blockIdx.x * 32, r0 = blockIdx.y * 32;
    const int tc = threadIdx.x & 31, tr = threadIdx.x >> 5;  // 8 rows per pass
    #pragma unroll
    for (int rr = 0; rr < 32; rr += 8)
        tile[tr + rr][tc] = src[(long long)(r0 + tr + rr) * C + c0 + tc];
    __syncthreads();
    #pragma unroll
    for (int rr = 0; rr < 32; rr += 8)
        dst[(long long)(c0 + tr + rr) * R + r0 + tc] = tile[tc][tr + rr];
}

// si = Wh . a1, sj = Wh . a2 ; Wh [H*N][64], si/sj [H*N]
__global__ __launch_bounds__(256) void sisj_k(const float* __restrict__ Wh,
                                              const float* __restrict__ a1,
                                              const float* __restrict__ a2,
                                              float* __restrict__ si, float* __restrict__ sj)
{
    const int t = threadIdx.x;
    const long long row = (long long)blockIdx.x * 16 + (t >> 4);
    const int lane = t & 15;
    const int h = (int)(row >> 14);  // 16384 rows per head
    const float4 w  = *(const float4*)(Wh + row * 64 + lane * 4);
    const float4 va = *(const float4*)(a1 + h * 64 + lane * 4);
    const float4 vb = *(const float4*)(a2 + h * 64 + lane * 4);
    float p1 = w.x * va.x + w.y * va.y + w.z * va.z + w.w * va.w;
    float p2 = w.x * vb.x + w.y * vb.y + w.z * vb.z + w.w * vb.w;
    #pragma unroll
    for (int ofs = 1; ofs < 16; ofs <<= 1) {
        p1 += __shfl_xor(p1, ofs, 64);
        p2 += __shfl_xor(p2, ofs, 64);
    }
    if (lane == 0) { si[row] = p1; sj[row] = p2; }
}

// max over each 1024-row of sj -> sjmax[hb]
__global__ __launch_bounds__(256) void sjmax_k(const float* __restrict__ sj,
                                               float* __restrict__ out)
{
    __shared__ float red[4];
    const int hb = blockIdx.x;
    const int t  = threadIdx.x;
    const float4 v = ((const float4*)(sj + (long long)hb * Lc))[t];
    float m = fmaxf(fmaxf(v.x, v.y), fmaxf(v.z, v.w));
    #pragma unroll
    for (int ofs = 32; ofs >= 1; ofs >>= 1) m = fmaxf(m, __shfl_xor(m, ofs, 64));
    if ((t & 63) == 0) red[t >> 6] = m;
    __syncthreads();
    if (t == 0) out[hb] = fmaxf(fmaxf(red[0], red[1]), fmaxf(red[2], red[3]));
}

// GAT softmax: analytic row max (lrelu monotone), single pass.
__global__ __launch_bounds__(256) void gatt_k(const float* __restrict__ si,
                                              const float* __restrict__ sj,
                                              const float* __restrict__ sjmax,
                                              float* __restrict__ att)
{
    __shared__ __align__(16) float sjs[Lc];
    __shared__ float red[4];
    const int hb    = blockIdx.y;
    const int chunk = blockIdx.x;
    const int t     = threadIdx.x;
    ((float4*)sjs)[t] = ((const float4*)(sj + (long long)hb * Lc))[t];
    const float smax = sjmax[hb];
    __syncthreads();
    const float* sip = si + (long long)hb * Lc + chunk * 16;
    float* attp = att + ((long long)hb * Lc + (long long)chunk * 16) * Lc;
    const float4 sv = ((const float4*)sjs)[t];
    for (int r = 0; r < 16; ++r) {
        const float siv = sip[r];
        const float m = lrelu(siv + smax);
        float4 p;
        p.x = __expf(lrelu(siv + sv.x) - m);
        p.y = __expf(lrelu(siv + sv.y) - m);
        p.z = __expf(lrelu(siv + sv.z) - m);
        p.w = __expf(lrelu(siv + sv.w) - m);
        float s = p.x + p.y + p.z + p.w;
        #pragma unroll
        for (int ofs = 32; ofs >= 1; ofs >>= 1) s += __shfl_xor(s, ofs, 64);
        if ((t & 63) == 0) red[t >> 6] = s;
        __syncthreads();
        const float inv = 1.0f / (red[0] + red[1] + red[2] + red[3]);
        float4 o = { p.x * inv, p.y * inv, p.z * inv, p.w * inv };
        ((float4*)(attp + (long long)r * Lc))[t] = o;
        __syncthreads();
    }
}

// temporal softmax, in place on t_att region
__global__ __launch_bounds__(256) void tsm_k(float* __restrict__ att)
{
    __shared__ float redm[4];
    __shared__ float reds[4];
    const int b     = blockIdx.y;
    const int chunk = blockIdx.x;
    const int t     = threadIdx.x;
    float* base = att + ((long long)b * Lc + (long long)chunk * 16) * Lc;
    for (int r = 0; r < 16; ++r) {
        float4 v = ((float4*)(base + (long long)r * Lc))[t];
        float m = fmaxf(fmaxf(v.x, v.y), fmaxf(v.z, v.w));
        #pragma unroll
        for (int ofs = 32; ofs >= 1; ofs >>= 1) m = fmaxf(m, __shfl_xor(m, ofs, 64));
        if ((t & 63) == 0) redm[t >> 6] = m;
        __syncthreads();
        m = fmaxf(fmaxf(redm[0], redm[1]), fmaxf(redm[2], redm[3]));
        float4 p;
        p.x = __expf(v.x - m); p.y = __expf(v.y - m);
        p.z = __expf(v.z - m); p.w = __expf(v.w - m);
        float s = p.x + p.y + p.z + p.w;
        #pragma unroll
        for (int ofs = 32; ofs >= 1; ofs >>= 1) s += __shfl_xor(s, ofs, 64);
        if ((t & 63) == 0) reds[t >> 6] = s;
        __syncthreads();
        s = reds[0] + reds[1] + reds[2] + reds[3];
        const float inv = 1.0f / s;
        float4 o = { p.x * inv, p.y * inv, p.z * inv, p.w * inv };
        ((float4*)(base + (long long)r * Lc))[t] = o;
        __syncthreads();
    }
}

extern "C" void kernel_launch(void* const* d_in, const int* in_sizes, int n_in,
                              void* d_out, int out_size, void* d_ws, size_t ws_size,
                              hipStream_t stream)
{
    const float* x   = (const float*)d_in[0];
    const float* W   = (const float*)d_in[1];
    const float* a1  = (const float*)d_in[2];
    const float* a2  = (const float*)d_in[3];
    const float* Wq  = (const float*)d_in[4];
    const float* bq  = (const float*)d_in[5];
    const float* Wk  = (const float*)d_in[6];
    const float* bk  = (const float*)d_in[7];
    const float* Wv  = (const float*)d_in[8];
    const float* bv  = (const float*)d_in[9];
    const float* Wfc = (const float*)d_in[10];
    const float* bfc = (const float*)d_in[11];

    float* outp    = (float*)d_out;
    float* gat_att = outp + (long long)Bc * Lc * Dc;
    float* t_att   = gat_att + (long long)Hc * Bc * Lc * Lc;
    float* t_out   = t_att + (long long)Bc * Lc * Lc;

    // ws aliasing: ws0 = Wh -> gout -> VT ; ws1 = WhT -> V ; ws2 = Q ; ws3 = Km
    constexpr long long BIG = (long long)Hc * Nrows * Dc;  // 4,194,304 floats (16 MB)
    float* ws   = (float*)d_ws;
    float* ws0  = ws;
    float* ws1  = ws0 + BIG;
    float* ws2  = ws1 + BIG;
    float* ws3  = ws2 + BIG;
    float* si   = ws3 + BIG;
    float* sj   = si + (long long)Hc * Nrows;
    float* sjm  = sj + (long long)Hc * Nrows;
    float* WT   = sjm + 64;                    // [4][64][128]
    float* WqT  = WT + Hc * Dc * Fc;           // [256][256]
    float* WkT  = WqT + HDc * HDc;
    float* WvT  = WkT + HDc * HDc;
    float* WfcT = WvT + HDc * HDc;             // [64][256]

    float* Wh  = ws0;  float* gout = ws0;  float* VT = ws0;
    float* WhT = ws1;  float* V    = ws1;
    float* Q   = ws2;
    float* Km  = ws3;

    const dim3 blk(256);
    const float qk_scale = 0.0625f;  // 1/sqrt(256)

    // 0. weight transposes (tiny)
    tr_k<<<dim3(2, 4, Hc), blk, 0, stream>>>(W,   WT,   Fc, Dc, (long long)Fc * Dc, (long long)Fc * Dc);
    tr_k<<<dim3(8, 8, 1),  blk, 0, stream>>>(Wq,  WqT,  HDc, HDc, 0, 0);
    tr_k<<<dim3(8, 8, 1),  blk, 0, stream>>>(Wk,  WkT,  HDc, HDc, 0, 0);
    tr_k<<<dim3(8, 8, 1),  blk, 0, stream>>>(Wv,  WvT,  HDc, HDc, 0, 0);
    tr_k<<<dim3(2, 8, 1),  blk, 0, stream>>>(Wfc, WfcT, HDc, Dc, 0, 0);

    // 1. Wh[h] = x @ W[h]   (A = x shared; B = WT[h])
    mm_k<128, 64, EPI_NONE><<<dim3(Nrows / 128, 1, Hc), blk, 0, stream>>>(
        x, WT, nullptr, Wh, Fc, Fc, Fc, Dc,
        0LL, (long long)Dc * Fc, (long long)Nrows * Dc, 1.f);

    // 2. si/sj
    sisj_k<<<dim3(Hc * Nrows / 16), blk, 0, stream>>>(Wh, a1, a2, si, sj);

    // 3. WhT[h][b] = Wh[h][b]^T  (64 batches of 1024x64 -> 64x1024)
    tr_k<<<dim3(2, 32, Hc * Bc), blk, 0, stream>>>(Wh, WhT, Lc, Dc,
        (long long)Lc * Dc, (long long)Lc * Dc);

    // 4. per-(h,b) max of sj ; gat softmax
    sjmax_k<<<dim3(Hc * Bc), blk, 0, stream>>>(sj, sjm);
    gatt_k<<<dim3(Lc / 16, Hc * Bc), blk, 0, stream>>>(si, sj, sjm, gat_att);

    // 5. gout = gat_att @ Wh  -> concat layout  (B = WhT)
    mm_k<128, 64, EPI_GAT><<<dim3(Lc / 128, 1, Hc * Bc), blk, 0, stream>>>(
        gat_att, WhT, nullptr, gout, Lc, Lc, Lc, HDc,
        (long long)Lc * Lc, (long long)Dc * Lc, 0LL, 1.f);

    // 6. Q/K/V projections
    mm_k<128, 128, EPI_BIAS><<<dim3(Nrows / 128, 2, 1), blk, 0, stream>>>(
        gout, WqT, bq, Q, HDc, HDc, HDc, HDc, 0LL, 0LL, 0LL, 1.f);
    mm_k<128, 128, EPI_BIAS><<<dim3(Nrows / 128, 2, 1), blk, 0, stream>>>(
        gout, WkT, bk, Km, HDc, HDc, HDc, HDc, 0LL, 0LL, 0LL, 1.f);
    mm_k<128, 128, EPI_BIAS><<<dim3(Nrows / 128, 2, 1), blk, 0, stream>>>(
        gout, WvT, bv, V, HDc, HDc, HDc, HDc, 0LL, 0LL, 0LL, 1.f);

    // 7. VT[b] = V[b]^T  (16 batches 1024x256 -> 256x1024); gout dead now
    tr_k<<<dim3(8, 32, Bc), blk, 0, stream>>>(V, VT, Lc, HDc,
        (long long)Lc * HDc, (long long)Lc * HDc);

    // 8. scores = Q @ K^T * scale -> t_att region
    mm_k<128, 128, EPI_SCALE><<<dim3(Lc / 128, Lc / 128, Bc), blk, 0, stream>>>(
        Q, Km, nullptr, t_att, HDc, HDc, HDc, Lc,
        (long long)Lc * HDc, (long long)Lc * HDc, (long long)Lc * Lc, qk_scale);

    // 9. softmax in place
    tsm_k<<<dim3(Lc / 16, Bc), blk, 0, stream>>>(t_att);

    // 10. temporal_out = t_att @ V   (B = VT)
    mm_k<128, 128, EPI_NONE><<<dim3(Lc / 128, HDc / 128, Bc), blk, 0, stream>>>(
        t_att, VT, nullptr, t_out, Lc, Lc, Lc, HDc,
        (long long)Lc * Lc, (long long)HDc * Lc, (long long)Lc * HDc, 1.f);

    // 11. out = temporal_out @ Wfc + bfc   (B = WfcT)
    mm_k<128, 64, EPI_BIAS><<<dim3(Nrows / 128, 1, 1), blk, 0, stream>>>(
        t_out, WfcT, bfc, outp, HDc, HDc, HDc, Dc, 0LL, 0LL, 0LL, 1.f);
}

// Round 3
// 329.218 us; speedup vs baseline: 4.5658x; 1.4915x over previous
//
#include <hip/hip_runtime.h>

// TemporalGAT on MI355X — round 3: pre-split bf16 hi/lo operands + global_load_lds
// staging (m97 structure) + fused GAT (in-register P generation, no score re-read).
// B=16, L=1024, F=128, H=4, D=64, HD=256, N=B*L=16384
// Outputs: out[B,L,D], gat_att[H,B,L,L], t_att[B,L,L], temporal_out[B,L,HD]

constexpr int Bc = 16, Lc = 1024, Fc = 128, Hc = 4, Dc = 64, HDc = 256;
constexpr int Nrows = Bc * Lc;  // 16384
#define ALPHA_SLOPE 0.2f

typedef __attribute__((ext_vector_type(8))) short bf16x8;
typedef __attribute__((ext_vector_type(4))) float f32x4;

enum { A_F32 = 0, A_HL = 1 };
enum { E_F32 = 0, E_BIAS = 1, E_SCALE = 2, E_HL = 3, E_WH = 4 };

__device__ __forceinline__ float lrelu(float x) { return x > 0.f ? x : ALPHA_SLOPE * x; }

// async global->LDS, 16B per lane; LDS dst is wave-uniform base + lane*16
__device__ __forceinline__ void gll16(const void* g, void* l) {
    __builtin_amdgcn_global_load_lds(
        (const __attribute__((address_space(1))) void*)g,
        (__attribute__((address_space(3))) void*)l, 16, 0, 0);
}

// split f32 pair into packed-hi u32 and packed-lo u32 (truncation split: x = hi + lo)
__device__ __forceinline__ void split2(float a, float b, unsigned& h, unsigned& l) {
    const unsigned ua = __float_as_uint(a), ub = __float_as_uint(b);
    h = __byte_perm(ua, ub, 0x7632);
    const float la = a - __uint_as_float(ua & 0xffff0000u);
    const float lb = b - __uint_as_float(ub & 0xffff0000u);
    l = __byte_perm(__float_as_uint(la), __float_as_uint(lb), 0x7632);
}
__device__ __forceinline__ void split1(float v, unsigned short& h, unsigned short& l) {
    const unsigned u = __float_as_uint(v);
    h = (unsigned short)(u >> 16);
    const float lf = v - __uint_as_float(u & 0xffff0000u);
    l = (unsigned short)(__float_as_uint(lf) >> 16);
}

// ---------------------------------------------------------------------------
// MFMA GEMM: C[M,N] = A[M,K] @ Bt[N,K]^T. B always pre-split hi/lo bf16 (gll
// staged). A either f32 (reg-convert staging, BM must be 128) or hi/lo bf16.
// 3-term split accumulate: AhBh + AlBh + AhBl. 4 waves; BN=128 -> 2x2 wave
// grid, BN=64 -> 4x1 (each wave covers all cols; needed by E_WH reduction).
// ---------------------------------------------------------------------------
template <int BM, int BN, int AMODE, int EPI>
__global__ __launch_bounds__(256, 2) void mm_k(
    const float* __restrict__ Af,
    const unsigned short* __restrict__ Agh, const unsigned short* __restrict__ Agl,
    const unsigned short* __restrict__ Bgh, const unsigned short* __restrict__ Bgl,
    const float* __restrict__ bias,
    float* __restrict__ Cf, unsigned short* __restrict__ Ch, unsigned short* __restrict__ Cl,
    int K, int lda, int ldb, int ldc,
    long long zA, long long zB, long long zC, float alpha,
    const float* __restrict__ a1, const float* __restrict__ a2,
    float* __restrict__ si, float* __restrict__ sj)
{
    __shared__ __align__(16) unsigned short Ah_s[BM * 32], Al_s[BM * 32];
    __shared__ __align__(16) unsigned short Bh_s[BN * 32], Bl_s[BN * 32];

    const int z = blockIdx.z;
    if (AMODE == A_F32) { Af += (size_t)z * zA; }
    else { Agh += (size_t)z * zA; Agl += (size_t)z * zA; }
    Bgh += (size_t)z * zB; Bgl += (size_t)z * zB;
    if (Cf) Cf += (size_t)z * zC;
    if (Ch) { Ch += (size_t)z * zC; Cl += (size_t)z * zC; }

    constexpr int WR = (BN == 64) ? 4 : 2, WC = (BN == 64) ? 1 : 2;
    constexpr int WM = BM / WR, WN = BN / WC, MF = WM / 16, NF = WN / 16;
    const int row0 = blockIdx.x * BM, col0 = blockIdx.y * BN;
    const int t = threadIdx.x, lane = t & 63, wid = t >> 6;
    const int fr = lane & 15, g = lane >> 4, fk = g * 8;
    const int wrow = (wid / WC) * WM, wcol = (wid % WC) * WN;
    const int rsub = lane >> 2, cbyt = (lane & 3) * 16;

    f32x4 acc[MF][NF] = {};

    for (int k0 = 0; k0 < K; k0 += 32) {
        // ---- B stage: gll, 16 rows (1 KiB) per issue per wave
        #pragma unroll
        for (int q = 0; q < BN / 64; ++q) {
            const int r = wid * (BN / 4) + q * 16;
            const size_t gb = ((size_t)(col0 + r + rsub) * ldb + k0) * 2 + cbyt;
            gll16((const char*)Bgh + gb, (char*)Bh_s + (size_t)r * 64);
            gll16((const char*)Bgl + gb, (char*)Bl_s + (size_t)r * 64);
        }
        // ---- A stage
        if (AMODE == A_HL) {
            #pragma unroll
            for (int q = 0; q < BM / 64; ++q) {
                const int r = wid * (BM / 4) + q * 16;
                const size_t gb = ((size_t)(row0 + r + rsub) * lda + k0) * 2 + cbyt;
                gll16((const char*)Agh + gb, (char*)Ah_s + (size_t)r * 64);
                gll16((const char*)Agl + gb, (char*)Al_s + (size_t)r * 64);
            }
        } else {
            // f32 -> hi/lo convert staging; BM == 128: 128 rows x 2 half-rows
            const int r = t >> 1, h2 = t & 1;
            const float* srcA = Af + (size_t)(row0 + r) * lda + k0 + h2 * 16;
            const float4 v0 = ((const float4*)srcA)[0];
            const float4 v1 = ((const float4*)srcA)[1];
            const float4 v2 = ((const float4*)srcA)[2];
            const float4 v3 = ((const float4*)srcA)[3];
            unsigned hu[8], lu[8];
            split2(v0.x, v0.y, hu[0], lu[0]); split2(v0.z, v0.w, hu[1], lu[1]);
            split2(v1.x, v1.y, hu[2], lu[2]); split2(v1.z, v1.w, hu[3], lu[3]);
            split2(v2.x, v2.y, hu[4], lu[4]); split2(v2.z, v2.w, hu[5], lu[5]);
            split2(v3.x, v3.y, hu[6], lu[6]); split2(v3.z, v3.w, hu[7], lu[7]);
            uint4* dh = (uint4*)(Ah_s + r * 32 + h2 * 16);
            dh[0] = make_uint4(hu[0], hu[1], hu[2], hu[3]);
            dh[1] = make_uint4(hu[4], hu[5], hu[6], hu[7]);
            uint4* dl = (uint4*)(Al_s + r * 32 + h2 * 16);
            dl[0] = make_uint4(lu[0], lu[1], lu[2], lu[3]);
            dl[1] = make_uint4(lu[4], lu[5], lu[6], lu[7]);
        }
        __syncthreads();

        bf16x8 ah[MF], al[MF];
        #pragma unroll
        for (int mf = 0; mf < MF; ++mf) {
            const int off = (wrow + mf * 16 + fr) * 32 + fk;
            ah[mf] = *(const bf16x8*)(Ah_s + off);
            al[mf] = *(const bf16x8*)(Al_s + off);
        }
        #pragma unroll
        for (int nf = 0; nf < NF; ++nf) {
            const int off = (wcol + nf * 16 + fr) * 32 + fk;
            const bf16x8 bh = *(const bf16x8*)(Bh_s + off);
            const bf16x8 bl = *(const bf16x8*)(Bl_s + off);
            #pragma unroll
            for (int mf = 0; mf < MF; ++mf) {
                acc[mf][nf] = __builtin_amdgcn_mfma_f32_16x16x32_bf16(ah[mf], bh, acc[mf][nf], 0, 0, 0);
                acc[mf][nf] = __builtin_amdgcn_mfma_f32_16x16x32_bf16(al[mf], bh, acc[mf][nf], 0, 0, 0);
                acc[mf][nf] = __builtin_amdgcn_mfma_f32_16x16x32_bf16(ah[mf], bl, acc[mf][nf], 0, 0, 0);
            }
        }
        __syncthreads();
    }

    // ---- epilogue (C/D layout: col = lane&15, row = (lane>>4)*4 + i  [m89])
    float bv_[NF];
    if (EPI == E_BIAS || EPI == E_HL) {
        #pragma unroll
        for (int nf = 0; nf < NF; ++nf) bv_[nf] = bias[col0 + wcol + nf * 16 + fr];
    }
    #pragma unroll
    for (int mf = 0; mf < MF; ++mf) {
        #pragma unroll
        for (int i = 0; i < 4; ++i) {
            const size_t row = (size_t)row0 + wrow + mf * 16 + g * 4 + i;
            const size_t co = row * ldc + col0 + wcol + fr;
            #pragma unroll
            for (int nf = 0; nf < NF; ++nf) {
                float v = acc[mf][nf][i];
                if (EPI == E_SCALE) v *= alpha;
                if (EPI == E_BIAS || EPI == E_HL) v += bv_[nf];
                if (EPI == E_HL) {
                    unsigned short hh, ll; split1(v, hh, ll);
                    Ch[co + nf * 16] = hh; Cl[co + nf * 16] = ll;
                } else {
                    Cf[co + nf * 16] = v;
                }
            }
        }
    }
    if (EPI == E_WH) {  // fused si = Wh.a1, sj = Wh.a2 (BN==64: wave covers all cols)
        float a1v[NF], a2v[NF];
        #pragma unroll
        for (int nf = 0; nf < NF; ++nf) {
            a1v[nf] = a1[(size_t)z * Dc + nf * 16 + fr];
            a2v[nf] = a2[(size_t)z * Dc + nf * 16 + fr];
        }
        #pragma unroll
        for (int mf = 0; mf < MF; ++mf) {
            #pragma unroll
            for (int i = 0; i < 4; ++i) {
                float p1 = 0.f, p2 = 0.f;
                #pragma unroll
                for (int nf = 0; nf < NF; ++nf) {
                    p1 = fmaf(acc[mf][nf][i], a1v[nf], p1);
                    p2 = fmaf(acc[mf][nf][i], a2v[nf], p2);
                }
                #pragma unroll
                for (int ofs = 1; ofs < 16; ofs <<= 1) {
                    p1 += __shfl_xor(p1, ofs, 64);
                    p2 += __shfl_xor(p2, ofs, 64);
                }
                if (fr == 0) {
                    const int row = row0 + wrow + mf * 16 + g * 4 + i;
                    si[(size_t)z * Nrows + row] = p1;
                    sj[(size_t)z * Nrows + row] = p2;
                }
            }
        }
    }
}

// ---------------------------------------------------------------------------
// Fused GAT: per (h,b), row-block of 128. P = exp(lrelu(si+sj)-m)*inv generated
// in-register directly in MFMA A-fragment layout; writes gat_att f32 once and
// accumulates P @ WhT -> gout (hi/lo bf16, head-concat layout).
// ---------------------------------------------------------------------------
__global__ __launch_bounds__(256, 2) void gat_k(
    const float* __restrict__ si, const float* __restrict__ sj,
    const float* __restrict__ sjm, const float* __restrict__ irs,
    const unsigned short* __restrict__ WhTh, const unsigned short* __restrict__ WhTl,
    float* __restrict__ att, unsigned short* __restrict__ gouth,
    unsigned short* __restrict__ goutl)
{
    __shared__ __align__(16) unsigned short Bh_s[64 * 32], Bl_s[64 * 32];
    const int z = blockIdx.z;          // hb, h-major (z = h*16 + b)
    const int row0 = blockIdx.x * 128;
    const int t = threadIdx.x, lane = t & 63, wid = t >> 6;
    const int fr = lane & 15, g = lane >> 4, fk = g * 8;
    const int wrow = wid * 32;
    const int hh = z >> 4, bb = z & 15;
    const int rsub = lane >> 2, cbyt = (lane & 3) * 16;

    float siv[2], mr[2], inv[2];
    #pragma unroll
    for (int mf = 0; mf < 2; ++mf) {
        const int r = row0 + wrow + mf * 16 + fr;
        const float s = si[(size_t)hh * Nrows + bb * 1024 + r];
        siv[mf] = s;
        mr[mf] = lrelu(s + sjm[z]);
        inv[mf] = irs[(size_t)z * 1024 + r];
    }
    f32x4 acc[2][4] = {};
    const unsigned short* WhTh_z = WhTh + (size_t)z * 64 * 1024;
    const unsigned short* WhTl_z = WhTl + (size_t)z * 64 * 1024;
    const float* sjz = sj + (size_t)z * 1024;
    float* attz = att + ((size_t)z * 1024 + row0) * 1024;

    for (int j0 = 0; j0 < 1024; j0 += 32) {
        {   // stage WhT chunk [64 d][32 j]
            const int r = wid * 16;
            const size_t gb = ((size_t)(r + rsub) * 1024 + j0) * 2 + cbyt;
            gll16((const char*)WhTh_z + gb, (char*)Bh_s + (size_t)r * 64);
            gll16((const char*)WhTl_z + gb, (char*)Bl_s + (size_t)r * 64);
        }
        bf16x8 ph[2], pl[2];
        #pragma unroll
        for (int mf = 0; mf < 2; ++mf) {
            const float4 s0 = *(const float4*)(sjz + j0 + fk);
            const float4 s1 = *(const float4*)(sjz + j0 + fk + 4);
            float p[8];
            p[0] = __expf(lrelu(siv[mf] + s0.x) - mr[mf]) * inv[mf];
            p[1] = __expf(lrelu(siv[mf] + s0.y) - mr[mf]) * inv[mf];
            p[2] = __expf(lrelu(siv[mf] + s0.z) - mr[mf]) * inv[mf];
            p[3] = __expf(lrelu(siv[mf] + s0.w) - mr[mf]) * inv[mf];
            p[4] = __expf(lrelu(siv[mf] + s1.x) - mr[mf]) * inv[mf];
            p[5] = __expf(lrelu(siv[mf] + s1.y) - mr[mf]) * inv[mf];
            p[6] = __expf(lrelu(siv[mf] + s1.z) - mr[mf]) * inv[mf];
            p[7] = __expf(lrelu(siv[mf] + s1.w) - mr[mf]) * inv[mf];
            float* ap = attz + (size_t)(wrow + mf * 16 + fr) * 1024 + j0 + fk;
            *(float4*)ap       = make_float4(p[0], p[1], p[2], p[3]);
            *(float4*)(ap + 4) = make_float4(p[4], p[5], p[6], p[7]);
            union { unsigned u[4]; bf16x8 v; } uh, ul;
            split2(p[0], p[1], uh.u[0], ul.u[0]);
            split2(p[2], p[3], uh.u[1], ul.u[1]);
            split2(p[4], p[5], uh.u[2], ul.u[2]);
            split2(p[6], p[7], uh.u[3], ul.u[3]);
            ph[mf] = uh.v; pl[mf] = ul.v;
        }
        __syncthreads();
        #pragma unroll
        for (int nf = 0; nf < 4; ++nf) {
            const int off = (nf * 16 + fr) * 32 + fk;
            const bf16x8 bh = *(const bf16x8*)(Bh_s + off);
            const bf16x8 bl = *(const bf16x8*)(Bl_s + off);
            #pragma unroll
            for (int mf = 0; mf < 2; ++mf) {
                acc[mf][nf] = __builtin_amdgcn_mfma_f32_16x16x32_bf16(ph[mf], bh, acc[mf][nf], 0, 0, 0);
                acc[mf][nf] = __builtin_amdgcn_mfma_f32_16x16x32_bf16(pl[mf], bh, acc[mf][nf], 0, 0, 0);
                acc[mf][nf] = __builtin_amdgcn_mfma_f32_16x16x32_bf16(ph[mf], bl, acc[mf][nf], 0, 0, 0);
            }
        }
        __syncthreads();
    }
    // epilogue: gout hi/lo, concat layout [b, l, h*64+d]
    #pragma unroll
    for (int mf = 0; mf < 2; ++mf) {
        #pragma unroll
        for (int i = 0; i < 4; ++i) {
            const int row_l = wrow + mf * 16 + g * 4 + i;
            const size_t base = ((size_t)bb * 1024 + row0 + row_l) * 256 + hh * 64 + fr;
            #pragma unroll
            for (int nf = 0; nf < 4; ++nf) {
                unsigned short hh16, ll16; split1(acc[mf][nf][i], hh16, ll16);
                gouth[base + nf * 16] = hh16;
                goutl[base + nf * 16] = ll16;
            }
        }
    }
}

// batched transpose + hi/lo split: dst[C][R] (bf16 hi,lo) = src[R][C] (f32)
__global__ __launch_bounds__(256) void trcvt_k(
    const float* __restrict__ src, unsigned short* __restrict__ dh,
    unsigned short* __restrict__ dl, int R, int C, long long sS, long long sD)
{
    __shared__ float tile[32][33];
    const int z = blockIdx.z;
    src += (size_t)z * sS; dh += (size_t)z * sD; dl += (size_t)z * sD;
    const int c0 = blockIdx.x * 32, r0 = blockIdx.y * 32;
    const int tc = threadIdx.x & 31, tr = threadIdx.x >> 5;
    #pragma unroll
    for (int rr = 0; rr < 32; rr += 8)
        tile[tr + rr][tc] = src[(size_t)(r0 + tr + rr) * C + c0 + tc];
    __syncthreads();
    #pragma unroll
    for (int rr = 0; rr < 32; rr += 8) {
        unsigned short h, l; split1(tile[tc][tr + rr], h, l);
        const size_t o = (size_t)(c0 + tr + rr) * R + r0 + tc;
        dh[o] = h; dl[o] = l;
    }
}

// max over each 1024-row of sj -> sjm[hb]
__global__ __launch_bounds__(256) void sjmax_k(const float* __restrict__ sj,
                                               float* __restrict__ out)
{
    __shared__ float red[4];
    const int hb = blockIdx.x;
    const int t = threadIdx.x;
    const float4 v = ((const float4*)(sj + (size_t)hb * Lc))[t];
    float m = fmaxf(fmaxf(v.x, v.y), fmaxf(v.z, v.w));
    #pragma unroll
    for (int ofs = 32; ofs >= 1; ofs >>= 1) m = fmaxf(m, __shfl_xor(m, ofs, 64));
    if ((t & 63) == 0) red[t >> 6] = m;
    __syncthreads();
    if (t == 0) out[hb] = fmaxf(fmaxf(red[0], red[1]), fmaxf(red[2], red[3]));
}

// inv row sums: irs[hb][i] = 1 / sum_j exp(lrelu(si+sj)-m)
__global__ __launch_bounds__(256) void rsum_k(const float* __restrict__ si,
                                              const float* __restrict__ sj,
                                              const float* __restrict__ sjm,
                                              float* __restrict__ irs)
{
    __shared__ __align__(16) float sjs[Lc];
    __shared__ float red[4];
    const int z = blockIdx.y, c0 = blockIdx.x * 16;
    const int t = threadIdx.x;
    ((float4*)sjs)[t] = ((const float4*)(sj + (size_t)z * Lc))[t];
    const float smax = sjm[z];
    __syncthreads();
    const int hh = z >> 4, bb = z & 15;
    const float4 v = ((const float4*)sjs)[t];
    for (int r = 0; r < 16; ++r) {
        const int row = c0 + r;
        const float sv = si[(size_t)hh * Nrows + bb * 1024 + row];
        const float m = lrelu(sv + smax);
        float s = __expf(lrelu(sv + v.x) - m) + __expf(lrelu(sv + v.y) - m)
                + __expf(lrelu(sv + v.z) - m) + __expf(lrelu(sv + v.w) - m);
        #pragma unroll
        for (int ofs = 32; ofs >= 1; ofs >>= 1) s += __shfl_xor(s, ofs, 64);
        if ((t & 63) == 0) red[t >> 6] = s;
        __syncthreads();
        if (t == 0) irs[(size_t)z * Lc + row] = 1.0f / (red[0] + red[1] + red[2] + red[3]);
        __syncthreads();
    }
}

// temporal softmax, in place on t_att region
__global__ __launch_bounds__(256) void tsm_k(float* __restrict__ att)
{
    __shared__ float redm[4];
    __shared__ float reds[4];
    const int b = blockIdx.y, chunk = blockIdx.x;
    const int t = threadIdx.x;
    float* base = att + ((size_t)b * Lc + (size_t)chunk * 16) * Lc;
    for (int r = 0; r < 16; ++r) {
        float4 v = ((float4*)(base + (size_t)r * Lc))[t];
        float m = fmaxf(fmaxf(v.x, v.y), fmaxf(v.z, v.w));
        #pragma unroll
        for (int ofs = 32; ofs >= 1; ofs >>= 1) m = fmaxf(m, __shfl_xor(m, ofs, 64));
        if ((t & 63) == 0) redm[t >> 6] = m;
        __syncthreads();
        m = fmaxf(fmaxf(redm[0], redm[1]), fmaxf(redm[2], redm[3]));
        float4 p;
        p.x = __expf(v.x - m); p.y = __expf(v.y - m);
        p.z = __expf(v.z - m); p.w = __expf(v.w - m);
        float s = p.x + p.y + p.z + p.w;
        #pragma unroll
        for (int ofs = 32; ofs >= 1; ofs >>= 1) s += __shfl_xor(s, ofs, 64);
        if ((t & 63) == 0) reds[t >> 6] = s;
        __syncthreads();
        s = reds[0] + reds[1] + reds[2] + reds[3];
        const float inv = 1.0f / s;
        float4 o = { p.x * inv, p.y * inv, p.z * inv, p.w * inv };
        ((float4*)(base + (size_t)r * Lc))[t] = o;
        __syncthreads();
    }
}

extern "C" void kernel_launch(void* const* d_in, const int* in_sizes, int n_in,
                              void* d_out, int out_size, void* d_ws, size_t ws_size,
                              hipStream_t stream)
{
    const float* x   = (const float*)d_in[0];
    const float* W   = (const float*)d_in[1];
    const float* a1  = (const float*)d_in[2];
    const float* a2  = (const float*)d_in[3];
    const float* Wq  = (const float*)d_in[4];
    const float* bq  = (const float*)d_in[5];
    const float* Wk  = (const float*)d_in[6];
    const float* bk  = (const float*)d_in[7];
    const float* Wv  = (const float*)d_in[8];
    const float* bv  = (const float*)d_in[9];
    const float* Wfc = (const float*)d_in[10];
    const float* bfc = (const float*)d_in[11];

    float* outp    = (float*)d_out;
    float* gat_att = outp + (size_t)Bc * Lc * Dc;
    float* t_att   = gat_att + (size_t)Hc * Bc * Lc * Lc;
    float* t_out   = t_att + (size_t)Bc * Lc * Lc;

    constexpr size_t MB = 1024 * 1024;
    char* wsb = (char*)d_ws;
    // R0 (16MB): Wh f32 -> V f32
    float* Wh = (float*)wsb;
    float* V  = Wh;
    // R1 (16MB): WhT-hl -> Q-hl
    unsigned short* WhTh = (unsigned short*)(wsb + 16 * MB);
    unsigned short* WhTl = WhTh + (size_t)64 * 64 * 1024;
    unsigned short* Qh = WhTh; unsigned short* Ql = WhTl;
    // R2 (16MB): gout-hl -> VT-hl
    unsigned short* gouth = (unsigned short*)(wsb + 32 * MB);
    unsigned short* goutl = gouth + (size_t)Nrows * HDc;
    unsigned short* VTh = gouth; unsigned short* VTl = goutl;
    // R3 (16MB): K-hl
    unsigned short* Kh = (unsigned short*)(wsb + 48 * MB);
    unsigned short* Kl = Kh + (size_t)Nrows * HDc;
    // R4: small buffers
    float* si  = (float*)(wsb + 64 * MB);           // [4][16384]
    float* sj  = si + Hc * Nrows;
    float* sjm = sj + Hc * Nrows;                   // [64]
    float* irs = sjm + 64;                          // [64][1024]
    unsigned short* WTh  = (unsigned short*)(irs + Hc * Nrows);  // [4][64][128]
    unsigned short* WTl  = WTh + Hc * Dc * Fc;
    unsigned short* WqTh = WTl + Hc * Dc * Fc;      // [256][256]
    unsigned short* WqTl = WqTh + HDc * HDc;
    unsigned short* WkTh = WqTl + HDc * HDc;
    unsigned short* WkTl = WkTh + HDc * HDc;
    unsigned short* WvTh = WkTl + HDc * HDc;
    unsigned short* WvTl = WvTh + HDc * HDc;
    unsigned short* WfcTh = WvTl + HDc * HDc;       // [64][256]
    unsigned short* WfcTl = WfcTh + Dc * HDc;

    const dim3 blk(256);

    // 0. weight transpose+split
    trcvt_k<<<dim3(2, 4, Hc), blk, 0, stream>>>(W, WTh, WTl, Fc, Dc, (long long)Fc * Dc, (long long)Dc * Fc);
    trcvt_k<<<dim3(8, 8, 1), blk, 0, stream>>>(Wq, WqTh, WqTl, HDc, HDc, 0, 0);
    trcvt_k<<<dim3(8, 8, 1), blk, 0, stream>>>(Wk, WkTh, WkTl, HDc, HDc, 0, 0);
    trcvt_k<<<dim3(8, 8, 1), blk, 0, stream>>>(Wv, WvTh, WvTl, HDc, HDc, 0, 0);
    trcvt_k<<<dim3(2, 8, 1), blk, 0, stream>>>(Wfc, WfcTh, WfcTl, HDc, Dc, 0, 0);

    // 1. Wh[h] = x @ W[h]^T, fused si/sj
    mm_k<128, 64, A_F32, E_WH><<<dim3(Nrows / 128, 1, Hc), blk, 0, stream>>>(
        x, nullptr, nullptr, WTh, WTl, nullptr, Wh, nullptr, nullptr,
        Fc, Fc, Fc, Dc, 0LL, (long long)Dc * Fc, (long long)Nrows * Dc, 1.f,
        a1, a2, si, sj);

    // 2. WhT-hl (per hb: 1024x64 -> 64x1024)
    trcvt_k<<<dim3(2, 32, 64), blk, 0, stream>>>(Wh, WhTh, WhTl, Lc, Dc,
        (long long)Lc * Dc, (long long)Dc * Lc);

    // 3. softmax normalizers
    sjmax_k<<<dim3(64), blk, 0, stream>>>(sj, sjm);
    rsum_k<<<dim3(Lc / 16, 64), blk, 0, stream>>>(si, sj, sjm, irs);

    // 4. fused GAT: gat_att + gout-hl
    gat_k<<<dim3(Lc / 128, 1, 64), blk, 0, stream>>>(si, sj, sjm, irs,
        WhTh, WhTl, gat_att, gouth, goutl);

    // 5. Q/K/V projections
    mm_k<128, 128, A_HL, E_HL><<<dim3(Nrows / 128, 2, 1), blk, 0, stream>>>(
        nullptr, gouth, goutl, WqTh, WqTl, bq, nullptr, Qh, Ql,
        HDc, HDc, HDc, HDc, 0LL, 0LL, 0LL, 1.f, nullptr, nullptr, nullptr, nullptr);
    mm_k<128, 128, A_HL, E_HL><<<dim3(Nrows / 128, 2, 1), blk, 0, stream>>>(
        nullptr, gouth, goutl, WkTh, WkTl, bk, nullptr, Kh, Kl,
        HDc, HDc, HDc, HDc, 0LL, 0LL, 0LL, 1.f, nullptr, nullptr, nullptr, nullptr);
    mm_k<128, 128, A_HL, E_BIAS><<<dim3(Nrows / 128, 2, 1), blk, 0, stream>>>(
        nullptr, gouth, goutl, WvTh, WvTl, bv, V, nullptr, nullptr,
        HDc, HDc, HDc, HDc, 0LL, 0LL, 0LL, 1.f, nullptr, nullptr, nullptr, nullptr);

    // 6. VT-hl (per b: 1024x256 -> 256x1024); gout dead
    trcvt_k<<<dim3(8, 32, Bc), blk, 0, stream>>>(V, VTh, VTl, Lc, HDc,
        (long long)Lc * HDc, (long long)HDc * Lc);

    // 7. scores = Q @ K^T * scale -> t_att
    mm_k<128, 128, A_HL, E_SCALE><<<dim3(8, 8, Bc), blk, 0, stream>>>(
        nullptr, Qh, Ql, Kh, Kl, nullptr, t_att, nullptr, nullptr,
        HDc, HDc, HDc, Lc, (long long)Lc * HDc, (long long)Lc * HDc,
        (long long)Lc * Lc, 0.0625f, nullptr, nullptr, nullptr, nullptr);

    // 8. softmax in place
    tsm_k<<<dim3(Lc / 16, Bc), blk, 0, stream>>>(t_att);

    // 9. temporal_out = t_att @ V
    mm_k<128, 128, A_F32, E_F32><<<dim3(8, 2, Bc), blk, 0, stream>>>(
        t_att, nullptr, nullptr, VTh, VTl, nullptr, t_out, nullptr, nullptr,
        Lc, Lc, Lc, HDc, (long long)Lc * Lc, (long long)HDc * Lc,
        (long long)Lc * HDc, 1.f, nullptr, nullptr, nullptr, nullptr);

    // 10. out = temporal_out @ Wfc + bfc
    mm_k<128, 64, A_F32, E_BIAS><<<dim3(Nrows / 128, 1, 1), blk, 0, stream>>>(
        t_out, nullptr, nullptr, WfcTh, WfcTl, bfc, outp, nullptr, nullptr,
        HDc, HDc, HDc, Dc, 0LL, 0LL, 0LL, 1.f, nullptr, nullptr, nullptr, nullptr);
}

// Round 4
// 299.075 us; speedup vs baseline: 5.0260x; 1.1008x over previous
//
#include <hip/hip_runtime.h>

// TemporalGAT on MI355X — round 4: fused temporal softmax (QK stats epilogue +
// in-place normalize in PV), fused QKV projection. bf16 hi/lo split MFMA.
// B=16, L=1024, F=128, H=4, D=64, HD=256, N=B*L=16384
// Outputs: out[B,L,D], gat_att[H,B,L,L], t_att[B,L,L], temporal_out[B,L,HD]

constexpr int Bc = 16, Lc = 1024, Fc = 128, Hc = 4, Dc = 64, HDc = 256;
constexpr int Nrows = Bc * Lc;  // 16384
#define ALPHA_SLOPE 0.2f

typedef __attribute__((ext_vector_type(8))) short bf16x8;
typedef __attribute__((ext_vector_type(4))) float f32x4;

enum { A_F32 = 0, A_HL = 1 };
enum { E_F32 = 0, E_BIAS = 1, E_WH = 2, E_STATS = 3, E_QKV = 4 };

__device__ __forceinline__ float lrelu(float x) { return x > 0.f ? x : ALPHA_SLOPE * x; }

__device__ __forceinline__ void gll16(const void* g, void* l) {
    __builtin_amdgcn_global_load_lds(
        (const __attribute__((address_space(1))) void*)g,
        (__attribute__((address_space(3))) void*)l, 16, 0, 0);
}

__device__ __forceinline__ void split2(float a, float b, unsigned& h, unsigned& l) {
    const unsigned ua = __float_as_uint(a), ub = __float_as_uint(b);
    h = __byte_perm(ua, ub, 0x7632);
    const float la = a - __uint_as_float(ua & 0xffff0000u);
    const float lb = b - __uint_as_float(ub & 0xffff0000u);
    l = __byte_perm(__float_as_uint(la), __float_as_uint(lb), 0x7632);
}
__device__ __forceinline__ void split1(float v, unsigned short& h, unsigned short& l) {
    const unsigned u = __float_as_uint(v);
    h = (unsigned short)(u >> 16);
    const float lf = v - __uint_as_float(u & 0xffff0000u);
    l = (unsigned short)(__float_as_uint(lf) >> 16);
}

// ---------------------------------------------------------------------------
// MFMA GEMM: C[M,N] = A[M,K] @ Bt[N,K]^T. 3-term bf16 hi/lo split accumulate.
// ---------------------------------------------------------------------------
template <int BM, int BN, int AMODE, int EPI>
__global__ __launch_bounds__(256, 2) void mm_k(
    const float* __restrict__ Af,
    const unsigned short* __restrict__ Agh, const unsigned short* __restrict__ Agl,
    const unsigned short* __restrict__ Bgh, const unsigned short* __restrict__ Bgl,
    const float* __restrict__ bias,
    float* __restrict__ Cf, unsigned short* __restrict__ Ch, unsigned short* __restrict__ Cl,
    unsigned short* __restrict__ Ch2, unsigned short* __restrict__ Cl2,
    int K, int lda, int ldb, int ldc,
    long long zA, long long zB, long long zC, float alpha,
    const float* __restrict__ a1, const float* __restrict__ a2,
    float* __restrict__ si, float* __restrict__ sj, float* __restrict__ pstats)
{
    __shared__ __align__(16) unsigned short Ah_s[BM * 32], Al_s[BM * 32];
    __shared__ __align__(16) unsigned short Bh_s[BN * 32], Bl_s[BN * 32];

    const int z = blockIdx.z;
    if (AMODE == A_F32) { Af += (size_t)z * zA; }
    else { Agh += (size_t)z * zA; Agl += (size_t)z * zA; }
    Bgh += (size_t)z * zB; Bgl += (size_t)z * zB;
    if (Cf) Cf += (size_t)z * zC;
    if (EPI != E_QKV && Ch) { Ch += (size_t)z * zC; Cl += (size_t)z * zC; }

    constexpr int WC = (BN == 64) ? 1 : 2, WR = 4 / WC;
    constexpr int WM = BM / WR, WN = BN / WC, MF = WM / 16, NF = WN / 16;
    const int row0 = blockIdx.x * BM, col0 = blockIdx.y * BN;
    const int t = threadIdx.x, lane = t & 63, wid = t >> 6;
    const int fr = lane & 15, g = lane >> 4, fk = g * 8;
    const int wrow = (wid / WC) * WM, wcol = (wid % WC) * WN;
    const int rsub = lane >> 2, cbyt = (lane & 3) * 16;

    f32x4 acc[MF][NF] = {};

    for (int k0 = 0; k0 < K; k0 += 32) {
        #pragma unroll
        for (int q = 0; q < BN / 64; ++q) {
            const int r = wid * (BN / 4) + q * 16;
            const size_t gb = ((size_t)(col0 + r + rsub) * ldb + k0) * 2 + cbyt;
            gll16((const char*)Bgh + gb, (char*)Bh_s + (size_t)r * 64);
            gll16((const char*)Bgl + gb, (char*)Bl_s + (size_t)r * 64);
        }
        if (AMODE == A_HL) {
            #pragma unroll
            for (int q = 0; q < BM / 64; ++q) {
                const int r = wid * (BM / 4) + q * 16;
                const size_t gb = ((size_t)(row0 + r + rsub) * lda + k0) * 2 + cbyt;
                gll16((const char*)Agh + gb, (char*)Ah_s + (size_t)r * 64);
                gll16((const char*)Agl + gb, (char*)Al_s + (size_t)r * 64);
            }
        } else {
            const int r = t >> 1, h2 = t & 1;
            const float* srcA = Af + (size_t)(row0 + r) * lda + k0 + h2 * 16;
            const float4 v0 = ((const float4*)srcA)[0];
            const float4 v1 = ((const float4*)srcA)[1];
            const float4 v2 = ((const float4*)srcA)[2];
            const float4 v3 = ((const float4*)srcA)[3];
            unsigned hu[8], lu[8];
            split2(v0.x, v0.y, hu[0], lu[0]); split2(v0.z, v0.w, hu[1], lu[1]);
            split2(v1.x, v1.y, hu[2], lu[2]); split2(v1.z, v1.w, hu[3], lu[3]);
            split2(v2.x, v2.y, hu[4], lu[4]); split2(v2.z, v2.w, hu[5], lu[5]);
            split2(v3.x, v3.y, hu[6], lu[6]); split2(v3.z, v3.w, hu[7], lu[7]);
            uint4* dh = (uint4*)(Ah_s + r * 32 + h2 * 16);
            dh[0] = make_uint4(hu[0], hu[1], hu[2], hu[3]);
            dh[1] = make_uint4(hu[4], hu[5], hu[6], hu[7]);
            uint4* dl = (uint4*)(Al_s + r * 32 + h2 * 16);
            dl[0] = make_uint4(lu[0], lu[1], lu[2], lu[3]);
            dl[1] = make_uint4(lu[4], lu[5], lu[6], lu[7]);
        }
        __syncthreads();

        bf16x8 ah[MF], al[MF];
        #pragma unroll
        for (int mf = 0; mf < MF; ++mf) {
            const int off = (wrow + mf * 16 + fr) * 32 + fk;
            ah[mf] = *(const bf16x8*)(Ah_s + off);
            al[mf] = *(const bf16x8*)(Al_s + off);
        }
        #pragma unroll
        for (int nf = 0; nf < NF; ++nf) {
            const int off = (wcol + nf * 16 + fr) * 32 + fk;
            const bf16x8 bh = *(const bf16x8*)(Bh_s + off);
            const bf16x8 bl = *(const bf16x8*)(Bl_s + off);
            #pragma unroll
            for (int mf = 0; mf < MF; ++mf) {
                acc[mf][nf] = __builtin_amdgcn_mfma_f32_16x16x32_bf16(ah[mf], bh, acc[mf][nf], 0, 0, 0);
                acc[mf][nf] = __builtin_amdgcn_mfma_f32_16x16x32_bf16(al[mf], bh, acc[mf][nf], 0, 0, 0);
                acc[mf][nf] = __builtin_amdgcn_mfma_f32_16x16x32_bf16(ah[mf], bl, acc[mf][nf], 0, 0, 0);
            }
        }
        __syncthreads();
    }

    // ---- epilogue (C/D layout: col = lane&15, row = (lane>>4)*4 + i  [m89])
    float bv_[NF];
    if (EPI == E_BIAS || EPI == E_QKV) {
        #pragma unroll
        for (int nf = 0; nf < NF; ++nf) bv_[nf] = bias[col0 + wcol + nf * 16 + fr];
    }
    const int cl0 = (EPI == E_QKV) ? (col0 & 255) : col0;
    #pragma unroll
    for (int mf = 0; mf < MF; ++mf) {
        #pragma unroll
        for (int i = 0; i < 4; ++i) {
            const size_t row = (size_t)row0 + wrow + mf * 16 + g * 4 + i;
            const size_t co = row * ldc + cl0 + wcol + fr;
            #pragma unroll
            for (int nf = 0; nf < NF; ++nf) {
                float v = acc[mf][nf][i];
                if (EPI == E_STATS) v *= alpha;
                if (EPI == E_BIAS || EPI == E_QKV) v += bv_[nf];
                acc[mf][nf][i] = v;
                if (EPI == E_QKV) {
                    unsigned short hh, ll; split1(v, hh, ll);
                    if (col0 < 256)      { Ch[co + nf * 16] = hh;  Cl[co + nf * 16] = ll; }
                    else if (col0 < 512) { Ch2[co + nf * 16] = hh; Cl2[co + nf * 16] = ll; }
                    else                 { Cf[co + nf * 16] = v; }
                } else {
                    Cf[co + nf * 16] = v;
                }
            }
        }
    }
    if (EPI == E_STATS) {
        // partial softmax stats per (row, 64-col wave slice) -> pstats[z][16][1024][2]
        const int ty = blockIdx.y * WC + (wid % WC);
        #pragma unroll
        for (int mf = 0; mf < MF; ++mf) {
            #pragma unroll
            for (int i = 0; i < 4; ++i) {
                float m = acc[mf][0][i], s;
                #pragma unroll
                for (int nf = 1; nf < NF; ++nf) m = fmaxf(m, acc[mf][nf][i]);
                s = 0.f;
                #pragma unroll
                for (int nf = 0; nf < NF; ++nf) s += __expf(acc[mf][nf][i] - m);
                #pragma unroll
                for (int ofs = 1; ofs < 16; ofs <<= 1) {
                    const float om = __shfl_xor(m, ofs, 64);
                    const float os = __shfl_xor(s, ofs, 64);
                    const float nm = fmaxf(m, om);
                    s = s * __expf(m - nm) + os * __expf(om - nm);
                    m = nm;
                }
                if (fr == 0) {
                    const size_t row = (size_t)row0 + wrow + mf * 16 + g * 4 + i;
                    float* p = pstats + (((size_t)z * 16 + ty) * Lc + row) * 2;
                    p[0] = m; p[1] = s;
                }
            }
        }
    }
    if (EPI == E_WH) {
        float a1v[NF], a2v[NF];
        #pragma unroll
        for (int nf = 0; nf < NF; ++nf) {
            a1v[nf] = a1[(size_t)z * Dc + nf * 16 + fr];
            a2v[nf] = a2[(size_t)z * Dc + nf * 16 + fr];
        }
        #pragma unroll
        for (int mf = 0; mf < MF; ++mf) {
            #pragma unroll
            for (int i = 0; i < 4; ++i) {
                float p1 = 0.f, p2 = 0.f;
                #pragma unroll
                for (int nf = 0; nf < NF; ++nf) {
                    p1 = fmaf(acc[mf][nf][i], a1v[nf], p1);
                    p2 = fmaf(acc[mf][nf][i], a2v[nf], p2);
                }
                #pragma unroll
                for (int ofs = 1; ofs < 16; ofs <<= 1) {
                    p1 += __shfl_xor(p1, ofs, 64);
                    p2 += __shfl_xor(p2, ofs, 64);
                }
                if (fr == 0) {
                    const int row = row0 + wrow + mf * 16 + g * 4 + i;
                    si[(size_t)z * Nrows + row] = p1;
                    sj[(size_t)z * Nrows + row] = p2;
                }
            }
        }
    }
}

// combine 16 partial stats per row -> mrow, invs
__global__ __launch_bounds__(256) void rstat_k(const float* __restrict__ ps,
                                               float* __restrict__ mrow,
                                               float* __restrict__ invs)
{
    const int idx = blockIdx.x * 256 + threadIdx.x;  // b*1024 + row
    const int b = idx >> 10, row = idx & 1023;
    float m = -1e30f, s = 0.f;
    #pragma unroll
    for (int ty = 0; ty < 16; ++ty) {
        const float2 p = *(const float2*)(ps + (((size_t)b * 16 + ty) * Lc + row) * 2);
        const float nm = fmaxf(m, p.x);
        s = s * __expf(m - nm) + p.y * __expf(p.x - nm);
        m = nm;
    }
    mrow[idx] = m;
    invs[idx] = 1.0f / s;
}

// ---------------------------------------------------------------------------
// PV with fused softmax: reads raw scaled scores (own 64 rows), normalizes
// in place -> t_att, MFMAs p @ VT -> t_out.  BM=64, BN=256, grid (16,1,16).
// ---------------------------------------------------------------------------
__global__ __launch_bounds__(256, 2) void pv_k(
    float* __restrict__ scores, const float* __restrict__ mrow,
    const float* __restrict__ invs,
    const unsigned short* __restrict__ VTh, const unsigned short* __restrict__ VTl,
    float* __restrict__ tout)
{
    __shared__ __align__(16) unsigned short Ah_s[64 * 32], Al_s[64 * 32];
    __shared__ __align__(16) unsigned short Bh_s[256 * 32], Bl_s[256 * 32];
    const int z = blockIdx.z;
    const int row0 = blockIdx.x * 64;
    const int t = threadIdx.x, lane = t & 63, wid = t >> 6;
    const int fr = lane & 15, g = lane >> 4, fk = g * 8;
    const int rsub = lane >> 2, cbyt = (lane & 3) * 16;

    float* sc = scores + ((size_t)z * Lc + row0) * Lc;
    const unsigned short* VTh_z = VTh + (size_t)z * HDc * Lc;
    const unsigned short* VTl_z = VTl + (size_t)z * HDc * Lc;

    const int ar = t >> 2, cq = (t & 3) * 8;          // staging row / col-offset
    const float m_  = mrow[(size_t)z * Lc + row0 + ar];
    const float iv_ = invs[(size_t)z * Lc + row0 + ar];

    f32x4 acc[4][4] = {};

    for (int k0 = 0; k0 < Lc; k0 += 32) {
        #pragma unroll
        for (int q = 0; q < 4; ++q) {
            const int r = q * 64 + wid * 16;
            const size_t gb = ((size_t)(r + rsub) * Lc + k0) * 2 + cbyt;
            gll16((const char*)VTh_z + gb, (char*)Bh_s + (size_t)r * 64);
            gll16((const char*)VTl_z + gb, (char*)Bl_s + (size_t)r * 64);
        }
        {   // A stage: raw scores -> p, write back normalized, split to LDS
            float* srcS = sc + (size_t)ar * Lc + k0 + cq;
            const float4 v0 = ((const float4*)srcS)[0];
            const float4 v1 = ((const float4*)srcS)[1];
            float p[8];
            p[0] = __expf(v0.x - m_) * iv_; p[1] = __expf(v0.y - m_) * iv_;
            p[2] = __expf(v0.z - m_) * iv_; p[3] = __expf(v0.w - m_) * iv_;
            p[4] = __expf(v1.x - m_) * iv_; p[5] = __expf(v1.y - m_) * iv_;
            p[6] = __expf(v1.z - m_) * iv_; p[7] = __expf(v1.w - m_) * iv_;
            ((float4*)srcS)[0] = make_float4(p[0], p[1], p[2], p[3]);
            ((float4*)srcS)[1] = make_float4(p[4], p[5], p[6], p[7]);
            unsigned hu[4], lu[4];
            split2(p[0], p[1], hu[0], lu[0]); split2(p[2], p[3], hu[1], lu[1]);
            split2(p[4], p[5], hu[2], lu[2]); split2(p[6], p[7], hu[3], lu[3]);
            *(uint4*)(Ah_s + ar * 32 + cq) = make_uint4(hu[0], hu[1], hu[2], hu[3]);
            *(uint4*)(Al_s + ar * 32 + cq) = make_uint4(lu[0], lu[1], lu[2], lu[3]);
        }
        __syncthreads();

        bf16x8 ah[4], al[4];
        #pragma unroll
        for (int mf = 0; mf < 4; ++mf) {
            const int off = (mf * 16 + fr) * 32 + fk;
            ah[mf] = *(const bf16x8*)(Ah_s + off);
            al[mf] = *(const bf16x8*)(Al_s + off);
        }
        #pragma unroll
        for (int nf = 0; nf < 4; ++nf) {
            const int off = (wid * 64 + nf * 16 + fr) * 32 + fk;
            const bf16x8 bh = *(const bf16x8*)(Bh_s + off);
            const bf16x8 bl = *(const bf16x8*)(Bl_s + off);
            #pragma unroll
            for (int mf = 0; mf < 4; ++mf) {
                acc[mf][nf] = __builtin_amdgcn_mfma_f32_16x16x32_bf16(ah[mf], bh, acc[mf][nf], 0, 0, 0);
                acc[mf][nf] = __builtin_amdgcn_mfma_f32_16x16x32_bf16(al[mf], bh, acc[mf][nf], 0, 0, 0);
                acc[mf][nf] = __builtin_amdgcn_mfma_f32_16x16x32_bf16(ah[mf], bl, acc[mf][nf], 0, 0, 0);
            }
        }
        __syncthreads();
    }
    #pragma unroll
    for (int mf = 0; mf < 4; ++mf) {
        #pragma unroll
        for (int i = 0; i < 4; ++i) {
            const size_t row = (size_t)row0 + mf * 16 + g * 4 + i;
            float* cp = tout + ((size_t)z * Lc + row) * HDc + wid * 64 + fr;
            #pragma unroll
            for (int nf = 0; nf < 4; ++nf) cp[nf * 16] = acc[mf][nf][i];
        }
    }
}

// ---------------------------------------------------------------------------
// Fused GAT (unchanged from round 3)
// ---------------------------------------------------------------------------
__global__ __launch_bounds__(256, 2) void gat_k(
    const float* __restrict__ si, const float* __restrict__ sj,
    const float* __restrict__ sjm, const float* __restrict__ irs,
    const unsigned short* __restrict__ WhTh, const unsigned short* __restrict__ WhTl,
    float* __restrict__ att, unsigned short* __restrict__ gouth,
    unsigned short* __restrict__ goutl)
{
    __shared__ __align__(16) unsigned short Bh_s[64 * 32], Bl_s[64 * 32];
    const int z = blockIdx.z;
    const int row0 = blockIdx.x * 128;
    const int t = threadIdx.x, lane = t & 63, wid = t >> 6;
    const int fr = lane & 15, g = lane >> 4, fk = g * 8;
    const int wrow = wid * 32;
    const int hh = z >> 4, bb = z & 15;
    const int rsub = lane >> 2, cbyt = (lane & 3) * 16;

    float siv[2], mr[2], inv[2];
    #pragma unroll
    for (int mf = 0; mf < 2; ++mf) {
        const int r = row0 + wrow + mf * 16 + fr;
        const float s = si[(size_t)hh * Nrows + bb * 1024 + r];
        siv[mf] = s;
        mr[mf] = lrelu(s + sjm[z]);
        inv[mf] = irs[(size_t)z * 1024 + r];
    }
    f32x4 acc[2][4] = {};
    const unsigned short* WhTh_z = WhTh + (size_t)z * 64 * 1024;
    const unsigned short* WhTl_z = WhTl + (size_t)z * 64 * 1024;
    const float* sjz = sj + (size_t)z * 1024;
    float* attz = att + ((size_t)z * 1024 + row0) * 1024;

    for (int j0 = 0; j0 < 1024; j0 += 32) {
        {
            const int r = wid * 16;
            const size_t gb = ((size_t)(r + rsub) * 1024 + j0) * 2 + cbyt;
            gll16((const char*)WhTh_z + gb, (char*)Bh_s + (size_t)r * 64);
            gll16((const char*)WhTl_z + gb, (char*)Bl_s + (size_t)r * 64);
        }
        bf16x8 ph[2], pl[2];
        #pragma unroll
        for (int mf = 0; mf < 2; ++mf) {
            const float4 s0 = *(const float4*)(sjz + j0 + fk);
            const float4 s1 = *(const float4*)(sjz + j0 + fk + 4);
            float p[8];
            p[0] = __expf(lrelu(siv[mf] + s0.x) - mr[mf]) * inv[mf];
            p[1] = __expf(lrelu(siv[mf] + s0.y) - mr[mf]) * inv[mf];
            p[2] = __expf(lrelu(siv[mf] + s0.z) - mr[mf]) * inv[mf];
            p[3] = __expf(lrelu(siv[mf] + s0.w) - mr[mf]) * inv[mf];
            p[4] = __expf(lrelu(siv[mf] + s1.x) - mr[mf]) * inv[mf];
            p[5] = __expf(lrelu(siv[mf] + s1.y) - mr[mf]) * inv[mf];
            p[6] = __expf(lrelu(siv[mf] + s1.z) - mr[mf]) * inv[mf];
            p[7] = __expf(lrelu(siv[mf] + s1.w) - mr[mf]) * inv[mf];
            float* ap = attz + (size_t)(wrow + mf * 16 + fr) * 1024 + j0 + fk;
            *(float4*)ap       = make_float4(p[0], p[1], p[2], p[3]);
            *(float4*)(ap + 4) = make_float4(p[4], p[5], p[6], p[7]);
            union { unsigned u[4]; bf16x8 v; } uh, ul;
            split2(p[0], p[1], uh.u[0], ul.u[0]);
            split2(p[2], p[3], uh.u[1], ul.u[1]);
            split2(p[4], p[5], uh.u[2], ul.u[2]);
            split2(p[6], p[7], uh.u[3], ul.u[3]);
            ph[mf] = uh.v; pl[mf] = ul.v;
        }
        __syncthreads();
        #pragma unroll
        for (int nf = 0; nf < 4; ++nf) {
            const int off = (nf * 16 + fr) * 32 + fk;
            const bf16x8 bh = *(const bf16x8*)(Bh_s + off);
            const bf16x8 bl = *(const bf16x8*)(Bl_s + off);
            #pragma unroll
            for (int mf = 0; mf < 2; ++mf) {
                acc[mf][nf] = __builtin_amdgcn_mfma_f32_16x16x32_bf16(ph[mf], bh, acc[mf][nf], 0, 0, 0);
                acc[mf][nf] = __builtin_amdgcn_mfma_f32_16x16x32_bf16(pl[mf], bh, acc[mf][nf], 0, 0, 0);
                acc[mf][nf] = __builtin_amdgcn_mfma_f32_16x16x32_bf16(ph[mf], bl, acc[mf][nf], 0, 0, 0);
            }
        }
        __syncthreads();
    }
    #pragma unroll
    for (int mf = 0; mf < 2; ++mf) {
        #pragma unroll
        for (int i = 0; i < 4; ++i) {
            const int row_l = wrow + mf * 16 + g * 4 + i;
            const size_t base = ((size_t)bb * 1024 + row0 + row_l) * 256 + hh * 64 + fr;
            #pragma unroll
            for (int nf = 0; nf < 4; ++nf) {
                unsigned short hh16, ll16; split1(acc[mf][nf][i], hh16, ll16);
                gouth[base + nf * 16] = hh16;
                goutl[base + nf * 16] = ll16;
            }
        }
    }
}

// batched transpose + hi/lo split
__global__ __launch_bounds__(256) void trcvt_k(
    const float* __restrict__ src, unsigned short* __restrict__ dh,
    unsigned short* __restrict__ dl, int R, int C, long long sS, long long sD)
{
    __shared__ float tile[32][33];
    const int z = blockIdx.z;
    src += (size_t)z * sS; dh += (size_t)z * sD; dl += (size_t)z * sD;
    const int c0 = blockIdx.x * 32, r0 = blockIdx.y * 32;
    const int tc = threadIdx.x & 31, tr = threadIdx.x >> 5;
    #pragma unroll
    for (int rr = 0; rr < 32; rr += 8)
        tile[tr + rr][tc] = src[(size_t)(r0 + tr + rr) * C + c0 + tc];
    __syncthreads();
    #pragma unroll
    for (int rr = 0; rr < 32; rr += 8) {
        unsigned short h, l; split1(tile[tc][tr + rr], h, l);
        const size_t o = (size_t)(c0 + tr + rr) * R + r0 + tc;
        dh[o] = h; dl[o] = l;
    }
}

__global__ __launch_bounds__(256) void bcat_k(const float* __restrict__ bq,
                                              const float* __restrict__ bk,
                                              const float* __restrict__ bv,
                                              float* __restrict__ bcat)
{
    const int t = threadIdx.x;
    bcat[t] = bq[t]; bcat[256 + t] = bk[t]; bcat[512 + t] = bv[t];
}

__global__ __launch_bounds__(256) void sjmax_k(const float* __restrict__ sj,
                                               float* __restrict__ out)
{
    __shared__ float red[4];
    const int hb = blockIdx.x;
    const int t = threadIdx.x;
    const float4 v = ((const float4*)(sj + (size_t)hb * Lc))[t];
    float m = fmaxf(fmaxf(v.x, v.y), fmaxf(v.z, v.w));
    #pragma unroll
    for (int ofs = 32; ofs >= 1; ofs >>= 1) m = fmaxf(m, __shfl_xor(m, ofs, 64));
    if ((t & 63) == 0) red[t >> 6] = m;
    __syncthreads();
    if (t == 0) out[hb] = fmaxf(fmaxf(red[0], red[1]), fmaxf(red[2], red[3]));
}

__global__ __launch_bounds__(256) void rsum_k(const float* __restrict__ si,
                                              const float* __restrict__ sj,
                                              const float* __restrict__ sjm,
                                              float* __restrict__ irs)
{
    __shared__ __align__(16) float sjs[Lc];
    __shared__ float red[4];
    const int z = blockIdx.y, c0 = blockIdx.x * 16;
    const int t = threadIdx.x;
    ((float4*)sjs)[t] = ((const float4*)(sj + (size_t)z * Lc))[t];
    const float smax = sjm[z];
    __syncthreads();
    const int hh = z >> 4, bb = z & 15;
    const float4 v = ((const float4*)sjs)[t];
    for (int r = 0; r < 16; ++r) {
        const int row = c0 + r;
        const float sv = si[(size_t)hh * Nrows + bb * 1024 + row];
        const float m = lrelu(sv + smax);
        float s = __expf(lrelu(sv + v.x) - m) + __expf(lrelu(sv + v.y) - m)
                + __expf(lrelu(sv + v.z) - m) + __expf(lrelu(sv + v.w) - m);
        #pragma unroll
        for (int ofs = 32; ofs >= 1; ofs >>= 1) s += __shfl_xor(s, ofs, 64);
        if ((t & 63) == 0) red[t >> 6] = s;
        __syncthreads();
        if (t == 0) irs[(size_t)z * Lc + row] = 1.0f / (red[0] + red[1] + red[2] + red[3]);
        __syncthreads();
    }
}

extern "C" void kernel_launch(void* const* d_in, const int* in_sizes, int n_in,
                              void* d_out, int out_size, void* d_ws, size_t ws_size,
                              hipStream_t stream)
{
    const float* x   = (const float*)d_in[0];
    const float* W   = (const float*)d_in[1];
    const float* a1  = (const float*)d_in[2];
    const float* a2  = (const float*)d_in[3];
    const float* Wq  = (const float*)d_in[4];
    const float* bq  = (const float*)d_in[5];
    const float* Wk  = (const float*)d_in[6];
    const float* bk  = (const float*)d_in[7];
    const float* Wv  = (const float*)d_in[8];
    const float* bv  = (const float*)d_in[9];
    const float* Wfc = (const float*)d_in[10];
    const float* bfc = (const float*)d_in[11];

    float* outp    = (float*)d_out;
    float* gat_att = outp + (size_t)Bc * Lc * Dc;
    float* t_att   = gat_att + (size_t)Hc * Bc * Lc * Lc;
    float* t_out   = t_att + (size_t)Bc * Lc * Lc;

    constexpr size_t MB = 1024 * 1024;
    char* wsb = (char*)d_ws;
    // region 0 (0-16MB):  Wh f32  -> V f32
    float* Wh = (float*)wsb;
    float* V  = Wh;
    // region 1 (16-32MB): WhT-hl -> Q-hl
    unsigned short* WhTh = (unsigned short*)(wsb + 16 * MB);
    unsigned short* WhTl = WhTh + (size_t)64 * 64 * 1024;
    unsigned short* Qh = WhTh; unsigned short* Ql = WhTl;
    // region 2 (32-48MB): gout-hl -> VT-hl
    unsigned short* gouth = (unsigned short*)(wsb + 32 * MB);
    unsigned short* goutl = gouth + (size_t)Nrows * HDc;
    unsigned short* VTh = gouth; unsigned short* VTl = goutl;
    // region 3 (48-64MB): K-hl
    unsigned short* Kh = (unsigned short*)(wsb + 48 * MB);
    unsigned short* Kl = Kh + (size_t)Nrows * HDc;
    // region 4 (64MB+): small
    float* si  = (float*)(wsb + 64 * MB);
    float* sj  = si + Hc * Nrows;
    float* sjm = sj + Hc * Nrows;                   // [64]
    float* irs = sjm + 64;                          // [64][1024]
    float* pstats = irs + Hc * Nrows;               // [16][16][1024][2] = 2 MB
    float* mrow = pstats + (size_t)Bc * 16 * Lc * 2;  // [16][1024]
    float* invs = mrow + Bc * Lc;
    unsigned short* WTh = (unsigned short*)(invs + Bc * Lc);  // [4][64][128]
    unsigned short* WTl = WTh + Hc * Dc * Fc;
    unsigned short* Wch = WTl + Hc * Dc * Fc;       // [768][256] concat qkv
    unsigned short* Wcl = Wch + 768 * HDc;
    unsigned short* WfcTh = Wcl + 768 * HDc;        // [64][256]
    unsigned short* WfcTl = WfcTh + Dc * HDc;
    float* bcat = (float*)(WfcTl + Dc * HDc);       // [768]

    const dim3 blk(256);

    // 0. weight prep
    trcvt_k<<<dim3(2, 4, Hc), blk, 0, stream>>>(W, WTh, WTl, Fc, Dc, (long long)Fc * Dc, (long long)Dc * Fc);
    trcvt_k<<<dim3(8, 8, 1), blk, 0, stream>>>(Wq, Wch, Wcl, HDc, HDc, 0, 0);
    trcvt_k<<<dim3(8, 8, 1), blk, 0, stream>>>(Wk, Wch + 256 * HDc, Wcl + 256 * HDc, HDc, HDc, 0, 0);
    trcvt_k<<<dim3(8, 8, 1), blk, 0, stream>>>(Wv, Wch + 512 * HDc, Wcl + 512 * HDc, HDc, HDc, 0, 0);
    trcvt_k<<<dim3(2, 8, 1), blk, 0, stream>>>(Wfc, WfcTh, WfcTl, HDc, Dc, 0, 0);
    bcat_k<<<dim3(1), blk, 0, stream>>>(bq, bk, bv, bcat);

    // 1. Wh[h] = x @ W[h]^T, fused si/sj
    mm_k<128, 64, A_F32, E_WH><<<dim3(Nrows / 128, 1, Hc), blk, 0, stream>>>(
        x, nullptr, nullptr, WTh, WTl, nullptr, Wh, nullptr, nullptr, nullptr, nullptr,
        Fc, Fc, Fc, Dc, 0LL, (long long)Dc * Fc, (long long)Nrows * Dc, 1.f,
        a1, a2, si, sj, nullptr);

    // 2. WhT-hl
    trcvt_k<<<dim3(2, 32, 64), blk, 0, stream>>>(Wh, WhTh, WhTl, Lc, Dc,
        (long long)Lc * Dc, (long long)Dc * Lc);

    // 3. GAT softmax normalizers
    sjmax_k<<<dim3(64), blk, 0, stream>>>(sj, sjm);
    rsum_k<<<dim3(Lc / 16, 64), blk, 0, stream>>>(si, sj, sjm, irs);

    // 4. fused GAT: gat_att + gout-hl
    gat_k<<<dim3(Lc / 128, 1, 64), blk, 0, stream>>>(si, sj, sjm, irs,
        WhTh, WhTl, gat_att, gouth, goutl);

    // 5. fused QKV projection (Q-hl, K-hl, V f32)
    mm_k<128, 128, A_HL, E_QKV><<<dim3(Nrows / 128, 6, 1), blk, 0, stream>>>(
        nullptr, gouth, goutl, Wch, Wcl, bcat, V, Qh, Ql, Kh, Kl,
        HDc, HDc, HDc, HDc, 0LL, 0LL, 0LL, 1.f, nullptr, nullptr, nullptr, nullptr, nullptr);

    // 6. VT-hl
    trcvt_k<<<dim3(8, 32, Bc), blk, 0, stream>>>(V, VTh, VTl, Lc, HDc,
        (long long)Lc * HDc, (long long)HDc * Lc);

    // 7. raw scaled scores -> t_att region, + partial row stats
    mm_k<128, 128, A_HL, E_STATS><<<dim3(8, 8, Bc), blk, 0, stream>>>(
        nullptr, Qh, Ql, Kh, Kl, nullptr, t_att, nullptr, nullptr, nullptr, nullptr,
        HDc, HDc, HDc, Lc, (long long)Lc * HDc, (long long)Lc * HDc,
        (long long)Lc * Lc, 0.0625f, nullptr, nullptr, nullptr, nullptr, pstats);

    // 8. combine stats
    rstat_k<<<dim3(Nrows / 256), blk, 0, stream>>>(pstats, mrow, invs);

    // 9. PV with fused softmax: normalize t_att in place, t_out = p @ V
    pv_k<<<dim3(16, 1, Bc), blk, 0, stream>>>(t_att, mrow, invs, VTh, VTl, t_out);

    // 10. out = temporal_out @ Wfc + bfc
    mm_k<128, 64, A_F32, E_BIAS><<<dim3(Nrows / 128, 1, 1), blk, 0, stream>>>(
        t_out, nullptr, nullptr, WfcTh, WfcTl, bfc, outp, nullptr, nullptr, nullptr, nullptr,
        HDc, HDc, HDc, Dc, 0LL, 0LL, 0LL, 1.f, nullptr, nullptr, nullptr, nullptr, nullptr);
}

// Round 5
// 276.379 us; speedup vs baseline: 5.4387x; 1.0821x over previous
//
#include <hip/hip_runtime.h>

// TemporalGAT on MI355X — round 5: 2-phase double-buffered pipelines (prefetch
// overlap, 1 barrier/K-step), epilogue LDS-transposes (no Wh/V f32 round-trips),
// single weight-prep kernel. bf16 hi/lo 3-term split MFMA throughout.
// B=16, L=1024, F=128, H=4, D=64, HD=256, N=B*L=16384

constexpr int Bc = 16, Lc = 1024, Fc = 128, Hc = 4, Dc = 64, HDc = 256;
constexpr int Nrows = Bc * Lc;  // 16384
#define ALPHA_SLOPE 0.2f

typedef __attribute__((ext_vector_type(8))) short bf16x8;
typedef __attribute__((ext_vector_type(4))) float f32x4;

enum { A_F32 = 0, A_HL = 1 };
enum { E_BIAS = 1, E_WHT = 2, E_STATS = 3, E_QKV = 4 };

__device__ __forceinline__ float lrelu(float x) { return x > 0.f ? x : ALPHA_SLOPE * x; }

__device__ __forceinline__ void gll16(const void* g, void* l) {
    __builtin_amdgcn_global_load_lds(
        (const __attribute__((address_space(1))) void*)g,
        (__attribute__((address_space(3))) void*)l, 16, 0, 0);
}

__device__ __forceinline__ void split2(float a, float b, unsigned& h, unsigned& l) {
    const unsigned ua = __float_as_uint(a), ub = __float_as_uint(b);
    h = __byte_perm(ua, ub, 0x7632);
    const float la = a - __uint_as_float(ua & 0xffff0000u);
    const float lb = b - __uint_as_float(ub & 0xffff0000u);
    l = __byte_perm(__float_as_uint(la), __float_as_uint(lb), 0x7632);
}
__device__ __forceinline__ void split1(float v, unsigned short& h, unsigned short& l) {
    const unsigned u = __float_as_uint(v);
    h = (unsigned short)(u >> 16);
    const float lf = v - __uint_as_float(u & 0xffff0000u);
    l = (unsigned short)(__float_as_uint(lf) >> 16);
}

// ---------------------------------------------------------------------------
// MFMA GEMM, 2-phase double-buffered: C[M,N] = A[M,K] @ Bt[N,K]^T.
// ---------------------------------------------------------------------------
template <int BM, int BN, int AMODE, int EPI>
__global__ __launch_bounds__(256, 2) void mm_k(
    const float* __restrict__ Af,
    const unsigned short* __restrict__ Agh, const unsigned short* __restrict__ Agl,
    const unsigned short* __restrict__ Bgh, const unsigned short* __restrict__ Bgl,
    const float* __restrict__ bias,
    float* __restrict__ Cf,
    unsigned short* __restrict__ Ch, unsigned short* __restrict__ Cl,
    unsigned short* __restrict__ Ch2, unsigned short* __restrict__ Cl2,
    unsigned short* __restrict__ Ch3, unsigned short* __restrict__ Cl3,
    int K, int lda, int ldb, int ldc,
    long long zA, long long zB, long long zC, float alpha,
    const float* __restrict__ a1, const float* __restrict__ a2,
    float* __restrict__ si, float* __restrict__ sj, float* __restrict__ pstats)
{
    constexpr int ABUF = BM * 32, BBUF = BN * 32;
    __shared__ __align__(16) unsigned short SM[4 * ABUF + 4 * BBUF];
    unsigned short* const Ah_s = SM;
    unsigned short* const Al_s = SM + 2 * ABUF;
    unsigned short* const Bh_s = SM + 4 * ABUF;
    unsigned short* const Bl_s = SM + 4 * ABUF + 2 * BBUF;

    const int z = blockIdx.z;
    if (AMODE == A_F32) { Af += (size_t)z * zA; }
    else { Agh += (size_t)z * zA; Agl += (size_t)z * zA; }
    Bgh += (size_t)z * zB; Bgl += (size_t)z * zB;
    if (Cf) Cf += (size_t)z * zC;

    constexpr int WC = (BN == 64) ? 1 : 2, WR = 4 / WC;
    constexpr int WM = BM / WR, WN = BN / WC, MF = WM / 16, NF = WN / 16;
    const int row0 = blockIdx.x * BM, col0 = blockIdx.y * BN;
    const int t = threadIdx.x, lane = t & 63, wid = t >> 6;
    const int fr = lane & 15, g = lane >> 4, fk = g * 8;
    const int wrow = (wid / WC) * WM, wcol = (wid % WC) * WN;
    const int rsub = lane >> 2, cbyt = (lane & 3) * 16;

    f32x4 acc[MF][NF] = {};

    auto stageB = [&](int k0, int pp) {
        #pragma unroll
        for (int q = 0; q < BN / 64; ++q) {
            const int r = wid * (BN / 4) + q * 16;
            const size_t gb = ((size_t)(col0 + r + rsub) * ldb + k0) * 2 + cbyt;
            gll16((const char*)Bgh + gb, (char*)(Bh_s + pp * BBUF) + (size_t)r * 64);
            gll16((const char*)Bgl + gb, (char*)(Bl_s + pp * BBUF) + (size_t)r * 64);
        }
    };
    auto stageA = [&](int k0, int pp) {
        if (AMODE == A_HL) {
            #pragma unroll
            for (int q = 0; q < BM / 64; ++q) {
                const int r = wid * (BM / 4) + q * 16;
                const size_t gb = ((size_t)(row0 + r + rsub) * lda + k0) * 2 + cbyt;
                gll16((const char*)Agh + gb, (char*)(Ah_s + pp * ABUF) + (size_t)r * 64);
                gll16((const char*)Agl + gb, (char*)(Al_s + pp * ABUF) + (size_t)r * 64);
            }
        } else {
            // f32 -> hi/lo reg-convert staging (BM == 128)
            const int r = t >> 1, h2 = t & 1;
            const float* srcA = Af + (size_t)(row0 + r) * lda + k0 + h2 * 16;
            const float4 v0 = ((const float4*)srcA)[0];
            const float4 v1 = ((const float4*)srcA)[1];
            const float4 v2 = ((const float4*)srcA)[2];
            const float4 v3 = ((const float4*)srcA)[3];
            unsigned hu[8], lu[8];
            split2(v0.x, v0.y, hu[0], lu[0]); split2(v0.z, v0.w, hu[1], lu[1]);
            split2(v1.x, v1.y, hu[2], lu[2]); split2(v1.z, v1.w, hu[3], lu[3]);
            split2(v2.x, v2.y, hu[4], lu[4]); split2(v2.z, v2.w, hu[5], lu[5]);
            split2(v3.x, v3.y, hu[6], lu[6]); split2(v3.z, v3.w, hu[7], lu[7]);
            uint4* dh = (uint4*)(Ah_s + pp * ABUF + r * 32 + h2 * 16);
            dh[0] = make_uint4(hu[0], hu[1], hu[2], hu[3]);
            dh[1] = make_uint4(hu[4], hu[5], hu[6], hu[7]);
            uint4* dl = (uint4*)(Al_s + pp * ABUF + r * 32 + h2 * 16);
            dl[0] = make_uint4(lu[0], lu[1], lu[2], lu[3]);
            dl[1] = make_uint4(lu[4], lu[5], lu[6], lu[7]);
        }
    };

    stageB(0, 0);
    stageA(0, 0);
    __syncthreads();

    const int NT = K / 32;
    int p = 0;
    for (int kt = 0; kt < NT; ++kt) {
        bf16x8 ah[MF], al[MF];
        #pragma unroll
        for (int mf = 0; mf < MF; ++mf) {
            const int off = p * ABUF + (wrow + mf * 16 + fr) * 32 + fk;
            ah[mf] = *(const bf16x8*)(Ah_s + off);
            al[mf] = *(const bf16x8*)(Al_s + off);
        }
        if (kt + 1 < NT) { stageB((kt + 1) * 32, p ^ 1); stageA((kt + 1) * 32, p ^ 1); }
        #pragma unroll
        for (int nf = 0; nf < NF; ++nf) {
            const int off = p * BBUF + (wcol + nf * 16 + fr) * 32 + fk;
            const bf16x8 bh = *(const bf16x8*)(Bh_s + off);
            const bf16x8 bl = *(const bf16x8*)(Bl_s + off);
            #pragma unroll
            for (int mf = 0; mf < MF; ++mf) {
                acc[mf][nf] = __builtin_amdgcn_mfma_f32_16x16x32_bf16(ah[mf], bh, acc[mf][nf], 0, 0, 0);
                acc[mf][nf] = __builtin_amdgcn_mfma_f32_16x16x32_bf16(al[mf], bh, acc[mf][nf], 0, 0, 0);
                acc[mf][nf] = __builtin_amdgcn_mfma_f32_16x16x32_bf16(ah[mf], bl, acc[mf][nf], 0, 0, 0);
            }
        }
        __syncthreads();
        p ^= 1;
    }

    // ---- epilogues (C/D layout: col = lane&15, row = (lane>>4)*4 + i [m89])
    float* ts = (float*)SM;  // transpose scratch overlays staging (post-barrier)

    if (EPI == E_BIAS || EPI == E_STATS) {
        float bv_[NF];
        if (EPI == E_BIAS) {
            #pragma unroll
            for (int nf = 0; nf < NF; ++nf) bv_[nf] = bias[col0 + wcol + nf * 16 + fr];
        }
        #pragma unroll
        for (int mf = 0; mf < MF; ++mf) {
            #pragma unroll
            for (int i = 0; i < 4; ++i) {
                const size_t row = (size_t)row0 + wrow + mf * 16 + g * 4 + i;
                const size_t co = row * ldc + col0 + wcol + fr;
                #pragma unroll
                for (int nf = 0; nf < NF; ++nf) {
                    float v = acc[mf][nf][i];
                    if (EPI == E_STATS) v *= alpha;
                    if (EPI == E_BIAS)  v += bv_[nf];
                    acc[mf][nf][i] = v;
                    Cf[co + nf * 16] = v;
                }
            }
        }
        if (EPI == E_STATS) {
            const int ty = blockIdx.y * WC + (wid % WC);
            #pragma unroll
            for (int mf = 0; mf < MF; ++mf) {
                #pragma unroll
                for (int i = 0; i < 4; ++i) {
                    float m = acc[mf][0][i], s;
                    #pragma unroll
                    for (int nf = 1; nf < NF; ++nf) m = fmaxf(m, acc[mf][nf][i]);
                    s = 0.f;
                    #pragma unroll
                    for (int nf = 0; nf < NF; ++nf) s += __expf(acc[mf][nf][i] - m);
                    #pragma unroll
                    for (int ofs = 1; ofs < 16; ofs <<= 1) {
                        const float om = __shfl_xor(m, ofs, 64);
                        const float os = __shfl_xor(s, ofs, 64);
                        const float nm = fmaxf(m, om);
                        s = s * __expf(m - nm) + os * __expf(om - nm);
                        m = nm;
                    }
                    if (fr == 0) {
                        const size_t row = (size_t)row0 + wrow + mf * 16 + g * 4 + i;
                        float* pp = pstats + (((size_t)z * 16 + ty) * Lc + row) * 2;
                        pp[0] = m; pp[1] = s;
                    }
                }
            }
        }
    }

    if (EPI == E_QKV) {
        float bv_[NF];
        #pragma unroll
        for (int nf = 0; nf < NF; ++nf) bv_[nf] = bias[col0 + wcol + nf * 16 + fr];
        #pragma unroll
        for (int mf = 0; mf < MF; ++mf)
            #pragma unroll
            for (int i = 0; i < 4; ++i)
                #pragma unroll
                for (int nf = 0; nf < NF; ++nf) acc[mf][nf][i] += bv_[nf];

        if (col0 < 512) {
            // Q (cols 0-255) / K (256-511): linear hi/lo write
            unsigned short* dH = (col0 < 256) ? Ch : Ch2;
            unsigned short* dL = (col0 < 256) ? Cl : Cl2;
            const int cl0 = col0 & 255;
            #pragma unroll
            for (int mf = 0; mf < MF; ++mf) {
                #pragma unroll
                for (int i = 0; i < 4; ++i) {
                    const size_t row = (size_t)row0 + wrow + mf * 16 + g * 4 + i;
                    const size_t co = row * ldc + cl0 + wcol + fr;
                    #pragma unroll
                    for (int nf = 0; nf < NF; ++nf) {
                        unsigned short hh16, ll16; split1(acc[mf][nf][i], hh16, ll16);
                        dH[co + nf * 16] = hh16; dL[co + nf * 16] = ll16;
                    }
                }
            }
        } else {
            // V (cols 512-767): transposed hi/lo write -> VT[b][d][l], two col-halves
            const int bq_ = row0 >> 10, lg0 = row0 & 1023;
            #pragma unroll
            for (int hf = 0; hf < 2; ++hf) {
                if ((wid & 1) == hf) {
                    #pragma unroll
                    for (int mf = 0; mf < MF; ++mf)
                        #pragma unroll
                        for (int i = 0; i < 4; ++i) {
                            const int rr = wrow + mf * 16 + g * 4 + i;
                            #pragma unroll
                            for (int nf = 0; nf < NF; ++nf)
                                ts[rr * 65 + nf * 16 + fr] = acc[mf][nf][i];
                        }
                }
                __syncthreads();
                const int l = t & 127, db = (t >> 7) * 32;
                #pragma unroll
                for (int dd = 0; dd < 32; ++dd) {
                    const int dl = db + dd;
                    unsigned short hh16, ll16; split1(ts[l * 65 + dl], hh16, ll16);
                    const size_t o = ((size_t)bq_ * 256 + (col0 - 512) + hf * 64 + dl) * 1024 + lg0 + l;
                    Ch3[o] = hh16; Cl3[o] = ll16;
                }
                __syncthreads();
            }
        }
    }

    if (EPI == E_WHT) {
        // si/sj fused reductions (BN==64: each wave spans all 64 cols)
        float a1v[NF], a2v[NF];
        #pragma unroll
        for (int nf = 0; nf < NF; ++nf) {
            a1v[nf] = a1[(size_t)z * Dc + nf * 16 + fr];
            a2v[nf] = a2[(size_t)z * Dc + nf * 16 + fr];
        }
        #pragma unroll
        for (int mf = 0; mf < MF; ++mf) {
            #pragma unroll
            for (int i = 0; i < 4; ++i) {
                float p1 = 0.f, p2 = 0.f;
                #pragma unroll
                for (int nf = 0; nf < NF; ++nf) {
                    p1 = fmaf(acc[mf][nf][i], a1v[nf], p1);
                    p2 = fmaf(acc[mf][nf][i], a2v[nf], p2);
                }
                #pragma unroll
                for (int ofs = 1; ofs < 16; ofs <<= 1) {
                    p1 += __shfl_xor(p1, ofs, 64);
                    p2 += __shfl_xor(p2, ofs, 64);
                }
                if (fr == 0) {
                    const int row = row0 + wrow + mf * 16 + g * 4 + i;
                    si[(size_t)z * Nrows + row] = p1;
                    sj[(size_t)z * Nrows + row] = p2;
                }
            }
        }
        // transposed hi/lo write -> WhT[h*16+b][d][l]
        #pragma unroll
        for (int mf = 0; mf < MF; ++mf)
            #pragma unroll
            for (int i = 0; i < 4; ++i) {
                const int rr = wrow + mf * 16 + g * 4 + i;
                #pragma unroll
                for (int nf = 0; nf < NF; ++nf)
                    ts[rr * 65 + nf * 16 + fr] = acc[mf][nf][i];
            }
        __syncthreads();
        const int bq_ = row0 >> 10, lg0 = row0 & 1023;
        const int l = t & 127, db = (t >> 7) * 32;
        #pragma unroll
        for (int dd = 0; dd < 32; ++dd) {
            const int d = db + dd;
            unsigned short hh16, ll16; split1(ts[l * 65 + d], hh16, ll16);
            const size_t o = (((size_t)(z * 16 + bq_)) * 64 + d) * 1024 + lg0 + l;
            Ch[o] = hh16; Cl[o] = ll16;
        }
    }
}

// ---------------------------------------------------------------------------
// Fused GAT, 2-phase: P generated in-register in MFMA A-layout; writes
// normalized gat_att once; accumulates P @ WhT -> gout hi/lo (concat layout).
// ---------------------------------------------------------------------------
__global__ __launch_bounds__(256, 2) void gat_k(
    const float* __restrict__ si, const float* __restrict__ sj,
    const float* __restrict__ sjm, const float* __restrict__ irs,
    const unsigned short* __restrict__ WhTh, const unsigned short* __restrict__ WhTl,
    float* __restrict__ att, unsigned short* __restrict__ gouth,
    unsigned short* __restrict__ goutl)
{
    constexpr int BBUF = 64 * 32;
    __shared__ __align__(16) unsigned short SMg[4 * BBUF];
    unsigned short* const Bh_s = SMg;
    unsigned short* const Bl_s = SMg + 2 * BBUF;

    const int z = blockIdx.z;          // hb, h-major
    const int row0 = blockIdx.x * 128;
    const int t = threadIdx.x, lane = t & 63, wid = t >> 6;
    const int fr = lane & 15, g = lane >> 4, fk = g * 8;
    const int wrow = wid * 32;
    const int hh = z >> 4, bb = z & 15;
    const int rsub = lane >> 2, cbyt = (lane & 3) * 16;

    float siv[2], mr[2], inv[2];
    #pragma unroll
    for (int mf = 0; mf < 2; ++mf) {
        const int r = row0 + wrow + mf * 16 + fr;
        const float s = si[(size_t)hh * Nrows + bb * 1024 + r];
        siv[mf] = s;
        mr[mf] = lrelu(s + sjm[z]);
        inv[mf] = irs[(size_t)z * 1024 + r];
    }
    f32x4 acc[2][4] = {};
    const unsigned short* WhTh_z = WhTh + (size_t)z * 64 * 1024;
    const unsigned short* WhTl_z = WhTl + (size_t)z * 64 * 1024;
    const float* sjz = sj + (size_t)z * 1024;
    float* attz = att + ((size_t)z * 1024 + row0) * 1024;

    auto stageB = [&](int j0, int pp) {
        const int r = wid * 16;
        const size_t gb = ((size_t)(r + rsub) * 1024 + j0) * 2 + cbyt;
        gll16((const char*)WhTh_z + gb, (char*)(Bh_s + pp * BBUF) + (size_t)r * 64);
        gll16((const char*)WhTl_z + gb, (char*)(Bl_s + pp * BBUF) + (size_t)r * 64);
    };

    stageB(0, 0);
    __syncthreads();
    int p = 0;
    for (int kt = 0; kt < 32; ++kt) {
        const int j0 = kt * 32;
        if (kt < 31) stageB(j0 + 32, p ^ 1);
        bf16x8 ph[2], pl[2];
        #pragma unroll
        for (int mf = 0; mf < 2; ++mf) {
            const float4 s0 = *(const float4*)(sjz + j0 + fk);
            const float4 s1 = *(const float4*)(sjz + j0 + fk + 4);
            float pr[8];
            pr[0] = __expf(lrelu(siv[mf] + s0.x) - mr[mf]) * inv[mf];
            pr[1] = __expf(lrelu(siv[mf] + s0.y) - mr[mf]) * inv[mf];
            pr[2] = __expf(lrelu(siv[mf] + s0.z) - mr[mf]) * inv[mf];
            pr[3] = __expf(lrelu(siv[mf] + s0.w) - mr[mf]) * inv[mf];
            pr[4] = __expf(lrelu(siv[mf] + s1.x) - mr[mf]) * inv[mf];
            pr[5] = __expf(lrelu(siv[mf] + s1.y) - mr[mf]) * inv[mf];
            pr[6] = __expf(lrelu(siv[mf] + s1.z) - mr[mf]) * inv[mf];
            pr[7] = __expf(lrelu(siv[mf] + s1.w) - mr[mf]) * inv[mf];
            float* ap = attz + (size_t)(wrow + mf * 16 + fr) * 1024 + j0 + fk;
            *(float4*)ap       = make_float4(pr[0], pr[1], pr[2], pr[3]);
            *(float4*)(ap + 4) = make_float4(pr[4], pr[5], pr[6], pr[7]);
            union { unsigned u[4]; bf16x8 v; } uh, ul;
            split2(pr[0], pr[1], uh.u[0], ul.u[0]);
            split2(pr[2], pr[3], uh.u[1], ul.u[1]);
            split2(pr[4], pr[5], uh.u[2], ul.u[2]);
            split2(pr[6], pr[7], uh.u[3], ul.u[3]);
            ph[mf] = uh.v; pl[mf] = ul.v;
        }
        #pragma unroll
        for (int nf = 0; nf < 4; ++nf) {
            const int off = p * BBUF + (nf * 16 + fr) * 32 + fk;
            const bf16x8 bh = *(const bf16x8*)(Bh_s + off);
            const bf16x8 bl = *(const bf16x8*)(Bl_s + off);
            #pragma unroll
            for (int mf = 0; mf < 2; ++mf) {
                acc[mf][nf] = __builtin_amdgcn_mfma_f32_16x16x32_bf16(ph[mf], bh, acc[mf][nf], 0, 0, 0);
                acc[mf][nf] = __builtin_amdgcn_mfma_f32_16x16x32_bf16(pl[mf], bh, acc[mf][nf], 0, 0, 0);
                acc[mf][nf] = __builtin_amdgcn_mfma_f32_16x16x32_bf16(ph[mf], bl, acc[mf][nf], 0, 0, 0);
            }
        }
        __syncthreads();
        p ^= 1;
    }
    #pragma unroll
    for (int mf = 0; mf < 2; ++mf) {
        #pragma unroll
        for (int i = 0; i < 4; ++i) {
            const int row_l = wrow + mf * 16 + g * 4 + i;
            const size_t base = ((size_t)bb * 1024 + row0 + row_l) * 256 + hh * 64 + fr;
            #pragma unroll
            for (int nf = 0; nf < 4; ++nf) {
                unsigned short hh16, ll16; split1(acc[mf][nf][i], hh16, ll16);
                gouth[base + nf * 16] = hh16;
                goutl[base + nf * 16] = ll16;
            }
        }
    }
}

// ---------------------------------------------------------------------------
// PV with fused softmax, 2-phase: normalize raw scores in place -> t_att,
// t_out = p @ V.  BM=64, BN=256, grid (16,1,16).
// ---------------------------------------------------------------------------
__global__ __launch_bounds__(256, 2) void pv_k(
    float* __restrict__ scores, const float* __restrict__ mrow,
    const float* __restrict__ invs,
    const unsigned short* __restrict__ VTh, const unsigned short* __restrict__ VTl,
    float* __restrict__ tout)
{
    constexpr int ABUF = 64 * 32, BBUF = 256 * 32;
    __shared__ __align__(16) unsigned short SMp[4 * ABUF + 4 * BBUF];  // 80 KB
    unsigned short* const Ah_s = SMp;
    unsigned short* const Al_s = SMp + 2 * ABUF;
    unsigned short* const Bh_s = SMp + 4 * ABUF;
    unsigned short* const Bl_s = SMp + 4 * ABUF + 2 * BBUF;

    const int z = blockIdx.z;
    const int row0 = blockIdx.x * 64;
    const int t = threadIdx.x, lane = t & 63, wid = t >> 6;
    const int fr = lane & 15, g = lane >> 4, fk = g * 8;
    const int rsub = lane >> 2, cbyt = (lane & 3) * 16;

    float* sc = scores + ((size_t)z * Lc + row0) * Lc;
    const unsigned short* VTh_z = VTh + (size_t)z * HDc * Lc;
    const unsigned short* VTl_z = VTl + (size_t)z * HDc * Lc;

    const int ar = t >> 2, cq = (t & 3) * 8;
    const float m_  = mrow[(size_t)z * Lc + row0 + ar];
    const float iv_ = invs[(size_t)z * Lc + row0 + ar];

    f32x4 acc[4][4] = {};

    auto stageB = [&](int k0, int pp) {
        #pragma unroll
        for (int q = 0; q < 4; ++q) {
            const int r = q * 64 + wid * 16;
            const size_t gb = ((size_t)(r + rsub) * Lc + k0) * 2 + cbyt;
            gll16((const char*)VTh_z + gb, (char*)(Bh_s + pp * BBUF) + (size_t)r * 64);
            gll16((const char*)VTl_z + gb, (char*)(Bl_s + pp * BBUF) + (size_t)r * 64);
        }
    };
    auto stageA = [&](int k0, int pp) {
        float* srcS = sc + (size_t)ar * Lc + k0 + cq;
        const float4 v0 = ((const float4*)srcS)[0];
        const float4 v1 = ((const float4*)srcS)[1];
        float pr[8];
        pr[0] = __expf(v0.x - m_) * iv_; pr[1] = __expf(v0.y - m_) * iv_;
        pr[2] = __expf(v0.z - m_) * iv_; pr[3] = __expf(v0.w - m_) * iv_;
        pr[4] = __expf(v1.x - m_) * iv_; pr[5] = __expf(v1.y - m_) * iv_;
        pr[6] = __expf(v1.z - m_) * iv_; pr[7] = __expf(v1.w - m_) * iv_;
        ((float4*)srcS)[0] = make_float4(pr[0], pr[1], pr[2], pr[3]);
        ((float4*)srcS)[1] = make_float4(pr[4], pr[5], pr[6], pr[7]);
        unsigned hu[4], lu[4];
        split2(pr[0], pr[1], hu[0], lu[0]); split2(pr[2], pr[3], hu[1], lu[1]);
        split2(pr[4], pr[5], hu[2], lu[2]); split2(pr[6], pr[7], hu[3], lu[3]);
        *(uint4*)(Ah_s + pp * ABUF + ar * 32 + cq) = make_uint4(hu[0], hu[1], hu[2], hu[3]);
        *(uint4*)(Al_s + pp * ABUF + ar * 32 + cq) = make_uint4(lu[0], lu[1], lu[2], lu[3]);
    };

    stageB(0, 0);
    stageA(0, 0);
    __syncthreads();
    int p = 0;
    for (int kt = 0; kt < 32; ++kt) {
        bf16x8 ah[4], al[4];
        #pragma unroll
        for (int mf = 0; mf < 4; ++mf) {
            const int off = p * ABUF + (mf * 16 + fr) * 32 + fk;
            ah[mf] = *(const bf16x8*)(Ah_s + off);
            al[mf] = *(const bf16x8*)(Al_s + off);
        }
        if (kt < 31) { stageB((kt + 1) * 32, p ^ 1); stageA((kt + 1) * 32, p ^ 1); }
        #pragma unroll
        for (int nf = 0; nf < 4; ++nf) {
            const int off = p * BBUF + (wid * 64 + nf * 16 + fr) * 32 + fk;
            const bf16x8 bh = *(const bf16x8*)(Bh_s + off);
            const bf16x8 bl = *(const bf16x8*)(Bl_s + off);
            #pragma unroll
            for (int mf = 0; mf < 4; ++mf) {
                acc[mf][nf] = __builtin_amdgcn_mfma_f32_16x16x32_bf16(ah[mf], bh, acc[mf][nf], 0, 0, 0);
                acc[mf][nf] = __builtin_amdgcn_mfma_f32_16x16x32_bf16(al[mf], bh, acc[mf][nf], 0, 0, 0);
                acc[mf][nf] = __builtin_amdgcn_mfma_f32_16x16x32_bf16(ah[mf], bl, acc[mf][nf], 0, 0, 0);
            }
        }
        __syncthreads();
        p ^= 1;
    }
    #pragma unroll
    for (int mf = 0; mf < 4; ++mf) {
        #pragma unroll
        for (int i = 0; i < 4; ++i) {
            const size_t row = (size_t)row0 + mf * 16 + g * 4 + i;
            float* cp = tout + ((size_t)z * Lc + row) * HDc + wid * 64 + fr;
            #pragma unroll
            for (int nf = 0; nf < 4; ++nf) cp[nf * 16] = acc[mf][nf][i];
        }
    }
}

// combine 16 partial stats per row -> mrow, invs
__global__ __launch_bounds__(256) void rstat_k(const float* __restrict__ ps,
                                               float* __restrict__ mrow,
                                               float* __restrict__ invs)
{
    const int idx = blockIdx.x * 256 + threadIdx.x;
    const int b = idx >> 10, row = idx & 1023;
    float m = -1e30f, s = 0.f;
    #pragma unroll
    for (int ty = 0; ty < 16; ++ty) {
        const float2 pp = *(const float2*)(ps + (((size_t)b * 16 + ty) * Lc + row) * 2);
        const float nm = fmaxf(m, pp.x);
        s = s * __expf(m - nm) + pp.y * __expf(pp.x - nm);
        m = nm;
    }
    mrow[idx] = m;
    invs[idx] = 1.0f / s;
}

// 32x32 transpose + hi/lo split helper
__device__ __forceinline__ void tr32(const float* src, unsigned short* dh,
                                     unsigned short* dl, int R, int C,
                                     int r0, int c0, float (*tile)[33], int t)
{
    const int tc = t & 31, tr = t >> 5;
    #pragma unroll
    for (int rr = 0; rr < 32; rr += 8)
        tile[tr + rr][tc] = src[(size_t)(r0 + tr + rr) * C + c0 + tc];
    __syncthreads();
    #pragma unroll
    for (int rr = 0; rr < 32; rr += 8) {
        unsigned short h, l; split1(tile[tc][tr + rr], h, l);
        const size_t o = (size_t)(c0 + tr + rr) * R + r0 + tc;
        dh[o] = h; dl[o] = l;
    }
}

// all weight transposes + bias concat in one launch
__global__ __launch_bounds__(256) void prep_k(
    const float* __restrict__ W, const float* __restrict__ Wq,
    const float* __restrict__ Wk, const float* __restrict__ Wv,
    const float* __restrict__ Wfc, const float* __restrict__ bq,
    const float* __restrict__ bk, const float* __restrict__ bv,
    unsigned short* __restrict__ WTh, unsigned short* __restrict__ WTl,
    unsigned short* __restrict__ Wch, unsigned short* __restrict__ Wcl,
    unsigned short* __restrict__ WfcTh, unsigned short* __restrict__ WfcTl,
    float* __restrict__ bcat)
{
    __shared__ float tile[32][33];
    const int bx = blockIdx.x, by = blockIdx.y, t = threadIdx.x;
    if (by == 0) {
        if (bx >= 32) return;
        const int h = bx >> 3, tl = bx & 7;
        tr32(W + (size_t)h * Fc * Dc, WTh + (size_t)h * Dc * Fc,
             WTl + (size_t)h * Dc * Fc, Fc, Dc, (tl >> 1) * 32, (tl & 1) * 32, tile, t);
    } else if (by <= 3) {
        const float* s = (by == 1) ? Wq : (by == 2) ? Wk : Wv;
        const size_t off = (size_t)(by - 1) * HDc * HDc;
        tr32(s, Wch + off, Wcl + off, HDc, HDc, (bx >> 3) * 32, (bx & 7) * 32, tile, t);
    } else {
        if (bx < 16) {
            tr32(Wfc, WfcTh, WfcTl, HDc, Dc, (bx >> 1) * 32, (bx & 1) * 32, tile, t);
        } else if (bx == 16) {
            bcat[t] = bq[t]; bcat[256 + t] = bk[t]; bcat[512 + t] = bv[t];
        }
    }
}

__global__ __launch_bounds__(256) void sjmax_k(const float* __restrict__ sj,
                                               float* __restrict__ out)
{
    __shared__ float red[4];
    const int hb = blockIdx.x;
    const int t = threadIdx.x;
    const float4 v = ((const float4*)(sj + (size_t)hb * Lc))[t];
    float m = fmaxf(fmaxf(v.x, v.y), fmaxf(v.z, v.w));
    #pragma unroll
    for (int ofs = 32; ofs >= 1; ofs >>= 1) m = fmaxf(m, __shfl_xor(m, ofs, 64));
    if ((t & 63) == 0) red[t >> 6] = m;
    __syncthreads();
    if (t == 0) out[hb] = fmaxf(fmaxf(red[0], red[1]), fmaxf(red[2], red[3]));
}

__global__ __launch_bounds__(256) void rsum_k(const float* __restrict__ si,
                                              const float* __restrict__ sj,
                                              const float* __restrict__ sjm,
                                              float* __restrict__ irs)
{
    __shared__ __align__(16) float sjs[Lc];
    __shared__ float red[4];
    const int z = blockIdx.y, c0 = blockIdx.x * 16;
    const int t = threadIdx.x;
    ((float4*)sjs)[t] = ((const float4*)(sj + (size_t)z * Lc))[t];
    const float smax = sjm[z];
    __syncthreads();
    const int hh = z >> 4, bb = z & 15;
    const float4 v = ((const float4*)sjs)[t];
    for (int r = 0; r < 16; ++r) {
        const int row = c0 + r;
        const float sv = si[(size_t)hh * Nrows + bb * 1024 + row];
        const float m = lrelu(sv + smax);
        float s = __expf(lrelu(sv + v.x) - m) + __expf(lrelu(sv + v.y) - m)
                + __expf(lrelu(sv + v.z) - m) + __expf(lrelu(sv + v.w) - m);
        #pragma unroll
        for (int ofs = 32; ofs >= 1; ofs >>= 1) s += __shfl_xor(s, ofs, 64);
        if ((t & 63) == 0) red[t >> 6] = s;
        __syncthreads();
        if (t == 0) irs[(size_t)z * Lc + row] = 1.0f / (red[0] + red[1] + red[2] + red[3]);
        __syncthreads();
    }
}

extern "C" void kernel_launch(void* const* d_in, const int* in_sizes, int n_in,
                              void* d_out, int out_size, void* d_ws, size_t ws_size,
                              hipStream_t stream)
{
    const float* x   = (const float*)d_in[0];
    const float* W   = (const float*)d_in[1];
    const float* a1  = (const float*)d_in[2];
    const float* a2  = (const float*)d_in[3];
    const float* Wq  = (const float*)d_in[4];
    const float* bq  = (const float*)d_in[5];
    const float* Wk  = (const float*)d_in[6];
    const float* bk  = (const float*)d_in[7];
    const float* Wv  = (const float*)d_in[8];
    const float* bv  = (const float*)d_in[9];
    const float* Wfc = (const float*)d_in[10];
    const float* bfc = (const float*)d_in[11];

    float* outp    = (float*)d_out;
    float* gat_att = outp + (size_t)Bc * Lc * Dc;
    float* t_att   = gat_att + (size_t)Hc * Bc * Lc * Lc;
    float* t_out   = t_att + (size_t)Bc * Lc * Lc;

    constexpr size_t MB = 1024 * 1024;
    char* wsb = (char*)d_ws;
    // region 0 (0-16MB): WhT-hl -> VT-hl (WhT dead after gat_k)
    unsigned short* WhTh = (unsigned short*)wsb;
    unsigned short* WhTl = WhTh + (size_t)64 * 64 * 1024;
    unsigned short* VTh = WhTh; unsigned short* VTl = WhTl;
    // region 1 (16-32MB): gout-hl
    unsigned short* gouth = (unsigned short*)(wsb + 16 * MB);
    unsigned short* goutl = gouth + (size_t)Nrows * HDc;
    // region 2 (32-48MB): Q-hl
    unsigned short* Qh = (unsigned short*)(wsb + 32 * MB);
    unsigned short* Ql = Qh + (size_t)Nrows * HDc;
    // region 3 (48-64MB): K-hl
    unsigned short* Kh = (unsigned short*)(wsb + 48 * MB);
    unsigned short* Kl = Kh + (size_t)Nrows * HDc;
    // region 4 (64MB+): small buffers
    float* si  = (float*)(wsb + 64 * MB);
    float* sj  = si + Hc * Nrows;
    float* sjm = sj + Hc * Nrows;                     // [64]
    float* irs = sjm + 64;                            // [64][1024]
    float* pstats = irs + Hc * Nrows;                 // [16][16][1024][2]
    float* mrow = pstats + (size_t)Bc * 16 * Lc * 2;  // [16][1024]
    float* invs = mrow + Bc * Lc;
    unsigned short* WTh = (unsigned short*)(invs + Bc * Lc);  // [4][64][128]
    unsigned short* WTl = WTh + Hc * Dc * Fc;
    unsigned short* Wch = WTl + Hc * Dc * Fc;         // [768][256]
    unsigned short* Wcl = Wch + 768 * HDc;
    unsigned short* WfcTh = Wcl + 768 * HDc;          // [64][256]
    unsigned short* WfcTl = WfcTh + Dc * HDc;
    float* bcat = (float*)(WfcTl + Dc * HDc);         // [768]

    const dim3 blk(256);

    // 0. weight prep (one launch)
    prep_k<<<dim3(64, 5), blk, 0, stream>>>(W, Wq, Wk, Wv, Wfc, bq, bk, bv,
        WTh, WTl, Wch, Wcl, WfcTh, WfcTl, bcat);

    // 1. WhT-hl = (x @ W[h]^T)^T + fused si/sj  (no Wh f32 round-trip)
    mm_k<128, 64, A_F32, E_WHT><<<dim3(Nrows / 128, 1, Hc), blk, 0, stream>>>(
        x, nullptr, nullptr, WTh, WTl, nullptr, nullptr,
        WhTh, WhTl, nullptr, nullptr, nullptr, nullptr,
        Fc, Fc, Fc, 0, 0LL, (long long)Dc * Fc, 0LL, 1.f, a1, a2, si, sj, nullptr);

    // 2. GAT softmax normalizers
    sjmax_k<<<dim3(64), blk, 0, stream>>>(sj, sjm);
    rsum_k<<<dim3(Lc / 16, 64), blk, 0, stream>>>(si, sj, sjm, irs);

    // 3. fused GAT: gat_att + gout-hl
    gat_k<<<dim3(Lc / 128, 1, 64), blk, 0, stream>>>(si, sj, sjm, irs,
        WhTh, WhTl, gat_att, gouth, goutl);

    // 4. fused QKV projection (Q-hl, K-hl linear; VT-hl transposed; no V f32)
    mm_k<128, 128, A_HL, E_QKV><<<dim3(Nrows / 128, 6, 1), blk, 0, stream>>>(
        nullptr, gouth, goutl, Wch, Wcl, bcat, nullptr,
        Qh, Ql, Kh, Kl, VTh, VTl,
        HDc, HDc, HDc, HDc, 0LL, 0LL, 0LL, 1.f, nullptr, nullptr, nullptr, nullptr, nullptr);

    // 5. raw scaled scores -> t_att region + partial row stats
    mm_k<128, 128, A_HL, E_STATS><<<dim3(8, 8, Bc), blk, 0, stream>>>(
        nullptr, Qh, Ql, Kh, Kl, nullptr, t_att,
        nullptr, nullptr, nullptr, nullptr, nullptr, nullptr,
        HDc, HDc, HDc, Lc, (long long)Lc * HDc, (long long)Lc * HDc,
        (long long)Lc * Lc, 0.0625f, nullptr, nullptr, nullptr, nullptr, pstats);

    // 6. combine stats
    rstat_k<<<dim3(Nrows / 256), blk, 0, stream>>>(pstats, mrow, invs);

    // 7. PV with fused softmax (t_att normalized in place, t_out = p @ V)
    pv_k<<<dim3(16, 1, Bc), blk, 0, stream>>>(t_att, mrow, invs, VTh, VTl, t_out);

    // 8. out = temporal_out @ Wfc + bfc
    mm_k<128, 64, A_F32, E_BIAS><<<dim3(Nrows / 128, 1, 1), blk, 0, stream>>>(
        t_out, nullptr, nullptr, WfcTh, WfcTl, bfc, outp,
        nullptr, nullptr, nullptr, nullptr, nullptr, nullptr,
        HDc, HDc, HDc, Dc, 0LL, 0LL, 0LL, 1.f, nullptr, nullptr, nullptr, nullptr, nullptr);
}

// Round 6
// 249.456 us; speedup vs baseline: 6.0257x; 1.1079x over previous
//
#include <hip/hip_runtime.h>

// TemporalGAT on MI355X — round 6: XCD-chunked block swizzle (T1) on all MFMA
// kernels, sjmax/rsum folded into gat_k prologue, stage-first loop order.
// bf16 hi/lo 3-term split MFMA throughout.
// B=16, L=1024, F=128, H=4, D=64, HD=256, N=B*L=16384

constexpr int Bc = 16, Lc = 1024, Fc = 128, Hc = 4, Dc = 64, HDc = 256;
constexpr int Nrows = Bc * Lc;  // 16384
#define ALPHA_SLOPE 0.2f

typedef __attribute__((ext_vector_type(8))) short bf16x8;
typedef __attribute__((ext_vector_type(4))) float f32x4;

enum { A_F32 = 0, A_HL = 1 };
enum { E_BIAS = 1, E_WHT = 2, E_STATS = 3, E_QKV = 4 };

__device__ __forceinline__ float lrelu(float x) { return x > 0.f ? x : ALPHA_SLOPE * x; }

__device__ __forceinline__ void gll16(const void* g, void* l) {
    __builtin_amdgcn_global_load_lds(
        (const __attribute__((address_space(1))) void*)g,
        (__attribute__((address_space(3))) void*)l, 16, 0, 0);
}

__device__ __forceinline__ void split2(float a, float b, unsigned& h, unsigned& l) {
    const unsigned ua = __float_as_uint(a), ub = __float_as_uint(b);
    h = __byte_perm(ua, ub, 0x7632);
    const float la = a - __uint_as_float(ua & 0xffff0000u);
    const float lb = b - __uint_as_float(ub & 0xffff0000u);
    l = __byte_perm(__float_as_uint(la), __float_as_uint(lb), 0x7632);
}
__device__ __forceinline__ void split1(float v, unsigned short& h, unsigned short& l) {
    const unsigned u = __float_as_uint(v);
    h = (unsigned short)(u >> 16);
    const float lf = v - __uint_as_float(u & 0xffff0000u);
    l = (unsigned short)(__float_as_uint(lf) >> 16);
}

// ---------------------------------------------------------------------------
// MFMA GEMM, 2-phase double-buffered, XCD-swizzled: C = A[M,K] @ Bt[N,K]^T.
// ---------------------------------------------------------------------------
template <int BM, int BN, int AMODE, int EPI>
__global__ __launch_bounds__(256, 2) void mm_k(
    const float* __restrict__ Af,
    const unsigned short* __restrict__ Agh, const unsigned short* __restrict__ Agl,
    const unsigned short* __restrict__ Bgh, const unsigned short* __restrict__ Bgl,
    const float* __restrict__ bias,
    float* __restrict__ Cf,
    unsigned short* __restrict__ Ch, unsigned short* __restrict__ Cl,
    unsigned short* __restrict__ Ch2, unsigned short* __restrict__ Cl2,
    unsigned short* __restrict__ Ch3, unsigned short* __restrict__ Cl3,
    int K, int lda, int ldb, int ldc,
    long long zA, long long zB, long long zC, float alpha,
    const float* __restrict__ a1, const float* __restrict__ a2,
    float* __restrict__ si, float* __restrict__ sj, float* __restrict__ pstats)
{
    constexpr int ABUF = BM * 32, BBUF = BN * 32;
    __shared__ __align__(16) unsigned short SM[4 * ABUF + 4 * BBUF];
    unsigned short* const Ah_s = SM;
    unsigned short* const Al_s = SM + 2 * ABUF;
    unsigned short* const Bh_s = SM + 4 * ABUF;
    unsigned short* const Bl_s = SM + 4 * ABUF + 2 * BBUF;

    // XCD-chunked bijective block remap (grid size % 8 == 0 for all users)
    const int nbx = gridDim.x, nby = gridDim.y;
    int lin = blockIdx.x + nbx * (blockIdx.y + nby * blockIdx.z);
    const int ntot = nbx * nby * gridDim.z;
    lin = (lin & 7) * (ntot >> 3) + (lin >> 3);
    const int bx = lin % nbx;
    const int rem = lin / nbx;
    const int by = rem % nby;
    const int z  = rem / nby;

    if (AMODE == A_F32) { Af += (size_t)z * zA; }
    else { Agh += (size_t)z * zA; Agl += (size_t)z * zA; }
    Bgh += (size_t)z * zB; Bgl += (size_t)z * zB;
    if (Cf) Cf += (size_t)z * zC;

    constexpr int WC = (BN == 64) ? 1 : 2, WR = 4 / WC;
    constexpr int WM = BM / WR, WN = BN / WC, MF = WM / 16, NF = WN / 16;
    const int row0 = bx * BM, col0 = by * BN;
    const int t = threadIdx.x, lane = t & 63, wid = t >> 6;
    const int fr = lane & 15, g = lane >> 4, fk = g * 8;
    const int wrow = (wid / WC) * WM, wcol = (wid % WC) * WN;
    const int rsub = lane >> 2, cbyt = (lane & 3) * 16;

    f32x4 acc[MF][NF] = {};

    auto stageB = [&](int k0, int pp) {
        #pragma unroll
        for (int q = 0; q < BN / 64; ++q) {
            const int r = wid * (BN / 4) + q * 16;
            const size_t gb = ((size_t)(col0 + r + rsub) * ldb + k0) * 2 + cbyt;
            gll16((const char*)Bgh + gb, (char*)(Bh_s + pp * BBUF) + (size_t)r * 64);
            gll16((const char*)Bgl + gb, (char*)(Bl_s + pp * BBUF) + (size_t)r * 64);
        }
    };
    auto stageA = [&](int k0, int pp) {
        if (AMODE == A_HL) {
            #pragma unroll
            for (int q = 0; q < BM / 64; ++q) {
                const int r = wid * (BM / 4) + q * 16;
                const size_t gb = ((size_t)(row0 + r + rsub) * lda + k0) * 2 + cbyt;
                gll16((const char*)Agh + gb, (char*)(Ah_s + pp * ABUF) + (size_t)r * 64);
                gll16((const char*)Agl + gb, (char*)(Al_s + pp * ABUF) + (size_t)r * 64);
            }
        } else {
            // f32 -> hi/lo reg-convert staging (BM == 128)
            const int r = t >> 1, h2 = t & 1;
            const float* srcA = Af + (size_t)(row0 + r) * lda + k0 + h2 * 16;
            const float4 v0 = ((const float4*)srcA)[0];
            const float4 v1 = ((const float4*)srcA)[1];
            const float4 v2 = ((const float4*)srcA)[2];
            const float4 v3 = ((const float4*)srcA)[3];
            unsigned hu[8], lu[8];
            split2(v0.x, v0.y, hu[0], lu[0]); split2(v0.z, v0.w, hu[1], lu[1]);
            split2(v1.x, v1.y, hu[2], lu[2]); split2(v1.z, v1.w, hu[3], lu[3]);
            split2(v2.x, v2.y, hu[4], lu[4]); split2(v2.z, v2.w, hu[5], lu[5]);
            split2(v3.x, v3.y, hu[6], lu[6]); split2(v3.z, v3.w, hu[7], lu[7]);
            uint4* dh = (uint4*)(Ah_s + pp * ABUF + r * 32 + h2 * 16);
            dh[0] = make_uint4(hu[0], hu[1], hu[2], hu[3]);
            dh[1] = make_uint4(hu[4], hu[5], hu[6], hu[7]);
            uint4* dl = (uint4*)(Al_s + pp * ABUF + r * 32 + h2 * 16);
            dl[0] = make_uint4(lu[0], lu[1], lu[2], lu[3]);
            dl[1] = make_uint4(lu[4], lu[5], lu[6], lu[7]);
        }
    };

    stageB(0, 0);
    stageA(0, 0);
    __syncthreads();

    const int NT = K / 32;
    int p = 0;
    for (int kt = 0; kt < NT; ++kt) {
        if (kt + 1 < NT) { stageB((kt + 1) * 32, p ^ 1); stageA((kt + 1) * 32, p ^ 1); }
        bf16x8 ah[MF], al[MF];
        #pragma unroll
        for (int mf = 0; mf < MF; ++mf) {
            const int off = p * ABUF + (wrow + mf * 16 + fr) * 32 + fk;
            ah[mf] = *(const bf16x8*)(Ah_s + off);
            al[mf] = *(const bf16x8*)(Al_s + off);
        }
        #pragma unroll
        for (int nf = 0; nf < NF; ++nf) {
            const int off = p * BBUF + (wcol + nf * 16 + fr) * 32 + fk;
            const bf16x8 bh = *(const bf16x8*)(Bh_s + off);
            const bf16x8 bl = *(const bf16x8*)(Bl_s + off);
            #pragma unroll
            for (int mf = 0; mf < MF; ++mf) {
                acc[mf][nf] = __builtin_amdgcn_mfma_f32_16x16x32_bf16(ah[mf], bh, acc[mf][nf], 0, 0, 0);
                acc[mf][nf] = __builtin_amdgcn_mfma_f32_16x16x32_bf16(al[mf], bh, acc[mf][nf], 0, 0, 0);
                acc[mf][nf] = __builtin_amdgcn_mfma_f32_16x16x32_bf16(ah[mf], bl, acc[mf][nf], 0, 0, 0);
            }
        }
        __syncthreads();
        p ^= 1;
    }

    // ---- epilogues (C/D layout: col = lane&15, row = (lane>>4)*4 + i [m89])
    float* ts = (float*)SM;  // transpose scratch overlays staging (post-barrier)

    if (EPI == E_BIAS || EPI == E_STATS) {
        float bv_[NF];
        if (EPI == E_BIAS) {
            #pragma unroll
            for (int nf = 0; nf < NF; ++nf) bv_[nf] = bias[col0 + wcol + nf * 16 + fr];
        }
        #pragma unroll
        for (int mf = 0; mf < MF; ++mf) {
            #pragma unroll
            for (int i = 0; i < 4; ++i) {
                const size_t row = (size_t)row0 + wrow + mf * 16 + g * 4 + i;
                const size_t co = row * ldc + col0 + wcol + fr;
                #pragma unroll
                for (int nf = 0; nf < NF; ++nf) {
                    float v = acc[mf][nf][i];
                    if (EPI == E_STATS) v *= alpha;
                    if (EPI == E_BIAS)  v += bv_[nf];
                    acc[mf][nf][i] = v;
                    Cf[co + nf * 16] = v;
                }
            }
        }
        if (EPI == E_STATS) {
            const int ty = by * WC + (wid % WC);
            #pragma unroll
            for (int mf = 0; mf < MF; ++mf) {
                #pragma unroll
                for (int i = 0; i < 4; ++i) {
                    float m = acc[mf][0][i], s;
                    #pragma unroll
                    for (int nf = 1; nf < NF; ++nf) m = fmaxf(m, acc[mf][nf][i]);
                    s = 0.f;
                    #pragma unroll
                    for (int nf = 0; nf < NF; ++nf) s += __expf(acc[mf][nf][i] - m);
                    #pragma unroll
                    for (int ofs = 1; ofs < 16; ofs <<= 1) {
                        const float om = __shfl_xor(m, ofs, 64);
                        const float os = __shfl_xor(s, ofs, 64);
                        const float nm = fmaxf(m, om);
                        s = s * __expf(m - nm) + os * __expf(om - nm);
                        m = nm;
                    }
                    if (fr == 0) {
                        const size_t row = (size_t)row0 + wrow + mf * 16 + g * 4 + i;
                        float* pp = pstats + (((size_t)z * 16 + ty) * Lc + row) * 2;
                        pp[0] = m; pp[1] = s;
                    }
                }
            }
        }
    }

    if (EPI == E_QKV) {
        float bv_[NF];
        #pragma unroll
        for (int nf = 0; nf < NF; ++nf) bv_[nf] = bias[col0 + wcol + nf * 16 + fr];
        #pragma unroll
        for (int mf = 0; mf < MF; ++mf)
            #pragma unroll
            for (int i = 0; i < 4; ++i)
                #pragma unroll
                for (int nf = 0; nf < NF; ++nf) acc[mf][nf][i] += bv_[nf];

        if (col0 < 512) {
            // Q (cols 0-255) / K (256-511): linear hi/lo write
            unsigned short* dH = (col0 < 256) ? Ch : Ch2;
            unsigned short* dL = (col0 < 256) ? Cl : Cl2;
            const int cl0 = col0 & 255;
            #pragma unroll
            for (int mf = 0; mf < MF; ++mf) {
                #pragma unroll
                for (int i = 0; i < 4; ++i) {
                    const size_t row = (size_t)row0 + wrow + mf * 16 + g * 4 + i;
                    const size_t co = row * ldc + cl0 + wcol + fr;
                    #pragma unroll
                    for (int nf = 0; nf < NF; ++nf) {
                        unsigned short hh16, ll16; split1(acc[mf][nf][i], hh16, ll16);
                        dH[co + nf * 16] = hh16; dL[co + nf * 16] = ll16;
                    }
                }
            }
        } else {
            // V (cols 512-767): transposed hi/lo write -> VT[b][d][l]
            const int bq_ = row0 >> 10, lg0 = row0 & 1023;
            #pragma unroll
            for (int hf = 0; hf < 2; ++hf) {
                if ((wid & 1) == hf) {
                    #pragma unroll
                    for (int mf = 0; mf < MF; ++mf)
                        #pragma unroll
                        for (int i = 0; i < 4; ++i) {
                            const int rr = wrow + mf * 16 + g * 4 + i;
                            #pragma unroll
                            for (int nf = 0; nf < NF; ++nf)
                                ts[rr * 65 + nf * 16 + fr] = acc[mf][nf][i];
                        }
                }
                __syncthreads();
                const int l = t & 127, db = (t >> 7) * 32;
                #pragma unroll
                for (int dd = 0; dd < 32; ++dd) {
                    const int dl = db + dd;
                    unsigned short hh16, ll16; split1(ts[l * 65 + dl], hh16, ll16);
                    const size_t o = ((size_t)bq_ * 256 + (col0 - 512) + hf * 64 + dl) * 1024 + lg0 + l;
                    Ch3[o] = hh16; Cl3[o] = ll16;
                }
                __syncthreads();
            }
        }
    }

    if (EPI == E_WHT) {
        // si/sj fused reductions (BN==64: each wave spans all 64 cols)
        float a1v[NF], a2v[NF];
        #pragma unroll
        for (int nf = 0; nf < NF; ++nf) {
            a1v[nf] = a1[(size_t)z * Dc + nf * 16 + fr];
            a2v[nf] = a2[(size_t)z * Dc + nf * 16 + fr];
        }
        #pragma unroll
        for (int mf = 0; mf < MF; ++mf) {
            #pragma unroll
            for (int i = 0; i < 4; ++i) {
                float p1 = 0.f, p2 = 0.f;
                #pragma unroll
                for (int nf = 0; nf < NF; ++nf) {
                    p1 = fmaf(acc[mf][nf][i], a1v[nf], p1);
                    p2 = fmaf(acc[mf][nf][i], a2v[nf], p2);
                }
                #pragma unroll
                for (int ofs = 1; ofs < 16; ofs <<= 1) {
                    p1 += __shfl_xor(p1, ofs, 64);
                    p2 += __shfl_xor(p2, ofs, 64);
                }
                if (fr == 0) {
                    const int row = row0 + wrow + mf * 16 + g * 4 + i;
                    si[(size_t)z * Nrows + row] = p1;
                    sj[(size_t)z * Nrows + row] = p2;
                }
            }
        }
        // transposed hi/lo write -> WhT[h*16+b][d][l]
        #pragma unroll
        for (int mf = 0; mf < MF; ++mf)
            #pragma unroll
            for (int i = 0; i < 4; ++i) {
                const int rr = wrow + mf * 16 + g * 4 + i;
                #pragma unroll
                for (int nf = 0; nf < NF; ++nf)
                    ts[rr * 65 + nf * 16 + fr] = acc[mf][nf][i];
            }
        __syncthreads();
        const int bq_ = row0 >> 10, lg0 = row0 & 1023;
        const int l = t & 127, db = (t >> 7) * 32;
        #pragma unroll
        for (int dd = 0; dd < 32; ++dd) {
            const int d = db + dd;
            unsigned short hh16, ll16; split1(ts[l * 65 + d], hh16, ll16);
            const size_t o = (((size_t)(z * 16 + bq_)) * 64 + d) * 1024 + lg0 + l;
            Ch[o] = hh16; Cl[o] = ll16;
        }
    }
}

// ---------------------------------------------------------------------------
// Fused GAT, 2-phase, swizzled, with in-block softmax stats (sjmax + rowsum
// folded into prologue; sj row staged in LDS once, reused by the main loop).
// ---------------------------------------------------------------------------
__global__ __launch_bounds__(256, 2) void gat_k(
    const float* __restrict__ si, const float* __restrict__ sj,
    const unsigned short* __restrict__ WhTh, const unsigned short* __restrict__ WhTl,
    float* __restrict__ att, unsigned short* __restrict__ gouth,
    unsigned short* __restrict__ goutl)
{
    constexpr int BBUF = 64 * 32;
    __shared__ __align__(16) unsigned short SMg[4 * BBUF];
    __shared__ __align__(16) float sjs[Lc];
    __shared__ float redm[4];
    unsigned short* const Bh_s = SMg;
    unsigned short* const Bl_s = SMg + 2 * BBUF;

    // XCD-chunked remap over grid (8,1,64) = 512 blocks
    int lin = blockIdx.x + 8 * blockIdx.z;
    lin = (lin & 7) * 64 + (lin >> 3);
    const int bx = lin & 7, z = lin >> 3;

    const int row0 = bx * 128;
    const int t = threadIdx.x, lane = t & 63, wid = t >> 6;
    const int fr = lane & 15, g = lane >> 4, fk = g * 8;
    const int wrow = wid * 32;
    const int hh = z >> 4, bb = z & 15;
    const int rsub = lane >> 2, cbyt = (lane & 3) * 16;

    const unsigned short* WhTh_z = WhTh + (size_t)z * 64 * 1024;
    const unsigned short* WhTl_z = WhTl + (size_t)z * 64 * 1024;
    const float* sjz = sj + (size_t)z * 1024;
    float* attz = att + ((size_t)z * 1024 + row0) * 1024;

    auto stageB = [&](int j0, int pp) {
        const int r = wid * 16;
        const size_t gb = ((size_t)(r + rsub) * 1024 + j0) * 2 + cbyt;
        gll16((const char*)WhTh_z + gb, (char*)(Bh_s + pp * BBUF) + (size_t)r * 64);
        gll16((const char*)WhTl_z + gb, (char*)(Bl_s + pp * BBUF) + (size_t)r * 64);
    };

    stageB(0, 0);
    ((float4*)sjs)[t] = ((const float4*)sjz)[t];
    __syncthreads();  // sjs ready (also drains buf0 gll — harmless)

    // block-wide max of sj row
    {
        const float4 v = ((const float4*)sjs)[t];
        float m4 = fmaxf(fmaxf(v.x, v.y), fmaxf(v.z, v.w));
        #pragma unroll
        for (int ofs = 32; ofs >= 1; ofs >>= 1) m4 = fmaxf(m4, __shfl_xor(m4, ofs, 64));
        if (lane == 0) redm[wid] = m4;
    }
    __syncthreads();
    const float smax = fmaxf(fmaxf(redm[0], redm[1]), fmaxf(redm[2], redm[3]));

    // per-row stats for this thread's 2 rows (4 lanes g=0..3 split the 1024 cols)
    float siv[2], mr[2], inv[2];
    #pragma unroll
    for (int mf = 0; mf < 2; ++mf) {
        const int r = row0 + wrow + mf * 16 + fr;
        const float sv = si[(size_t)hh * Nrows + bb * 1024 + r];
        siv[mf] = sv;
        mr[mf] = lrelu(sv + smax);
        float s = 0.f;
        const float4* sp = (const float4*)sjs + g * 64;
        #pragma unroll 4
        for (int c = 0; c < 64; ++c) {
            const float4 w = sp[c];
            s += __expf(lrelu(sv + w.x) - mr[mf]) + __expf(lrelu(sv + w.y) - mr[mf])
               + __expf(lrelu(sv + w.z) - mr[mf]) + __expf(lrelu(sv + w.w) - mr[mf]);
        }
        s += __shfl_xor(s, 16, 64);
        s += __shfl_xor(s, 32, 64);
        inv[mf] = 1.0f / s;
    }

    f32x4 acc[2][4] = {};
    int p = 0;
    for (int kt = 0; kt < 32; ++kt) {
        const int j0 = kt * 32;
        if (kt < 31) stageB(j0 + 32, p ^ 1);
        bf16x8 ph[2], pl[2];
        #pragma unroll
        for (int mf = 0; mf < 2; ++mf) {
            const float4 s0 = ((const float4*)sjs)[(j0 >> 2) + g * 2];
            const float4 s1 = ((const float4*)sjs)[(j0 >> 2) + g * 2 + 1];
            float pr[8];
            pr[0] = __expf(lrelu(siv[mf] + s0.x) - mr[mf]) * inv[mf];
            pr[1] = __expf(lrelu(siv[mf] + s0.y) - mr[mf]) * inv[mf];
            pr[2] = __expf(lrelu(siv[mf] + s0.z) - mr[mf]) * inv[mf];
            pr[3] = __expf(lrelu(siv[mf] + s0.w) - mr[mf]) * inv[mf];
            pr[4] = __expf(lrelu(siv[mf] + s1.x) - mr[mf]) * inv[mf];
            pr[5] = __expf(lrelu(siv[mf] + s1.y) - mr[mf]) * inv[mf];
            pr[6] = __expf(lrelu(siv[mf] + s1.z) - mr[mf]) * inv[mf];
            pr[7] = __expf(lrelu(siv[mf] + s1.w) - mr[mf]) * inv[mf];
            float* ap = attz + (size_t)(wrow + mf * 16 + fr) * 1024 + j0 + fk;
            *(float4*)ap       = make_float4(pr[0], pr[1], pr[2], pr[3]);
            *(float4*)(ap + 4) = make_float4(pr[4], pr[5], pr[6], pr[7]);
            union { unsigned u[4]; bf16x8 v; } uh, ul;
            split2(pr[0], pr[1], uh.u[0], ul.u[0]);
            split2(pr[2], pr[3], uh.u[1], ul.u[1]);
            split2(pr[4], pr[5], uh.u[2], ul.u[2]);
            split2(pr[6], pr[7], uh.u[3], ul.u[3]);
            ph[mf] = uh.v; pl[mf] = ul.v;
        }
        #pragma unroll
        for (int nf = 0; nf < 4; ++nf) {
            const int off = p * BBUF + (nf * 16 + fr) * 32 + fk;
            const bf16x8 bh = *(const bf16x8*)(Bh_s + off);
            const bf16x8 bl = *(const bf16x8*)(Bl_s + off);
            #pragma unroll
            for (int mf = 0; mf < 2; ++mf) {
                acc[mf][nf] = __builtin_amdgcn_mfma_f32_16x16x32_bf16(ph[mf], bh, acc[mf][nf], 0, 0, 0);
                acc[mf][nf] = __builtin_amdgcn_mfma_f32_16x16x32_bf16(pl[mf], bh, acc[mf][nf], 0, 0, 0);
                acc[mf][nf] = __builtin_amdgcn_mfma_f32_16x16x32_bf16(ph[mf], bl, acc[mf][nf], 0, 0, 0);
            }
        }
        __syncthreads();
        p ^= 1;
    }
    #pragma unroll
    for (int mf = 0; mf < 2; ++mf) {
        #pragma unroll
        for (int i = 0; i < 4; ++i) {
            const int row_l = wrow + mf * 16 + g * 4 + i;
            const size_t base = ((size_t)bb * 1024 + row0 + row_l) * 256 + hh * 64 + fr;
            #pragma unroll
            for (int nf = 0; nf < 4; ++nf) {
                unsigned short hh16, ll16; split1(acc[mf][nf][i], hh16, ll16);
                gouth[base + nf * 16] = hh16;
                goutl[base + nf * 16] = ll16;
            }
        }
    }
}

// ---------------------------------------------------------------------------
// PV with fused softmax, 2-phase, swizzled: normalize raw scores in place ->
// t_att, t_out = p @ V.  BM=64, BN=256, grid (16,1,16).
// ---------------------------------------------------------------------------
__global__ __launch_bounds__(256, 2) void pv_k(
    float* __restrict__ scores, const float* __restrict__ mrow,
    const float* __restrict__ invs,
    const unsigned short* __restrict__ VTh, const unsigned short* __restrict__ VTl,
    float* __restrict__ tout)
{
    constexpr int ABUF = 64 * 32, BBUF = 256 * 32;
    __shared__ __align__(16) unsigned short SMp[4 * ABUF + 4 * BBUF];  // 80 KB
    unsigned short* const Ah_s = SMp;
    unsigned short* const Al_s = SMp + 2 * ABUF;
    unsigned short* const Bh_s = SMp + 4 * ABUF;
    unsigned short* const Bl_s = SMp + 4 * ABUF + 2 * BBUF;

    // XCD-chunked remap over grid (16,1,16) = 256 blocks
    int lin = blockIdx.x + 16 * blockIdx.z;
    lin = (lin & 7) * 32 + (lin >> 3);
    const int bx = lin & 15, z = lin >> 4;

    const int row0 = bx * 64;
    const int t = threadIdx.x, lane = t & 63, wid = t >> 6;
    const int fr = lane & 15, g = lane >> 4, fk = g * 8;
    const int rsub = lane >> 2, cbyt = (lane & 3) * 16;

    float* sc = scores + ((size_t)z * Lc + row0) * Lc;
    const unsigned short* VTh_z = VTh + (size_t)z * HDc * Lc;
    const unsigned short* VTl_z = VTl + (size_t)z * HDc * Lc;

    const int ar = t >> 2, cq = (t & 3) * 8;
    const float m_  = mrow[(size_t)z * Lc + row0 + ar];
    const float iv_ = invs[(size_t)z * Lc + row0 + ar];

    f32x4 acc[4][4] = {};

    auto stageB = [&](int k0, int pp) {
        #pragma unroll
        for (int q = 0; q < 4; ++q) {
            const int r = q * 64 + wid * 16;
            const size_t gb = ((size_t)(r + rsub) * Lc + k0) * 2 + cbyt;
            gll16((const char*)VTh_z + gb, (char*)(Bh_s + pp * BBUF) + (size_t)r * 64);
            gll16((const char*)VTl_z + gb, (char*)(Bl_s + pp * BBUF) + (size_t)r * 64);
        }
    };
    auto stageA = [&](int k0, int pp) {
        float* srcS = sc + (size_t)ar * Lc + k0 + cq;
        const float4 v0 = ((const float4*)srcS)[0];
        const float4 v1 = ((const float4*)srcS)[1];
        float pr[8];
        pr[0] = __expf(v0.x - m_) * iv_; pr[1] = __expf(v0.y - m_) * iv_;
        pr[2] = __expf(v0.z - m_) * iv_; pr[3] = __expf(v0.w - m_) * iv_;
        pr[4] = __expf(v1.x - m_) * iv_; pr[5] = __expf(v1.y - m_) * iv_;
        pr[6] = __expf(v1.z - m_) * iv_; pr[7] = __expf(v1.w - m_) * iv_;
        ((float4*)srcS)[0] = make_float4(pr[0], pr[1], pr[2], pr[3]);
        ((float4*)srcS)[1] = make_float4(pr[4], pr[5], pr[6], pr[7]);
        unsigned hu[4], lu[4];
        split2(pr[0], pr[1], hu[0], lu[0]); split2(pr[2], pr[3], hu[1], lu[1]);
        split2(pr[4], pr[5], hu[2], lu[2]); split2(pr[6], pr[7], hu[3], lu[3]);
        *(uint4*)(Ah_s + pp * ABUF + ar * 32 + cq) = make_uint4(hu[0], hu[1], hu[2], hu[3]);
        *(uint4*)(Al_s + pp * ABUF + ar * 32 + cq) = make_uint4(lu[0], lu[1], lu[2], lu[3]);
    };

    stageB(0, 0);
    stageA(0, 0);
    __syncthreads();
    int p = 0;
    for (int kt = 0; kt < 32; ++kt) {
        if (kt < 31) { stageB((kt + 1) * 32, p ^ 1); stageA((kt + 1) * 32, p ^ 1); }
        bf16x8 ah[4], al[4];
        #pragma unroll
        for (int mf = 0; mf < 4; ++mf) {
            const int off = p * ABUF + (mf * 16 + fr) * 32 + fk;
            ah[mf] = *(const bf16x8*)(Ah_s + off);
            al[mf] = *(const bf16x8*)(Al_s + off);
        }
        #pragma unroll
        for (int nf = 0; nf < 4; ++nf) {
            const int off = p * BBUF + (wid * 64 + nf * 16 + fr) * 32 + fk;
            const bf16x8 bh = *(const bf16x8*)(Bh_s + off);
            const bf16x8 bl = *(const bf16x8*)(Bl_s + off);
            #pragma unroll
            for (int mf = 0; mf < 4; ++mf) {
                acc[mf][nf] = __builtin_amdgcn_mfma_f32_16x16x32_bf16(ah[mf], bh, acc[mf][nf], 0, 0, 0);
                acc[mf][nf] = __builtin_amdgcn_mfma_f32_16x16x32_bf16(al[mf], bh, acc[mf][nf], 0, 0, 0);
                acc[mf][nf] = __builtin_amdgcn_mfma_f32_16x16x32_bf16(ah[mf], bl, acc[mf][nf], 0, 0, 0);
            }
        }
        __syncthreads();
        p ^= 1;
    }
    #pragma unroll
    for (int mf = 0; mf < 4; ++mf) {
        #pragma unroll
        for (int i = 0; i < 4; ++i) {
            const size_t row = (size_t)row0 + mf * 16 + g * 4 + i;
            float* cp = tout + ((size_t)z * Lc + row) * HDc + wid * 64 + fr;
            #pragma unroll
            for (int nf = 0; nf < 4; ++nf) cp[nf * 16] = acc[mf][nf][i];
        }
    }
}

// combine 16 partial stats per row -> mrow, invs
__global__ __launch_bounds__(256) void rstat_k(const float* __restrict__ ps,
                                               float* __restrict__ mrow,
                                               float* __restrict__ invs)
{
    const int idx = blockIdx.x * 256 + threadIdx.x;
    const int b = idx >> 10, row = idx & 1023;
    float m = -1e30f, s = 0.f;
    #pragma unroll
    for (int ty = 0; ty < 16; ++ty) {
        const float2 pp = *(const float2*)(ps + (((size_t)b * 16 + ty) * Lc + row) * 2);
        const float nm = fmaxf(m, pp.x);
        s = s * __expf(m - nm) + pp.y * __expf(pp.x - nm);
        m = nm;
    }
    mrow[idx] = m;
    invs[idx] = 1.0f / s;
}

// 32x32 transpose + hi/lo split helper
__device__ __forceinline__ void tr32(const float* src, unsigned short* dh,
                                     unsigned short* dl, int R, int C,
                                     int r0, int c0, float (*tile)[33], int t)
{
    const int tc = t & 31, tr = t >> 5;
    #pragma unroll
    for (int rr = 0; rr < 32; rr += 8)
        tile[tr + rr][tc] = src[(size_t)(r0 + tr + rr) * C + c0 + tc];
    __syncthreads();
    #pragma unroll
    for (int rr = 0; rr < 32; rr += 8) {
        unsigned short h, l; split1(tile[tc][tr + rr], h, l);
        const size_t o = (size_t)(c0 + tr + rr) * R + r0 + tc;
        dh[o] = h; dl[o] = l;
    }
}

// all weight transposes + bias concat in one launch
__global__ __launch_bounds__(256) void prep_k(
    const float* __restrict__ W, const float* __restrict__ Wq,
    const float* __restrict__ Wk, const float* __restrict__ Wv,
    const float* __restrict__ Wfc, const float* __restrict__ bq,
    const float* __restrict__ bk, const float* __restrict__ bv,
    unsigned short* __restrict__ WTh, unsigned short* __restrict__ WTl,
    unsigned short* __restrict__ Wch, unsigned short* __restrict__ Wcl,
    unsigned short* __restrict__ WfcTh, unsigned short* __restrict__ WfcTl,
    float* __restrict__ bcat)
{
    __shared__ float tile[32][33];
    const int bx = blockIdx.x, by = blockIdx.y, t = threadIdx.x;
    if (by == 0) {
        if (bx >= 32) return;
        const int h = bx >> 3, tl = bx & 7;
        tr32(W + (size_t)h * Fc * Dc, WTh + (size_t)h * Dc * Fc,
             WTl + (size_t)h * Dc * Fc, Fc, Dc, (tl >> 1) * 32, (tl & 1) * 32, tile, t);
    } else if (by <= 3) {
        const float* s = (by == 1) ? Wq : (by == 2) ? Wk : Wv;
        const size_t off = (size_t)(by - 1) * HDc * HDc;
        tr32(s, Wch + off, Wcl + off, HDc, HDc, (bx >> 3) * 32, (bx & 7) * 32, tile, t);
    } else {
        if (bx < 16) {
            tr32(Wfc, WfcTh, WfcTl, HDc, Dc, (bx >> 1) * 32, (bx & 1) * 32, tile, t);
        } else if (bx == 16) {
            bcat[t] = bq[t]; bcat[256 + t] = bk[t]; bcat[512 + t] = bv[t];
        }
    }
}

extern "C" void kernel_launch(void* const* d_in, const int* in_sizes, int n_in,
                              void* d_out, int out_size, void* d_ws, size_t ws_size,
                              hipStream_t stream)
{
    const float* x   = (const float*)d_in[0];
    const float* W   = (const float*)d_in[1];
    const float* a1  = (const float*)d_in[2];
    const float* a2  = (const float*)d_in[3];
    const float* Wq  = (const float*)d_in[4];
    const float* bq  = (const float*)d_in[5];
    const float* Wk  = (const float*)d_in[6];
    const float* bk  = (const float*)d_in[7];
    const float* Wv  = (const float*)d_in[8];
    const float* bv  = (const float*)d_in[9];
    const float* Wfc = (const float*)d_in[10];
    const float* bfc = (const float*)d_in[11];

    float* outp    = (float*)d_out;
    float* gat_att = outp + (size_t)Bc * Lc * Dc;
    float* t_att   = gat_att + (size_t)Hc * Bc * Lc * Lc;
    float* t_out   = t_att + (size_t)Bc * Lc * Lc;

    constexpr size_t MB = 1024 * 1024;
    char* wsb = (char*)d_ws;
    // region 0 (0-16MB): WhT-hl -> VT-hl (WhT dead after gat_k)
    unsigned short* WhTh = (unsigned short*)wsb;
    unsigned short* WhTl = WhTh + (size_t)64 * 64 * 1024;
    unsigned short* VTh = WhTh; unsigned short* VTl = WhTl;
    // region 1 (16-32MB): gout-hl
    unsigned short* gouth = (unsigned short*)(wsb + 16 * MB);
    unsigned short* goutl = gouth + (size_t)Nrows * HDc;
    // region 2 (32-48MB): Q-hl
    unsigned short* Qh = (unsigned short*)(wsb + 32 * MB);
    unsigned short* Ql = Qh + (size_t)Nrows * HDc;
    // region 3 (48-64MB): K-hl
    unsigned short* Kh = (unsigned short*)(wsb + 48 * MB);
    unsigned short* Kl = Kh + (size_t)Nrows * HDc;
    // region 4 (64MB+): small buffers
    float* si  = (float*)(wsb + 64 * MB);
    float* sj  = si + Hc * Nrows;
    float* pstats = sj + Hc * Nrows;                  // [16][16][1024][2]
    float* mrow = pstats + (size_t)Bc * 16 * Lc * 2;  // [16][1024]
    float* invs = mrow + Bc * Lc;
    unsigned short* WTh = (unsigned short*)(invs + Bc * Lc);  // [4][64][128]
    unsigned short* WTl = WTh + Hc * Dc * Fc;
    unsigned short* Wch = WTl + Hc * Dc * Fc;         // [768][256]
    unsigned short* Wcl = Wch + 768 * HDc;
    unsigned short* WfcTh = Wcl + 768 * HDc;          // [64][256]
    unsigned short* WfcTl = WfcTh + Dc * HDc;
    float* bcat = (float*)(WfcTl + Dc * HDc);         // [768]

    const dim3 blk(256);

    // 0. weight prep (one launch)
    prep_k<<<dim3(64, 5), blk, 0, stream>>>(W, Wq, Wk, Wv, Wfc, bq, bk, bv,
        WTh, WTl, Wch, Wcl, WfcTh, WfcTl, bcat);

    // 1. WhT-hl = (x @ W[h]^T)^T + fused si/sj
    mm_k<128, 64, A_F32, E_WHT><<<dim3(Nrows / 128, 1, Hc), blk, 0, stream>>>(
        x, nullptr, nullptr, WTh, WTl, nullptr, nullptr,
        WhTh, WhTl, nullptr, nullptr, nullptr, nullptr,
        Fc, Fc, Fc, 0, 0LL, (long long)Dc * Fc, 0LL, 1.f, a1, a2, si, sj, nullptr);

    // 2. fused GAT (stats in-block): gat_att + gout-hl
    gat_k<<<dim3(Lc / 128, 1, 64), blk, 0, stream>>>(si, sj,
        WhTh, WhTl, gat_att, gouth, goutl);

    // 3. fused QKV projection (Q-hl, K-hl linear; VT-hl transposed)
    mm_k<128, 128, A_HL, E_QKV><<<dim3(Nrows / 128, 6, 1), blk, 0, stream>>>(
        nullptr, gouth, goutl, Wch, Wcl, bcat, nullptr,
        Qh, Ql, Kh, Kl, VTh, VTl,
        HDc, HDc, HDc, HDc, 0LL, 0LL, 0LL, 1.f, nullptr, nullptr, nullptr, nullptr, nullptr);

    // 4. raw scaled scores -> t_att region + partial row stats
    mm_k<128, 128, A_HL, E_STATS><<<dim3(8, 8, Bc), blk, 0, stream>>>(
        nullptr, Qh, Ql, Kh, Kl, nullptr, t_att,
        nullptr, nullptr, nullptr, nullptr, nullptr, nullptr,
        HDc, HDc, HDc, Lc, (long long)Lc * HDc, (long long)Lc * HDc,
        (long long)Lc * Lc, 0.0625f, nullptr, nullptr, nullptr, nullptr, pstats);

    // 5. combine stats
    rstat_k<<<dim3(Nrows / 256), blk, 0, stream>>>(pstats, mrow, invs);

    // 6. PV with fused softmax (t_att normalized in place, t_out = p @ V)
    pv_k<<<dim3(16, 1, Bc), blk, 0, stream>>>(t_att, mrow, invs, VTh, VTl, t_out);

    // 7. out = temporal_out @ Wfc + bfc
    mm_k<128, 64, A_F32, E_BIAS><<<dim3(Nrows / 128, 1, 1), blk, 0, stream>>>(
        t_out, nullptr, nullptr, WfcTh, WfcTl, bfc, outp,
        nullptr, nullptr, nullptr, nullptr, nullptr, nullptr,
        HDc, HDc, HDc, Dc, 0LL, 0LL, 0LL, 1.f, nullptr, nullptr, nullptr, nullptr, nullptr);
}

// Round 7
// 237.228 us; speedup vs baseline: 6.3363x; 1.0515x over previous
//
#include <hip/hip_runtime.h>

// TemporalGAT on MI355X — round 7: rstat folded into pv prologue, final
// out-GEMM fused into pv epilogue (LDS-tile re-GEMM), QKV grid swapped for
// XCD A-panel sharing. 6 launches. bf16 hi/lo 3-term split MFMA throughout.
// B=16, L=1024, F=128, H=4, D=64, HD=256, N=B*L=16384

constexpr int Bc = 16, Lc = 1024, Fc = 128, Hc = 4, Dc = 64, HDc = 256;
constexpr int Nrows = Bc * Lc;  // 16384
#define ALPHA_SLOPE 0.2f

typedef __attribute__((ext_vector_type(8))) short bf16x8;
typedef __attribute__((ext_vector_type(4))) float f32x4;

enum { A_F32 = 0, A_HL = 1 };
enum { E_BIAS = 1, E_WHT = 2, E_STATS = 3, E_QKV = 4 };

__device__ __forceinline__ float lrelu(float x) { return x > 0.f ? x : ALPHA_SLOPE * x; }

__device__ __forceinline__ void gll16(const void* g, void* l) {
    __builtin_amdgcn_global_load_lds(
        (const __attribute__((address_space(1))) void*)g,
        (__attribute__((address_space(3))) void*)l, 16, 0, 0);
}

__device__ __forceinline__ void split2(float a, float b, unsigned& h, unsigned& l) {
    const unsigned ua = __float_as_uint(a), ub = __float_as_uint(b);
    h = __byte_perm(ua, ub, 0x7632);
    const float la = a - __uint_as_float(ua & 0xffff0000u);
    const float lb = b - __uint_as_float(ub & 0xffff0000u);
    l = __byte_perm(__float_as_uint(la), __float_as_uint(lb), 0x7632);
}
__device__ __forceinline__ void split1(float v, unsigned short& h, unsigned short& l) {
    const unsigned u = __float_as_uint(v);
    h = (unsigned short)(u >> 16);
    const float lf = v - __uint_as_float(u & 0xffff0000u);
    l = (unsigned short)(__float_as_uint(lf) >> 16);
}

// ---------------------------------------------------------------------------
// MFMA GEMM, 2-phase double-buffered, XCD-swizzled: C = A[M,K] @ Bt[N,K]^T.
// SWAPXY (E_QKV): blockIdx.x indexes columns so A-panel-sharing blocks are
// lin-consecutive (same XCD chunk).
// ---------------------------------------------------------------------------
template <int BM, int BN, int AMODE, int EPI>
__global__ __launch_bounds__(256, 2) void mm_k(
    const float* __restrict__ Af,
    const unsigned short* __restrict__ Agh, const unsigned short* __restrict__ Agl,
    const unsigned short* __restrict__ Bgh, const unsigned short* __restrict__ Bgl,
    const float* __restrict__ bias,
    float* __restrict__ Cf,
    unsigned short* __restrict__ Ch, unsigned short* __restrict__ Cl,
    unsigned short* __restrict__ Ch2, unsigned short* __restrict__ Cl2,
    unsigned short* __restrict__ Ch3, unsigned short* __restrict__ Cl3,
    int K, int lda, int ldb, int ldc,
    long long zA, long long zB, long long zC, float alpha,
    const float* __restrict__ a1, const float* __restrict__ a2,
    float* __restrict__ si, float* __restrict__ sj, float* __restrict__ pstats)
{
    constexpr int ABUF = BM * 32, BBUF = BN * 32;
    __shared__ __align__(16) unsigned short SM[4 * ABUF + 4 * BBUF];
    unsigned short* const Ah_s = SM;
    unsigned short* const Al_s = SM + 2 * ABUF;
    unsigned short* const Bh_s = SM + 4 * ABUF;
    unsigned short* const Bl_s = SM + 4 * ABUF + 2 * BBUF;

    constexpr bool SWAPXY = (EPI == E_QKV);

    // XCD-chunked bijective block remap (grid size % 8 == 0 for all users)
    const int nbx = gridDim.x, nby = gridDim.y;
    int lin = blockIdx.x + nbx * (blockIdx.y + nby * blockIdx.z);
    const int ntot = nbx * nby * gridDim.z;
    lin = (lin & 7) * (ntot >> 3) + (lin >> 3);
    const int bx = lin % nbx;
    const int rem = lin / nbx;
    const int by = rem % nby;
    const int z  = rem / nby;

    if (AMODE == A_F32) { Af += (size_t)z * zA; }
    else { Agh += (size_t)z * zA; Agl += (size_t)z * zA; }
    Bgh += (size_t)z * zB; Bgl += (size_t)z * zB;
    if (Cf) Cf += (size_t)z * zC;

    constexpr int WC = (BN == 64) ? 1 : 2, WR = 4 / WC;
    constexpr int WM = BM / WR, WN = BN / WC, MF = WM / 16, NF = WN / 16;
    const int row0 = (SWAPXY ? by : bx) * BM;
    const int col0 = (SWAPXY ? bx : by) * BN;
    const int t = threadIdx.x, lane = t & 63, wid = t >> 6;
    const int fr = lane & 15, g = lane >> 4, fk = g * 8;
    const int wrow = (wid / WC) * WM, wcol = (wid % WC) * WN;
    const int rsub = lane >> 2, cbyt = (lane & 3) * 16;

    f32x4 acc[MF][NF] = {};

    auto stageB = [&](int k0, int pp) {
        #pragma unroll
        for (int q = 0; q < BN / 64; ++q) {
            const int r = wid * (BN / 4) + q * 16;
            const size_t gb = ((size_t)(col0 + r + rsub) * ldb + k0) * 2 + cbyt;
            gll16((const char*)Bgh + gb, (char*)(Bh_s + pp * BBUF) + (size_t)r * 64);
            gll16((const char*)Bgl + gb, (char*)(Bl_s + pp * BBUF) + (size_t)r * 64);
        }
    };
    auto stageA = [&](int k0, int pp) {
        if (AMODE == A_HL) {
            #pragma unroll
            for (int q = 0; q < BM / 64; ++q) {
                const int r = wid * (BM / 4) + q * 16;
                const size_t gb = ((size_t)(row0 + r + rsub) * lda + k0) * 2 + cbyt;
                gll16((const char*)Agh + gb, (char*)(Ah_s + pp * ABUF) + (size_t)r * 64);
                gll16((const char*)Agl + gb, (char*)(Al_s + pp * ABUF) + (size_t)r * 64);
            }
        } else {
            // f32 -> hi/lo reg-convert staging (BM == 128)
            const int r = t >> 1, h2 = t & 1;
            const float* srcA = Af + (size_t)(row0 + r) * lda + k0 + h2 * 16;
            const float4 v0 = ((const float4*)srcA)[0];
            const float4 v1 = ((const float4*)srcA)[1];
            const float4 v2 = ((const float4*)srcA)[2];
            const float4 v3 = ((const float4*)srcA)[3];
            unsigned hu[8], lu[8];
            split2(v0.x, v0.y, hu[0], lu[0]); split2(v0.z, v0.w, hu[1], lu[1]);
            split2(v1.x, v1.y, hu[2], lu[2]); split2(v1.z, v1.w, hu[3], lu[3]);
            split2(v2.x, v2.y, hu[4], lu[4]); split2(v2.z, v2.w, hu[5], lu[5]);
            split2(v3.x, v3.y, hu[6], lu[6]); split2(v3.z, v3.w, hu[7], lu[7]);
            uint4* dh = (uint4*)(Ah_s + pp * ABUF + r * 32 + h2 * 16);
            dh[0] = make_uint4(hu[0], hu[1], hu[2], hu[3]);
            dh[1] = make_uint4(hu[4], hu[5], hu[6], hu[7]);
            uint4* dl = (uint4*)(Al_s + pp * ABUF + r * 32 + h2 * 16);
            dl[0] = make_uint4(lu[0], lu[1], lu[2], lu[3]);
            dl[1] = make_uint4(lu[4], lu[5], lu[6], lu[7]);
        }
    };

    stageB(0, 0);
    stageA(0, 0);
    __syncthreads();

    const int NT = K / 32;
    int p = 0;
    for (int kt = 0; kt < NT; ++kt) {
        if (kt + 1 < NT) { stageB((kt + 1) * 32, p ^ 1); stageA((kt + 1) * 32, p ^ 1); }
        bf16x8 ah[MF], al[MF];
        #pragma unroll
        for (int mf = 0; mf < MF; ++mf) {
            const int off = p * ABUF + (wrow + mf * 16 + fr) * 32 + fk;
            ah[mf] = *(const bf16x8*)(Ah_s + off);
            al[mf] = *(const bf16x8*)(Al_s + off);
        }
        #pragma unroll
        for (int nf = 0; nf < NF; ++nf) {
            const int off = p * BBUF + (wcol + nf * 16 + fr) * 32 + fk;
            const bf16x8 bh = *(const bf16x8*)(Bh_s + off);
            const bf16x8 bl = *(const bf16x8*)(Bl_s + off);
            #pragma unroll
            for (int mf = 0; mf < MF; ++mf) {
                acc[mf][nf] = __builtin_amdgcn_mfma_f32_16x16x32_bf16(ah[mf], bh, acc[mf][nf], 0, 0, 0);
                acc[mf][nf] = __builtin_amdgcn_mfma_f32_16x16x32_bf16(al[mf], bh, acc[mf][nf], 0, 0, 0);
                acc[mf][nf] = __builtin_amdgcn_mfma_f32_16x16x32_bf16(ah[mf], bl, acc[mf][nf], 0, 0, 0);
            }
        }
        __syncthreads();
        p ^= 1;
    }

    // ---- epilogues (C/D layout: col = lane&15, row = (lane>>4)*4 + i [m89])
    float* ts = (float*)SM;  // transpose scratch overlays staging (post-barrier)

    if (EPI == E_BIAS || EPI == E_STATS) {
        float bv_[NF];
        if (EPI == E_BIAS) {
            #pragma unroll
            for (int nf = 0; nf < NF; ++nf) bv_[nf] = bias[col0 + wcol + nf * 16 + fr];
        }
        #pragma unroll
        for (int mf = 0; mf < MF; ++mf) {
            #pragma unroll
            for (int i = 0; i < 4; ++i) {
                const size_t row = (size_t)row0 + wrow + mf * 16 + g * 4 + i;
                const size_t co = row * ldc + col0 + wcol + fr;
                #pragma unroll
                for (int nf = 0; nf < NF; ++nf) {
                    float v = acc[mf][nf][i];
                    if (EPI == E_STATS) v *= alpha;
                    if (EPI == E_BIAS)  v += bv_[nf];
                    acc[mf][nf][i] = v;
                    Cf[co + nf * 16] = v;
                }
            }
        }
        if (EPI == E_STATS) {
            const int ty = by * WC + (wid % WC);
            #pragma unroll
            for (int mf = 0; mf < MF; ++mf) {
                #pragma unroll
                for (int i = 0; i < 4; ++i) {
                    float m = acc[mf][0][i], s;
                    #pragma unroll
                    for (int nf = 1; nf < NF; ++nf) m = fmaxf(m, acc[mf][nf][i]);
                    s = 0.f;
                    #pragma unroll
                    for (int nf = 0; nf < NF; ++nf) s += __expf(acc[mf][nf][i] - m);
                    #pragma unroll
                    for (int ofs = 1; ofs < 16; ofs <<= 1) {
                        const float om = __shfl_xor(m, ofs, 64);
                        const float os = __shfl_xor(s, ofs, 64);
                        const float nm = fmaxf(m, om);
                        s = s * __expf(m - nm) + os * __expf(om - nm);
                        m = nm;
                    }
                    if (fr == 0) {
                        const size_t row = (size_t)row0 + wrow + mf * 16 + g * 4 + i;
                        float* pp = pstats + (((size_t)z * 16 + ty) * Lc + row) * 2;
                        pp[0] = m; pp[1] = s;
                    }
                }
            }
        }
    }

    if (EPI == E_QKV) {
        float bv_[NF];
        #pragma unroll
        for (int nf = 0; nf < NF; ++nf) bv_[nf] = bias[col0 + wcol + nf * 16 + fr];
        #pragma unroll
        for (int mf = 0; mf < MF; ++mf)
            #pragma unroll
            for (int i = 0; i < 4; ++i)
                #pragma unroll
                for (int nf = 0; nf < NF; ++nf) acc[mf][nf][i] += bv_[nf];

        if (col0 < 512) {
            // Q (cols 0-255) / K (256-511): linear hi/lo write
            unsigned short* dH = (col0 < 256) ? Ch : Ch2;
            unsigned short* dL = (col0 < 256) ? Cl : Cl2;
            const int cl0 = col0 & 255;
            #pragma unroll
            for (int mf = 0; mf < MF; ++mf) {
                #pragma unroll
                for (int i = 0; i < 4; ++i) {
                    const size_t row = (size_t)row0 + wrow + mf * 16 + g * 4 + i;
                    const size_t co = row * ldc + cl0 + wcol + fr;
                    #pragma unroll
                    for (int nf = 0; nf < NF; ++nf) {
                        unsigned short hh16, ll16; split1(acc[mf][nf][i], hh16, ll16);
                        dH[co + nf * 16] = hh16; dL[co + nf * 16] = ll16;
                    }
                }
            }
        } else {
            // V (cols 512-767): transposed hi/lo write -> VT[b][d][l]
            const int bq_ = row0 >> 10, lg0 = row0 & 1023;
            #pragma unroll
            for (int hf = 0; hf < 2; ++hf) {
                if ((wid & 1) == hf) {
                    #pragma unroll
                    for (int mf = 0; mf < MF; ++mf)
                        #pragma unroll
                        for (int i = 0; i < 4; ++i) {
                            const int rr = wrow + mf * 16 + g * 4 + i;
                            #pragma unroll
                            for (int nf = 0; nf < NF; ++nf)
                                ts[rr * 65 + nf * 16 + fr] = acc[mf][nf][i];
                        }
                }
                __syncthreads();
                const int l = t & 127, db = (t >> 7) * 32;
                #pragma unroll
                for (int dd = 0; dd < 32; ++dd) {
                    const int dl = db + dd;
                    unsigned short hh16, ll16; split1(ts[l * 65 + dl], hh16, ll16);
                    const size_t o = ((size_t)bq_ * 256 + (col0 - 512) + hf * 64 + dl) * 1024 + lg0 + l;
                    Ch3[o] = hh16; Cl3[o] = ll16;
                }
                __syncthreads();
            }
        }
    }

    if (EPI == E_WHT) {
        // si/sj fused reductions (BN==64: each wave spans all 64 cols)
        float a1v[NF], a2v[NF];
        #pragma unroll
        for (int nf = 0; nf < NF; ++nf) {
            a1v[nf] = a1[(size_t)z * Dc + nf * 16 + fr];
            a2v[nf] = a2[(size_t)z * Dc + nf * 16 + fr];
        }
        #pragma unroll
        for (int mf = 0; mf < MF; ++mf) {
            #pragma unroll
            for (int i = 0; i < 4; ++i) {
                float p1 = 0.f, p2 = 0.f;
                #pragma unroll
                for (int nf = 0; nf < NF; ++nf) {
                    p1 = fmaf(acc[mf][nf][i], a1v[nf], p1);
                    p2 = fmaf(acc[mf][nf][i], a2v[nf], p2);
                }
                #pragma unroll
                for (int ofs = 1; ofs < 16; ofs <<= 1) {
                    p1 += __shfl_xor(p1, ofs, 64);
                    p2 += __shfl_xor(p2, ofs, 64);
                }
                if (fr == 0) {
                    const int row = row0 + wrow + mf * 16 + g * 4 + i;
                    si[(size_t)z * Nrows + row] = p1;
                    sj[(size_t)z * Nrows + row] = p2;
                }
            }
        }
        // transposed hi/lo write -> WhT[h*16+b][d][l]
        #pragma unroll
        for (int mf = 0; mf < MF; ++mf)
            #pragma unroll
            for (int i = 0; i < 4; ++i) {
                const int rr = wrow + mf * 16 + g * 4 + i;
                #pragma unroll
                for (int nf = 0; nf < NF; ++nf)
                    ts[rr * 65 + nf * 16 + fr] = acc[mf][nf][i];
            }
        __syncthreads();
        const int bq_ = row0 >> 10, lg0 = row0 & 1023;
        const int l = t & 127, db = (t >> 7) * 32;
        #pragma unroll
        for (int dd = 0; dd < 32; ++dd) {
            const int d = db + dd;
            unsigned short hh16, ll16; split1(ts[l * 65 + d], hh16, ll16);
            const size_t o = (((size_t)(z * 16 + bq_)) * 64 + d) * 1024 + lg0 + l;
            Ch[o] = hh16; Cl[o] = ll16;
        }
    }
}

// ---------------------------------------------------------------------------
// Fused GAT, 2-phase, swizzled, in-block softmax stats.
// ---------------------------------------------------------------------------
__global__ __launch_bounds__(256, 2) void gat_k(
    const float* __restrict__ si, const float* __restrict__ sj,
    const unsigned short* __restrict__ WhTh, const unsigned short* __restrict__ WhTl,
    float* __restrict__ att, unsigned short* __restrict__ gouth,
    unsigned short* __restrict__ goutl)
{
    constexpr int BBUF = 64 * 32;
    __shared__ __align__(16) unsigned short SMg[4 * BBUF];
    __shared__ __align__(16) float sjs[Lc];
    __shared__ float redm[4];
    unsigned short* const Bh_s = SMg;
    unsigned short* const Bl_s = SMg + 2 * BBUF;

    // XCD-chunked remap over grid (8,1,64) = 512 blocks
    int lin = blockIdx.x + 8 * blockIdx.z;
    lin = (lin & 7) * 64 + (lin >> 3);
    const int bx = lin & 7, z = lin >> 3;

    const int row0 = bx * 128;
    const int t = threadIdx.x, lane = t & 63, wid = t >> 6;
    const int fr = lane & 15, g = lane >> 4, fk = g * 8;
    const int wrow = wid * 32;
    const int hh = z >> 4, bb = z & 15;
    const int rsub = lane >> 2, cbyt = (lane & 3) * 16;

    const unsigned short* WhTh_z = WhTh + (size_t)z * 64 * 1024;
    const unsigned short* WhTl_z = WhTl + (size_t)z * 64 * 1024;
    const float* sjz = sj + (size_t)z * 1024;
    float* attz = att + ((size_t)z * 1024 + row0) * 1024;

    auto stageB = [&](int j0, int pp) {
        const int r = wid * 16;
        const size_t gb = ((size_t)(r + rsub) * 1024 + j0) * 2 + cbyt;
        gll16((const char*)WhTh_z + gb, (char*)(Bh_s + pp * BBUF) + (size_t)r * 64);
        gll16((const char*)WhTl_z + gb, (char*)(Bl_s + pp * BBUF) + (size_t)r * 64);
    };

    stageB(0, 0);
    ((float4*)sjs)[t] = ((const float4*)sjz)[t];
    __syncthreads();

    // block-wide max of sj row
    {
        const float4 v = ((const float4*)sjs)[t];
        float m4 = fmaxf(fmaxf(v.x, v.y), fmaxf(v.z, v.w));
        #pragma unroll
        for (int ofs = 32; ofs >= 1; ofs >>= 1) m4 = fmaxf(m4, __shfl_xor(m4, ofs, 64));
        if (lane == 0) redm[wid] = m4;
    }
    __syncthreads();
    const float smax = fmaxf(fmaxf(redm[0], redm[1]), fmaxf(redm[2], redm[3]));

    float siv[2], mr[2], inv[2];
    #pragma unroll
    for (int mf = 0; mf < 2; ++mf) {
        const int r = row0 + wrow + mf * 16 + fr;
        const float sv = si[(size_t)hh * Nrows + bb * 1024 + r];
        siv[mf] = sv;
        mr[mf] = lrelu(sv + smax);
        float s = 0.f;
        const float4* sp = (const float4*)sjs + g * 64;
        #pragma unroll 4
        for (int c = 0; c < 64; ++c) {
            const float4 w = sp[c];
            s += __expf(lrelu(sv + w.x) - mr[mf]) + __expf(lrelu(sv + w.y) - mr[mf])
               + __expf(lrelu(sv + w.z) - mr[mf]) + __expf(lrelu(sv + w.w) - mr[mf]);
        }
        s += __shfl_xor(s, 16, 64);
        s += __shfl_xor(s, 32, 64);
        inv[mf] = 1.0f / s;
    }

    f32x4 acc[2][4] = {};
    int p = 0;
    for (int kt = 0; kt < 32; ++kt) {
        const int j0 = kt * 32;
        if (kt < 31) stageB(j0 + 32, p ^ 1);
        bf16x8 ph[2], pl[2];
        #pragma unroll
        for (int mf = 0; mf < 2; ++mf) {
            const float4 s0 = ((const float4*)sjs)[(j0 >> 2) + g * 2];
            const float4 s1 = ((const float4*)sjs)[(j0 >> 2) + g * 2 + 1];
            float pr[8];
            pr[0] = __expf(lrelu(siv[mf] + s0.x) - mr[mf]) * inv[mf];
            pr[1] = __expf(lrelu(siv[mf] + s0.y) - mr[mf]) * inv[mf];
            pr[2] = __expf(lrelu(siv[mf] + s0.z) - mr[mf]) * inv[mf];
            pr[3] = __expf(lrelu(siv[mf] + s0.w) - mr[mf]) * inv[mf];
            pr[4] = __expf(lrelu(siv[mf] + s1.x) - mr[mf]) * inv[mf];
            pr[5] = __expf(lrelu(siv[mf] + s1.y) - mr[mf]) * inv[mf];
            pr[6] = __expf(lrelu(siv[mf] + s1.z) - mr[mf]) * inv[mf];
            pr[7] = __expf(lrelu(siv[mf] + s1.w) - mr[mf]) * inv[mf];
            float* ap = attz + (size_t)(wrow + mf * 16 + fr) * 1024 + j0 + fk;
            *(float4*)ap       = make_float4(pr[0], pr[1], pr[2], pr[3]);
            *(float4*)(ap + 4) = make_float4(pr[4], pr[5], pr[6], pr[7]);
            union { unsigned u[4]; bf16x8 v; } uh, ul;
            split2(pr[0], pr[1], uh.u[0], ul.u[0]);
            split2(pr[2], pr[3], uh.u[1], ul.u[1]);
            split2(pr[4], pr[5], uh.u[2], ul.u[2]);
            split2(pr[6], pr[7], uh.u[3], ul.u[3]);
            ph[mf] = uh.v; pl[mf] = ul.v;
        }
        #pragma unroll
        for (int nf = 0; nf < 4; ++nf) {
            const int off = p * BBUF + (nf * 16 + fr) * 32 + fk;
            const bf16x8 bh = *(const bf16x8*)(Bh_s + off);
            const bf16x8 bl = *(const bf16x8*)(Bl_s + off);
            #pragma unroll
            for (int mf = 0; mf < 2; ++mf) {
                acc[mf][nf] = __builtin_amdgcn_mfma_f32_16x16x32_bf16(ph[mf], bh, acc[mf][nf], 0, 0, 0);
                acc[mf][nf] = __builtin_amdgcn_mfma_f32_16x16x32_bf16(pl[mf], bh, acc[mf][nf], 0, 0, 0);
                acc[mf][nf] = __builtin_amdgcn_mfma_f32_16x16x32_bf16(ph[mf], bl, acc[mf][nf], 0, 0, 0);
            }
        }
        __syncthreads();
        p ^= 1;
    }
    #pragma unroll
    for (int mf = 0; mf < 2; ++mf) {
        #pragma unroll
        for (int i = 0; i < 4; ++i) {
            const int row_l = wrow + mf * 16 + g * 4 + i;
            const size_t base = ((size_t)bb * 1024 + row0 + row_l) * 256 + hh * 64 + fr;
            #pragma unroll
            for (int nf = 0; nf < 4; ++nf) {
                unsigned short hh16, ll16; split1(acc[mf][nf][i], hh16, ll16);
                gouth[base + nf * 16] = hh16;
                goutl[base + nf * 16] = ll16;
            }
        }
    }
}

// ---------------------------------------------------------------------------
// PV with fused softmax + folded rstat + fused output projection.
// Normalizes raw scores in place -> t_att; t_out = p @ V; out = t_out @ Wfc
// + bfc via LDS-tile re-GEMM (block owns full 64x256 t_out tile).
// BM=64, BN=256, grid (16,1,16).
// ---------------------------------------------------------------------------
__global__ __launch_bounds__(256, 2) void pv_k(
    float* __restrict__ scores, const float* __restrict__ pstats,
    const unsigned short* __restrict__ VTh, const unsigned short* __restrict__ VTl,
    const unsigned short* __restrict__ WfcTh, const unsigned short* __restrict__ WfcTl,
    const float* __restrict__ bfc,
    float* __restrict__ tout, float* __restrict__ outp)
{
    constexpr int ABUF = 64 * 32, BBUF = 256 * 32;
    __shared__ __align__(16) unsigned short SMp[4 * ABUF + 4 * BBUF];  // 80 KB
    unsigned short* const Ah_s = SMp;
    unsigned short* const Al_s = SMp + 2 * ABUF;
    unsigned short* const Bh_s = SMp + 4 * ABUF;
    unsigned short* const Bl_s = SMp + 4 * ABUF + 2 * BBUF;

    // XCD-chunked remap over grid (16,1,16) = 256 blocks
    int lin = blockIdx.x + 16 * blockIdx.z;
    lin = (lin & 7) * 32 + (lin >> 3);
    const int bx = lin & 15, z = lin >> 4;

    const int row0 = bx * 64;
    const int t = threadIdx.x, lane = t & 63, wid = t >> 6;
    const int fr = lane & 15, g = lane >> 4, fk = g * 8;
    const int rsub = lane >> 2, cbyt = (lane & 3) * 16;

    float* sc = scores + ((size_t)z * Lc + row0) * Lc;
    const unsigned short* VTh_z = VTh + (size_t)z * HDc * Lc;
    const unsigned short* VTl_z = VTl + (size_t)z * HDc * Lc;

    auto stageB = [&](int k0, int pp) {
        #pragma unroll
        for (int q = 0; q < 4; ++q) {
            const int r = q * 64 + wid * 16;
            const size_t gb = ((size_t)(r + rsub) * Lc + k0) * 2 + cbyt;
            gll16((const char*)VTh_z + gb, (char*)(Bh_s + pp * BBUF) + (size_t)r * 64);
            gll16((const char*)VTl_z + gb, (char*)(Bl_s + pp * BBUF) + (size_t)r * 64);
        }
    };

    stageB(0, 0);  // get loads in flight before stats math

    // folded rstat: combine 16 partials for row ar; 4 lanes/row, 4 partials each
    const int ar = t >> 2, cq = (t & 3) * 8;
    float m_ = -1e30f, s_ = 0.f;
    {
        const int q = t & 3;
        const float* pb = pstats + (((size_t)z * 16 + q * 4) * Lc + row0 + ar) * 2;
        #pragma unroll
        for (int j = 0; j < 4; ++j) {
            const float2 pp = *(const float2*)(pb + (size_t)j * Lc * 2);
            const float nm = fmaxf(m_, pp.x);
            s_ = s_ * __expf(m_ - nm) + pp.y * __expf(pp.x - nm);
            m_ = nm;
        }
        #pragma unroll
        for (int ofs = 1; ofs < 4; ofs <<= 1) {
            const float om = __shfl_xor(m_, ofs, 64);
            const float os = __shfl_xor(s_, ofs, 64);
            const float nm = fmaxf(m_, om);
            s_ = s_ * __expf(m_ - nm) + os * __expf(om - nm);
            m_ = nm;
        }
    }
    const float iv_ = 1.0f / s_;

    auto stageA = [&](int k0, int pp) {
        float* srcS = sc + (size_t)ar * Lc + k0 + cq;
        const float4 v0 = ((const float4*)srcS)[0];
        const float4 v1 = ((const float4*)srcS)[1];
        float pr[8];
        pr[0] = __expf(v0.x - m_) * iv_; pr[1] = __expf(v0.y - m_) * iv_;
        pr[2] = __expf(v0.z - m_) * iv_; pr[3] = __expf(v0.w - m_) * iv_;
        pr[4] = __expf(v1.x - m_) * iv_; pr[5] = __expf(v1.y - m_) * iv_;
        pr[6] = __expf(v1.z - m_) * iv_; pr[7] = __expf(v1.w - m_) * iv_;
        ((float4*)srcS)[0] = make_float4(pr[0], pr[1], pr[2], pr[3]);
        ((float4*)srcS)[1] = make_float4(pr[4], pr[5], pr[6], pr[7]);
        unsigned hu[4], lu[4];
        split2(pr[0], pr[1], hu[0], lu[0]); split2(pr[2], pr[3], hu[1], lu[1]);
        split2(pr[4], pr[5], hu[2], lu[2]); split2(pr[6], pr[7], hu[3], lu[3]);
        *(uint4*)(Ah_s + pp * ABUF + ar * 32 + cq) = make_uint4(hu[0], hu[1], hu[2], hu[3]);
        *(uint4*)(Al_s + pp * ABUF + ar * 32 + cq) = make_uint4(lu[0], lu[1], lu[2], lu[3]);
    };

    f32x4 acc[4][4] = {};
    stageA(0, 0);
    __syncthreads();
    int p = 0;
    for (int kt = 0; kt < 32; ++kt) {
        if (kt < 31) { stageB((kt + 1) * 32, p ^ 1); stageA((kt + 1) * 32, p ^ 1); }
        bf16x8 ah[4], al[4];
        #pragma unroll
        for (int mf = 0; mf < 4; ++mf) {
            const int off = p * ABUF + (mf * 16 + fr) * 32 + fk;
            ah[mf] = *(const bf16x8*)(Ah_s + off);
            al[mf] = *(const bf16x8*)(Al_s + off);
        }
        #pragma unroll
        for (int nf = 0; nf < 4; ++nf) {
            const int off = p * BBUF + (wid * 64 + nf * 16 + fr) * 32 + fk;
            const bf16x8 bh = *(const bf16x8*)(Bh_s + off);
            const bf16x8 bl = *(const bf16x8*)(Bl_s + off);
            #pragma unroll
            for (int mf = 0; mf < 4; ++mf) {
                acc[mf][nf] = __builtin_amdgcn_mfma_f32_16x16x32_bf16(ah[mf], bh, acc[mf][nf], 0, 0, 0);
                acc[mf][nf] = __builtin_amdgcn_mfma_f32_16x16x32_bf16(al[mf], bh, acc[mf][nf], 0, 0, 0);
                acc[mf][nf] = __builtin_amdgcn_mfma_f32_16x16x32_bf16(ah[mf], bl, acc[mf][nf], 0, 0, 0);
            }
        }
        __syncthreads();
        p ^= 1;
    }

    // t_out write + stash tile to LDS for the fused output projection
    constexpr int TS = 258;  // f32 row stride (bank-spread)
    float* ts = (float*)SMp;
    #pragma unroll
    for (int mf = 0; mf < 4; ++mf) {
        #pragma unroll
        for (int i = 0; i < 4; ++i) {
            const size_t row = (size_t)row0 + mf * 16 + g * 4 + i;
            float* cp = tout + ((size_t)z * Lc + row) * HDc + wid * 64 + fr;
            #pragma unroll
            for (int nf = 0; nf < 4; ++nf) {
                cp[nf * 16] = acc[mf][nf][i];
                ts[(mf * 16 + g * 4 + i) * TS + wid * 64 + nf * 16 + fr] = acc[mf][nf][i];
            }
        }
    }
    __syncthreads();

    // out = t_out_tile @ WfcT^T + bfc  (K=256; each wave -> 16 out cols)
    const int ocol = wid * 16 + fr;
    f32x4 acc2[4] = {};
    #pragma unroll
    for (int kt2 = 0; kt2 < 8; ++kt2) {
        const int kk = kt2 * 32 + fk;
        const bf16x8 bh = *(const bf16x8*)(WfcTh + ocol * 256 + kk);
        const bf16x8 bl = *(const bf16x8*)(WfcTl + ocol * 256 + kk);
        #pragma unroll
        for (int mf = 0; mf < 4; ++mf) {
            const float* ap = ts + (mf * 16 + fr) * TS + kk;
            union { unsigned u[4]; bf16x8 v; } ahh, all_;
            split2(ap[0], ap[1], ahh.u[0], all_.u[0]);
            split2(ap[2], ap[3], ahh.u[1], all_.u[1]);
            split2(ap[4], ap[5], ahh.u[2], all_.u[2]);
            split2(ap[6], ap[7], ahh.u[3], all_.u[3]);
            acc2[mf] = __builtin_amdgcn_mfma_f32_16x16x32_bf16(ahh.v, bh, acc2[mf], 0, 0, 0);
            acc2[mf] = __builtin_amdgcn_mfma_f32_16x16x32_bf16(all_.v, bh, acc2[mf], 0, 0, 0);
            {
                // ah*bl third term
                acc2[mf] = __builtin_amdgcn_mfma_f32_16x16x32_bf16(ahh.v, bl, acc2[mf], 0, 0, 0);
            }
        }
    }
    const float bo = bfc[ocol];
    #pragma unroll
    for (int mf = 0; mf < 4; ++mf)
        #pragma unroll
        for (int i = 0; i < 4; ++i)
            outp[((size_t)z * Lc + row0 + mf * 16 + g * 4 + i) * Dc + ocol] = acc2[mf][i] + bo;
}

// 32x32 transpose + hi/lo split helper
__device__ __forceinline__ void tr32(const float* src, unsigned short* dh,
                                     unsigned short* dl, int R, int C,
                                     int r0, int c0, float (*tile)[33], int t)
{
    const int tc = t & 31, tr = t >> 5;
    #pragma unroll
    for (int rr = 0; rr < 32; rr += 8)
        tile[tr + rr][tc] = src[(size_t)(r0 + tr + rr) * C + c0 + tc];
    __syncthreads();
    #pragma unroll
    for (int rr = 0; rr < 32; rr += 8) {
        unsigned short h, l; split1(tile[tc][tr + rr], h, l);
        const size_t o = (size_t)(c0 + tr + rr) * R + r0 + tc;
        dh[o] = h; dl[o] = l;
    }
}

// all weight transposes + bias concat in one launch
__global__ __launch_bounds__(256) void prep_k(
    const float* __restrict__ W, const float* __restrict__ Wq,
    const float* __restrict__ Wk, const float* __restrict__ Wv,
    const float* __restrict__ Wfc, const float* __restrict__ bq,
    const float* __restrict__ bk, const float* __restrict__ bv,
    unsigned short* __restrict__ WTh, unsigned short* __restrict__ WTl,
    unsigned short* __restrict__ Wch, unsigned short* __restrict__ Wcl,
    unsigned short* __restrict__ WfcTh, unsigned short* __restrict__ WfcTl,
    float* __restrict__ bcat)
{
    __shared__ float tile[32][33];
    const int bx = blockIdx.x, by = blockIdx.y, t = threadIdx.x;
    if (by == 0) {
        if (bx >= 32) return;
        const int h = bx >> 3, tl = bx & 7;
        tr32(W + (size_t)h * Fc * Dc, WTh + (size_t)h * Dc * Fc,
             WTl + (size_t)h * Dc * Fc, Fc, Dc, (tl >> 1) * 32, (tl & 1) * 32, tile, t);
    } else if (by <= 3) {
        const float* s = (by == 1) ? Wq : (by == 2) ? Wk : Wv;
        const size_t off = (size_t)(by - 1) * HDc * HDc;
        tr32(s, Wch + off, Wcl + off, HDc, HDc, (bx >> 3) * 32, (bx & 7) * 32, tile, t);
    } else {
        if (bx < 16) {
            tr32(Wfc, WfcTh, WfcTl, HDc, Dc, (bx >> 1) * 32, (bx & 1) * 32, tile, t);
        } else if (bx == 16) {
            bcat[t] = bq[t]; bcat[256 + t] = bk[t]; bcat[512 + t] = bv[t];
        }
    }
}

extern "C" void kernel_launch(void* const* d_in, const int* in_sizes, int n_in,
                              void* d_out, int out_size, void* d_ws, size_t ws_size,
                              hipStream_t stream)
{
    const float* x   = (const float*)d_in[0];
    const float* W   = (const float*)d_in[1];
    const float* a1  = (const float*)d_in[2];
    const float* a2  = (const float*)d_in[3];
    const float* Wq  = (const float*)d_in[4];
    const float* bq  = (const float*)d_in[5];
    const float* Wk  = (const float*)d_in[6];
    const float* bk  = (const float*)d_in[7];
    const float* Wv  = (const float*)d_in[8];
    const float* bv  = (const float*)d_in[9];
    const float* Wfc = (const float*)d_in[10];
    const float* bfc = (const float*)d_in[11];

    float* outp    = (float*)d_out;
    float* gat_att = outp + (size_t)Bc * Lc * Dc;
    float* t_att   = gat_att + (size_t)Hc * Bc * Lc * Lc;
    float* t_out   = t_att + (size_t)Bc * Lc * Lc;

    constexpr size_t MB = 1024 * 1024;
    char* wsb = (char*)d_ws;
    // region 0 (0-16MB): WhT-hl -> VT-hl (WhT dead after gat_k)
    unsigned short* WhTh = (unsigned short*)wsb;
    unsigned short* WhTl = WhTh + (size_t)64 * 64 * 1024;
    unsigned short* VTh = WhTh; unsigned short* VTl = WhTl;
    // region 1 (16-32MB): gout-hl
    unsigned short* gouth = (unsigned short*)(wsb + 16 * MB);
    unsigned short* goutl = gouth + (size_t)Nrows * HDc;
    // region 2 (32-48MB): Q-hl
    unsigned short* Qh = (unsigned short*)(wsb + 32 * MB);
    unsigned short* Ql = Qh + (size_t)Nrows * HDc;
    // region 3 (48-64MB): K-hl
    unsigned short* Kh = (unsigned short*)(wsb + 48 * MB);
    unsigned short* Kl = Kh + (size_t)Nrows * HDc;
    // region 4 (64MB+): small buffers
    float* si  = (float*)(wsb + 64 * MB);
    float* sj  = si + Hc * Nrows;
    float* pstats = sj + Hc * Nrows;                  // [16][16][1024][2]
    unsigned short* WTh = (unsigned short*)(pstats + (size_t)Bc * 16 * Lc * 2);  // [4][64][128]
    unsigned short* WTl = WTh + Hc * Dc * Fc;
    unsigned short* Wch = WTl + Hc * Dc * Fc;         // [768][256]
    unsigned short* Wcl = Wch + 768 * HDc;
    unsigned short* WfcTh = Wcl + 768 * HDc;          // [64][256]
    unsigned short* WfcTl = WfcTh + Dc * HDc;
    float* bcat = (float*)(WfcTl + Dc * HDc);         // [768]

    const dim3 blk(256);

    // 0. weight prep (one launch)
    prep_k<<<dim3(64, 5), blk, 0, stream>>>(W, Wq, Wk, Wv, Wfc, bq, bk, bv,
        WTh, WTl, Wch, Wcl, WfcTh, WfcTl, bcat);

    // 1. WhT-hl = (x @ W[h]^T)^T + fused si/sj
    mm_k<128, 64, A_F32, E_WHT><<<dim3(Nrows / 128, 1, Hc), blk, 0, stream>>>(
        x, nullptr, nullptr, WTh, WTl, nullptr, nullptr,
        WhTh, WhTl, nullptr, nullptr, nullptr, nullptr,
        Fc, Fc, Fc, 0, 0LL, (long long)Dc * Fc, 0LL, 1.f, a1, a2, si, sj, nullptr);

    // 2. fused GAT (stats in-block): gat_att + gout-hl
    gat_k<<<dim3(Lc / 128, 1, 64), blk, 0, stream>>>(si, sj,
        WhTh, WhTl, gat_att, gouth, goutl);

    // 3. fused QKV projection (col-block on x for XCD A-panel sharing)
    mm_k<128, 128, A_HL, E_QKV><<<dim3(6, Nrows / 128, 1), blk, 0, stream>>>(
        nullptr, gouth, goutl, Wch, Wcl, bcat, nullptr,
        Qh, Ql, Kh, Kl, VTh, VTl,
        HDc, HDc, HDc, HDc, 0LL, 0LL, 0LL, 1.f, nullptr, nullptr, nullptr, nullptr, nullptr);

    // 4. raw scaled scores -> t_att region + partial row stats
    mm_k<128, 128, A_HL, E_STATS><<<dim3(8, 8, Bc), blk, 0, stream>>>(
        nullptr, Qh, Ql, Kh, Kl, nullptr, t_att,
        nullptr, nullptr, nullptr, nullptr, nullptr, nullptr,
        HDc, HDc, HDc, Lc, (long long)Lc * HDc, (long long)Lc * HDc,
        (long long)Lc * Lc, 0.0625f, nullptr, nullptr, nullptr, nullptr, pstats);

    // 5. PV: folded rstat + fused softmax + t_out + fused out-projection
    pv_k<<<dim3(16, 1, Bc), blk, 0, stream>>>(t_att, pstats, VTh, VTl,
        WfcTh, WfcTl, bfc, t_out, outp);
}

// Round 8
// 235.155 us; speedup vs baseline: 6.3921x; 1.0088x over previous
//
#include <hip/hip_runtime.h>

// TemporalGAT on MI355X — round 8: pv_k BM=32 (2 blocks/CU, was 1), gat_k at
// 3 blocks/CU. Otherwise round-7 structure (6 launches, bf16 hi/lo 3-term
// split MFMA, XCD swizzle, fused epilogues).
// B=16, L=1024, F=128, H=4, D=64, HD=256, N=B*L=16384

constexpr int Bc = 16, Lc = 1024, Fc = 128, Hc = 4, Dc = 64, HDc = 256;
constexpr int Nrows = Bc * Lc;  // 16384
#define ALPHA_SLOPE 0.2f

typedef __attribute__((ext_vector_type(8))) short bf16x8;
typedef __attribute__((ext_vector_type(4))) float f32x4;

enum { A_F32 = 0, A_HL = 1 };
enum { E_BIAS = 1, E_WHT = 2, E_STATS = 3, E_QKV = 4 };

__device__ __forceinline__ float lrelu(float x) { return x > 0.f ? x : ALPHA_SLOPE * x; }

__device__ __forceinline__ void gll16(const void* g, void* l) {
    __builtin_amdgcn_global_load_lds(
        (const __attribute__((address_space(1))) void*)g,
        (__attribute__((address_space(3))) void*)l, 16, 0, 0);
}

__device__ __forceinline__ void split2(float a, float b, unsigned& h, unsigned& l) {
    const unsigned ua = __float_as_uint(a), ub = __float_as_uint(b);
    h = __byte_perm(ua, ub, 0x7632);
    const float la = a - __uint_as_float(ua & 0xffff0000u);
    const float lb = b - __uint_as_float(ub & 0xffff0000u);
    l = __byte_perm(__float_as_uint(la), __float_as_uint(lb), 0x7632);
}
__device__ __forceinline__ void split1(float v, unsigned short& h, unsigned short& l) {
    const unsigned u = __float_as_uint(v);
    h = (unsigned short)(u >> 16);
    const float lf = v - __uint_as_float(u & 0xffff0000u);
    l = (unsigned short)(__float_as_uint(lf) >> 16);
}

// ---------------------------------------------------------------------------
// MFMA GEMM, 2-phase double-buffered, XCD-swizzled: C = A[M,K] @ Bt[N,K]^T.
// ---------------------------------------------------------------------------
template <int BM, int BN, int AMODE, int EPI>
__global__ __launch_bounds__(256, 2) void mm_k(
    const float* __restrict__ Af,
    const unsigned short* __restrict__ Agh, const unsigned short* __restrict__ Agl,
    const unsigned short* __restrict__ Bgh, const unsigned short* __restrict__ Bgl,
    const float* __restrict__ bias,
    float* __restrict__ Cf,
    unsigned short* __restrict__ Ch, unsigned short* __restrict__ Cl,
    unsigned short* __restrict__ Ch2, unsigned short* __restrict__ Cl2,
    unsigned short* __restrict__ Ch3, unsigned short* __restrict__ Cl3,
    int K, int lda, int ldb, int ldc,
    long long zA, long long zB, long long zC, float alpha,
    const float* __restrict__ a1, const float* __restrict__ a2,
    float* __restrict__ si, float* __restrict__ sj, float* __restrict__ pstats)
{
    constexpr int ABUF = BM * 32, BBUF = BN * 32;
    __shared__ __align__(16) unsigned short SM[4 * ABUF + 4 * BBUF];
    unsigned short* const Ah_s = SM;
    unsigned short* const Al_s = SM + 2 * ABUF;
    unsigned short* const Bh_s = SM + 4 * ABUF;
    unsigned short* const Bl_s = SM + 4 * ABUF + 2 * BBUF;

    constexpr bool SWAPXY = (EPI == E_QKV);

    // XCD-chunked bijective block remap (grid size % 8 == 0 for all users)
    const int nbx = gridDim.x, nby = gridDim.y;
    int lin = blockIdx.x + nbx * (blockIdx.y + nby * blockIdx.z);
    const int ntot = nbx * nby * gridDim.z;
    lin = (lin & 7) * (ntot >> 3) + (lin >> 3);
    const int bx = lin % nbx;
    const int rem = lin / nbx;
    const int by = rem % nby;
    const int z  = rem / nby;

    if (AMODE == A_F32) { Af += (size_t)z * zA; }
    else { Agh += (size_t)z * zA; Agl += (size_t)z * zA; }
    Bgh += (size_t)z * zB; Bgl += (size_t)z * zB;
    if (Cf) Cf += (size_t)z * zC;

    constexpr int WC = (BN == 64) ? 1 : 2, WR = 4 / WC;
    constexpr int WM = BM / WR, WN = BN / WC, MF = WM / 16, NF = WN / 16;
    const int row0 = (SWAPXY ? by : bx) * BM;
    const int col0 = (SWAPXY ? bx : by) * BN;
    const int t = threadIdx.x, lane = t & 63, wid = t >> 6;
    const int fr = lane & 15, g = lane >> 4, fk = g * 8;
    const int wrow = (wid / WC) * WM, wcol = (wid % WC) * WN;
    const int rsub = lane >> 2, cbyt = (lane & 3) * 16;

    f32x4 acc[MF][NF] = {};

    auto stageB = [&](int k0, int pp) {
        #pragma unroll
        for (int q = 0; q < BN / 64; ++q) {
            const int r = wid * (BN / 4) + q * 16;
            const size_t gb = ((size_t)(col0 + r + rsub) * ldb + k0) * 2 + cbyt;
            gll16((const char*)Bgh + gb, (char*)(Bh_s + pp * BBUF) + (size_t)r * 64);
            gll16((const char*)Bgl + gb, (char*)(Bl_s + pp * BBUF) + (size_t)r * 64);
        }
    };
    auto stageA = [&](int k0, int pp) {
        if (AMODE == A_HL) {
            #pragma unroll
            for (int q = 0; q < BM / 64; ++q) {
                const int r = wid * (BM / 4) + q * 16;
                const size_t gb = ((size_t)(row0 + r + rsub) * lda + k0) * 2 + cbyt;
                gll16((const char*)Agh + gb, (char*)(Ah_s + pp * ABUF) + (size_t)r * 64);
                gll16((const char*)Agl + gb, (char*)(Al_s + pp * ABUF) + (size_t)r * 64);
            }
        } else {
            // f32 -> hi/lo reg-convert staging (BM == 128)
            const int r = t >> 1, h2 = t & 1;
            const float* srcA = Af + (size_t)(row0 + r) * lda + k0 + h2 * 16;
            const float4 v0 = ((const float4*)srcA)[0];
            const float4 v1 = ((const float4*)srcA)[1];
            const float4 v2 = ((const float4*)srcA)[2];
            const float4 v3 = ((const float4*)srcA)[3];
            unsigned hu[8], lu[8];
            split2(v0.x, v0.y, hu[0], lu[0]); split2(v0.z, v0.w, hu[1], lu[1]);
            split2(v1.x, v1.y, hu[2], lu[2]); split2(v1.z, v1.w, hu[3], lu[3]);
            split2(v2.x, v2.y, hu[4], lu[4]); split2(v2.z, v2.w, hu[5], lu[5]);
            split2(v3.x, v3.y, hu[6], lu[6]); split2(v3.z, v3.w, hu[7], lu[7]);
            uint4* dh = (uint4*)(Ah_s + pp * ABUF + r * 32 + h2 * 16);
            dh[0] = make_uint4(hu[0], hu[1], hu[2], hu[3]);
            dh[1] = make_uint4(hu[4], hu[5], hu[6], hu[7]);
            uint4* dl = (uint4*)(Al_s + pp * ABUF + r * 32 + h2 * 16);
            dl[0] = make_uint4(lu[0], lu[1], lu[2], lu[3]);
            dl[1] = make_uint4(lu[4], lu[5], lu[6], lu[7]);
        }
    };

    stageB(0, 0);
    stageA(0, 0);
    __syncthreads();

    const int NT = K / 32;
    int p = 0;
    for (int kt = 0; kt < NT; ++kt) {
        if (kt + 1 < NT) { stageB((kt + 1) * 32, p ^ 1); stageA((kt + 1) * 32, p ^ 1); }
        bf16x8 ah[MF], al[MF];
        #pragma unroll
        for (int mf = 0; mf < MF; ++mf) {
            const int off = p * ABUF + (wrow + mf * 16 + fr) * 32 + fk;
            ah[mf] = *(const bf16x8*)(Ah_s + off);
            al[mf] = *(const bf16x8*)(Al_s + off);
        }
        #pragma unroll
        for (int nf = 0; nf < NF; ++nf) {
            const int off = p * BBUF + (wcol + nf * 16 + fr) * 32 + fk;
            const bf16x8 bh = *(const bf16x8*)(Bh_s + off);
            const bf16x8 bl = *(const bf16x8*)(Bl_s + off);
            #pragma unroll
            for (int mf = 0; mf < MF; ++mf) {
                acc[mf][nf] = __builtin_amdgcn_mfma_f32_16x16x32_bf16(ah[mf], bh, acc[mf][nf], 0, 0, 0);
                acc[mf][nf] = __builtin_amdgcn_mfma_f32_16x16x32_bf16(al[mf], bh, acc[mf][nf], 0, 0, 0);
                acc[mf][nf] = __builtin_amdgcn_mfma_f32_16x16x32_bf16(ah[mf], bl, acc[mf][nf], 0, 0, 0);
            }
        }
        __syncthreads();
        p ^= 1;
    }

    // ---- epilogues (C/D layout: col = lane&15, row = (lane>>4)*4 + i [m89])
    float* ts = (float*)SM;  // transpose scratch overlays staging (post-barrier)

    if (EPI == E_BIAS || EPI == E_STATS) {
        float bv_[NF];
        if (EPI == E_BIAS) {
            #pragma unroll
            for (int nf = 0; nf < NF; ++nf) bv_[nf] = bias[col0 + wcol + nf * 16 + fr];
        }
        #pragma unroll
        for (int mf = 0; mf < MF; ++mf) {
            #pragma unroll
            for (int i = 0; i < 4; ++i) {
                const size_t row = (size_t)row0 + wrow + mf * 16 + g * 4 + i;
                const size_t co = row * ldc + col0 + wcol + fr;
                #pragma unroll
                for (int nf = 0; nf < NF; ++nf) {
                    float v = acc[mf][nf][i];
                    if (EPI == E_STATS) v *= alpha;
                    if (EPI == E_BIAS)  v += bv_[nf];
                    acc[mf][nf][i] = v;
                    Cf[co + nf * 16] = v;
                }
            }
        }
        if (EPI == E_STATS) {
            const int ty = by * WC + (wid % WC);
            #pragma unroll
            for (int mf = 0; mf < MF; ++mf) {
                #pragma unroll
                for (int i = 0; i < 4; ++i) {
                    float m = acc[mf][0][i], s;
                    #pragma unroll
                    for (int nf = 1; nf < NF; ++nf) m = fmaxf(m, acc[mf][nf][i]);
                    s = 0.f;
                    #pragma unroll
                    for (int nf = 0; nf < NF; ++nf) s += __expf(acc[mf][nf][i] - m);
                    #pragma unroll
                    for (int ofs = 1; ofs < 16; ofs <<= 1) {
                        const float om = __shfl_xor(m, ofs, 64);
                        const float os = __shfl_xor(s, ofs, 64);
                        const float nm = fmaxf(m, om);
                        s = s * __expf(m - nm) + os * __expf(om - nm);
                        m = nm;
                    }
                    if (fr == 0) {
                        const size_t row = (size_t)row0 + wrow + mf * 16 + g * 4 + i;
                        float* pp = pstats + (((size_t)z * 16 + ty) * Lc + row) * 2;
                        pp[0] = m; pp[1] = s;
                    }
                }
            }
        }
    }

    if (EPI == E_QKV) {
        float bv_[NF];
        #pragma unroll
        for (int nf = 0; nf < NF; ++nf) bv_[nf] = bias[col0 + wcol + nf * 16 + fr];
        #pragma unroll
        for (int mf = 0; mf < MF; ++mf)
            #pragma unroll
            for (int i = 0; i < 4; ++i)
                #pragma unroll
                for (int nf = 0; nf < NF; ++nf) acc[mf][nf][i] += bv_[nf];

        if (col0 < 512) {
            // Q (cols 0-255) / K (256-511): linear hi/lo write
            unsigned short* dH = (col0 < 256) ? Ch : Ch2;
            unsigned short* dL = (col0 < 256) ? Cl : Cl2;
            const int cl0 = col0 & 255;
            #pragma unroll
            for (int mf = 0; mf < MF; ++mf) {
                #pragma unroll
                for (int i = 0; i < 4; ++i) {
                    const size_t row = (size_t)row0 + wrow + mf * 16 + g * 4 + i;
                    const size_t co = row * ldc + cl0 + wcol + fr;
                    #pragma unroll
                    for (int nf = 0; nf < NF; ++nf) {
                        unsigned short hh16, ll16; split1(acc[mf][nf][i], hh16, ll16);
                        dH[co + nf * 16] = hh16; dL[co + nf * 16] = ll16;
                    }
                }
            }
        } else {
            // V (cols 512-767): transposed hi/lo write -> VT[b][d][l]
            const int bq_ = row0 >> 10, lg0 = row0 & 1023;
            #pragma unroll
            for (int hf = 0; hf < 2; ++hf) {
                if ((wid & 1) == hf) {
                    #pragma unroll
                    for (int mf = 0; mf < MF; ++mf)
                        #pragma unroll
                        for (int i = 0; i < 4; ++i) {
                            const int rr = wrow + mf * 16 + g * 4 + i;
                            #pragma unroll
                            for (int nf = 0; nf < NF; ++nf)
                                ts[rr * 65 + nf * 16 + fr] = acc[mf][nf][i];
                        }
                }
                __syncthreads();
                const int l = t & 127, db = (t >> 7) * 32;
                #pragma unroll
                for (int dd = 0; dd < 32; ++dd) {
                    const int dl = db + dd;
                    unsigned short hh16, ll16; split1(ts[l * 65 + dl], hh16, ll16);
                    const size_t o = ((size_t)bq_ * 256 + (col0 - 512) + hf * 64 + dl) * 1024 + lg0 + l;
                    Ch3[o] = hh16; Cl3[o] = ll16;
                }
                __syncthreads();
            }
        }
    }

    if (EPI == E_WHT) {
        // si/sj fused reductions (BN==64: each wave spans all 64 cols)
        float a1v[NF], a2v[NF];
        #pragma unroll
        for (int nf = 0; nf < NF; ++nf) {
            a1v[nf] = a1[(size_t)z * Dc + nf * 16 + fr];
            a2v[nf] = a2[(size_t)z * Dc + nf * 16 + fr];
        }
        #pragma unroll
        for (int mf = 0; mf < MF; ++mf) {
            #pragma unroll
            for (int i = 0; i < 4; ++i) {
                float p1 = 0.f, p2 = 0.f;
                #pragma unroll
                for (int nf = 0; nf < NF; ++nf) {
                    p1 = fmaf(acc[mf][nf][i], a1v[nf], p1);
                    p2 = fmaf(acc[mf][nf][i], a2v[nf], p2);
                }
                #pragma unroll
                for (int ofs = 1; ofs < 16; ofs <<= 1) {
                    p1 += __shfl_xor(p1, ofs, 64);
                    p2 += __shfl_xor(p2, ofs, 64);
                }
                if (fr == 0) {
                    const int row = row0 + wrow + mf * 16 + g * 4 + i;
                    si[(size_t)z * Nrows + row] = p1;
                    sj[(size_t)z * Nrows + row] = p2;
                }
            }
        }
        // transposed hi/lo write -> WhT[h*16+b][d][l]
        #pragma unroll
        for (int mf = 0; mf < MF; ++mf)
            #pragma unroll
            for (int i = 0; i < 4; ++i) {
                const int rr = wrow + mf * 16 + g * 4 + i;
                #pragma unroll
                for (int nf = 0; nf < NF; ++nf)
                    ts[rr * 65 + nf * 16 + fr] = acc[mf][nf][i];
            }
        __syncthreads();
        const int bq_ = row0 >> 10, lg0 = row0 & 1023;
        const int l = t & 127, db = (t >> 7) * 32;
        #pragma unroll
        for (int dd = 0; dd < 32; ++dd) {
            const int d = db + dd;
            unsigned short hh16, ll16; split1(ts[l * 65 + d], hh16, ll16);
            const size_t o = (((size_t)(z * 16 + bq_)) * 64 + d) * 1024 + lg0 + l;
            Ch[o] = hh16; Cl[o] = ll16;
        }
    }
}

// ---------------------------------------------------------------------------
// Fused GAT, 2-phase, swizzled, in-block softmax stats. 3 blocks/CU.
// ---------------------------------------------------------------------------
__global__ __launch_bounds__(256, 3) void gat_k(
    const float* __restrict__ si, const float* __restrict__ sj,
    const unsigned short* __restrict__ WhTh, const unsigned short* __restrict__ WhTl,
    float* __restrict__ att, unsigned short* __restrict__ gouth,
    unsigned short* __restrict__ goutl)
{
    constexpr int BBUF = 64 * 32;
    __shared__ __align__(16) unsigned short SMg[4 * BBUF];
    __shared__ __align__(16) float sjs[Lc];
    __shared__ float redm[4];
    unsigned short* const Bh_s = SMg;
    unsigned short* const Bl_s = SMg + 2 * BBUF;

    // XCD-chunked remap over grid (8,1,64) = 512 blocks
    int lin = blockIdx.x + 8 * blockIdx.z;
    lin = (lin & 7) * 64 + (lin >> 3);
    const int bx = lin & 7, z = lin >> 3;

    const int row0 = bx * 128;
    const int t = threadIdx.x, lane = t & 63, wid = t >> 6;
    const int fr = lane & 15, g = lane >> 4, fk = g * 8;
    const int wrow = wid * 32;
    const int hh = z >> 4, bb = z & 15;
    const int rsub = lane >> 2, cbyt = (lane & 3) * 16;

    const unsigned short* WhTh_z = WhTh + (size_t)z * 64 * 1024;
    const unsigned short* WhTl_z = WhTl + (size_t)z * 64 * 1024;
    const float* sjz = sj + (size_t)z * 1024;
    float* attz = att + ((size_t)z * 1024 + row0) * 1024;

    auto stageB = [&](int j0, int pp) {
        const int r = wid * 16;
        const size_t gb = ((size_t)(r + rsub) * 1024 + j0) * 2 + cbyt;
        gll16((const char*)WhTh_z + gb, (char*)(Bh_s + pp * BBUF) + (size_t)r * 64);
        gll16((const char*)WhTl_z + gb, (char*)(Bl_s + pp * BBUF) + (size_t)r * 64);
    };

    stageB(0, 0);
    ((float4*)sjs)[t] = ((const float4*)sjz)[t];
    __syncthreads();

    // block-wide max of sj row
    {
        const float4 v = ((const float4*)sjs)[t];
        float m4 = fmaxf(fmaxf(v.x, v.y), fmaxf(v.z, v.w));
        #pragma unroll
        for (int ofs = 32; ofs >= 1; ofs >>= 1) m4 = fmaxf(m4, __shfl_xor(m4, ofs, 64));
        if (lane == 0) redm[wid] = m4;
    }
    __syncthreads();
    const float smax = fmaxf(fmaxf(redm[0], redm[1]), fmaxf(redm[2], redm[3]));

    float siv[2], mr[2], inv[2];
    #pragma unroll
    for (int mf = 0; mf < 2; ++mf) {
        const int r = row0 + wrow + mf * 16 + fr;
        const float sv = si[(size_t)hh * Nrows + bb * 1024 + r];
        siv[mf] = sv;
        mr[mf] = lrelu(sv + smax);
        float s = 0.f;
        const float4* sp = (const float4*)sjs + g * 64;
        #pragma unroll 4
        for (int c = 0; c < 64; ++c) {
            const float4 w = sp[c];
            s += __expf(lrelu(sv + w.x) - mr[mf]) + __expf(lrelu(sv + w.y) - mr[mf])
               + __expf(lrelu(sv + w.z) - mr[mf]) + __expf(lrelu(sv + w.w) - mr[mf]);
        }
        s += __shfl_xor(s, 16, 64);
        s += __shfl_xor(s, 32, 64);
        inv[mf] = 1.0f / s;
    }

    f32x4 acc[2][4] = {};
    int p = 0;
    for (int kt = 0; kt < 32; ++kt) {
        const int j0 = kt * 32;
        if (kt < 31) stageB(j0 + 32, p ^ 1);
        bf16x8 ph[2], pl[2];
        #pragma unroll
        for (int mf = 0; mf < 2; ++mf) {
            const float4 s0 = ((const float4*)sjs)[(j0 >> 2) + g * 2];
            const float4 s1 = ((const float4*)sjs)[(j0 >> 2) + g * 2 + 1];
            float pr[8];
            pr[0] = __expf(lrelu(siv[mf] + s0.x) - mr[mf]) * inv[mf];
            pr[1] = __expf(lrelu(siv[mf] + s0.y) - mr[mf]) * inv[mf];
            pr[2] = __expf(lrelu(siv[mf] + s0.z) - mr[mf]) * inv[mf];
            pr[3] = __expf(lrelu(siv[mf] + s0.w) - mr[mf]) * inv[mf];
            pr[4] = __expf(lrelu(siv[mf] + s1.x) - mr[mf]) * inv[mf];
            pr[5] = __expf(lrelu(siv[mf] + s1.y) - mr[mf]) * inv[mf];
            pr[6] = __expf(lrelu(siv[mf] + s1.z) - mr[mf]) * inv[mf];
            pr[7] = __expf(lrelu(siv[mf] + s1.w) - mr[mf]) * inv[mf];
            float* ap = attz + (size_t)(wrow + mf * 16 + fr) * 1024 + j0 + fk;
            *(float4*)ap       = make_float4(pr[0], pr[1], pr[2], pr[3]);
            *(float4*)(ap + 4) = make_float4(pr[4], pr[5], pr[6], pr[7]);
            union { unsigned u[4]; bf16x8 v; } uh, ul;
            split2(pr[0], pr[1], uh.u[0], ul.u[0]);
            split2(pr[2], pr[3], uh.u[1], ul.u[1]);
            split2(pr[4], pr[5], uh.u[2], ul.u[2]);
            split2(pr[6], pr[7], uh.u[3], ul.u[3]);
            ph[mf] = uh.v; pl[mf] = ul.v;
        }
        #pragma unroll
        for (int nf = 0; nf < 4; ++nf) {
            const int off = p * BBUF + (nf * 16 + fr) * 32 + fk;
            const bf16x8 bh = *(const bf16x8*)(Bh_s + off);
            const bf16x8 bl = *(const bf16x8*)(Bl_s + off);
            #pragma unroll
            for (int mf = 0; mf < 2; ++mf) {
                acc[mf][nf] = __builtin_amdgcn_mfma_f32_16x16x32_bf16(ph[mf], bh, acc[mf][nf], 0, 0, 0);
                acc[mf][nf] = __builtin_amdgcn_mfma_f32_16x16x32_bf16(pl[mf], bh, acc[mf][nf], 0, 0, 0);
                acc[mf][nf] = __builtin_amdgcn_mfma_f32_16x16x32_bf16(ph[mf], bl, acc[mf][nf], 0, 0, 0);
            }
        }
        __syncthreads();
        p ^= 1;
    }
    #pragma unroll
    for (int mf = 0; mf < 2; ++mf) {
        #pragma unroll
        for (int i = 0; i < 4; ++i) {
            const int row_l = wrow + mf * 16 + g * 4 + i;
            const size_t base = ((size_t)bb * 1024 + row0 + row_l) * 256 + hh * 64 + fr;
            #pragma unroll
            for (int nf = 0; nf < 4; ++nf) {
                unsigned short hh16, ll16; split1(acc[mf][nf][i], hh16, ll16);
                gouth[base + nf * 16] = hh16;
                goutl[base + nf * 16] = ll16;
            }
        }
    }
}

// ---------------------------------------------------------------------------
// PV with fused softmax + folded rstat + fused output projection.
// BM=32, BN=256, grid (32,1,16) = 512 blocks -> 2 blocks/CU.
// ---------------------------------------------------------------------------
__global__ __launch_bounds__(256, 2) void pv_k(
    float* __restrict__ scores, const float* __restrict__ pstats,
    const unsigned short* __restrict__ VTh, const unsigned short* __restrict__ VTl,
    const unsigned short* __restrict__ WfcTh, const unsigned short* __restrict__ WfcTl,
    const float* __restrict__ bfc,
    float* __restrict__ tout, float* __restrict__ outp)
{
    constexpr int ABUF = 32 * 32, BBUF = 256 * 32;
    __shared__ __align__(16) unsigned short SMp[4 * ABUF + 4 * BBUF];  // 72 KB
    unsigned short* const Ah_s = SMp;
    unsigned short* const Al_s = SMp + 2 * ABUF;
    unsigned short* const Bh_s = SMp + 4 * ABUF;
    unsigned short* const Bl_s = SMp + 4 * ABUF + 2 * BBUF;

    // XCD-chunked remap over grid (32,1,16) = 512 blocks
    int lin = blockIdx.x + 32 * blockIdx.z;
    lin = (lin & 7) * 64 + (lin >> 3);
    const int bx = lin & 31, z = lin >> 5;

    const int row0 = bx * 32;
    const int t = threadIdx.x, lane = t & 63, wid = t >> 6;
    const int fr = lane & 15, g = lane >> 4, fk = g * 8;
    const int rsub = lane >> 2, cbyt = (lane & 3) * 16;

    float* sc = scores + ((size_t)z * Lc + row0) * Lc;
    const unsigned short* VTh_z = VTh + (size_t)z * HDc * Lc;
    const unsigned short* VTl_z = VTl + (size_t)z * HDc * Lc;

    auto stageB = [&](int k0, int pp) {
        #pragma unroll
        for (int q = 0; q < 4; ++q) {
            const int r = q * 64 + wid * 16;
            const size_t gb = ((size_t)(r + rsub) * Lc + k0) * 2 + cbyt;
            gll16((const char*)VTh_z + gb, (char*)(Bh_s + pp * BBUF) + (size_t)r * 64);
            gll16((const char*)VTl_z + gb, (char*)(Bl_s + pp * BBUF) + (size_t)r * 64);
        }
    };

    stageB(0, 0);  // get loads in flight before stats math

    // folded rstat: 8 lanes/row (q = t&7), 2 partials each + 3-step butterfly
    const int ar = t >> 3, cq = (t & 7) * 4;
    float m_ = -1e30f, s_ = 0.f;
    {
        const int q = t & 7;
        const float* pb = pstats + (((size_t)z * 16 + q * 2) * Lc + row0 + ar) * 2;
        #pragma unroll
        for (int j = 0; j < 2; ++j) {
            const float2 pp = *(const float2*)(pb + (size_t)j * Lc * 2);
            const float nm = fmaxf(m_, pp.x);
            s_ = s_ * __expf(m_ - nm) + pp.y * __expf(pp.x - nm);
            m_ = nm;
        }
        #pragma unroll
        for (int ofs = 1; ofs < 8; ofs <<= 1) {
            const float om = __shfl_xor(m_, ofs, 64);
            const float os = __shfl_xor(s_, ofs, 64);
            const float nm = fmaxf(m_, om);
            s_ = s_ * __expf(m_ - nm) + os * __expf(om - nm);
            m_ = nm;
        }
    }
    const float iv_ = 1.0f / s_;

    auto stageA = [&](int k0, int pp) {
        float* srcS = sc + (size_t)ar * Lc + k0 + cq;
        const float4 v0 = *(const float4*)srcS;
        float pr[4];
        pr[0] = __expf(v0.x - m_) * iv_; pr[1] = __expf(v0.y - m_) * iv_;
        pr[2] = __expf(v0.z - m_) * iv_; pr[3] = __expf(v0.w - m_) * iv_;
        *(float4*)srcS = make_float4(pr[0], pr[1], pr[2], pr[3]);
        unsigned hu[2], lu[2];
        split2(pr[0], pr[1], hu[0], lu[0]); split2(pr[2], pr[3], hu[1], lu[1]);
        *(uint2*)(Ah_s + pp * ABUF + ar * 32 + cq) = make_uint2(hu[0], hu[1]);
        *(uint2*)(Al_s + pp * ABUF + ar * 32 + cq) = make_uint2(lu[0], lu[1]);
    };

    f32x4 acc[2][4] = {};
    stageA(0, 0);
    __syncthreads();
    int p = 0;
    for (int kt = 0; kt < 32; ++kt) {
        if (kt < 31) { stageB((kt + 1) * 32, p ^ 1); stageA((kt + 1) * 32, p ^ 1); }
        bf16x8 ah[2], al[2];
        #pragma unroll
        for (int mf = 0; mf < 2; ++mf) {
            const int off = p * ABUF + (mf * 16 + fr) * 32 + fk;
            ah[mf] = *(const bf16x8*)(Ah_s + off);
            al[mf] = *(const bf16x8*)(Al_s + off);
        }
        #pragma unroll
        for (int nf = 0; nf < 4; ++nf) {
            const int off = p * BBUF + (wid * 64 + nf * 16 + fr) * 32 + fk;
            const bf16x8 bh = *(const bf16x8*)(Bh_s + off);
            const bf16x8 bl = *(const bf16x8*)(Bl_s + off);
            #pragma unroll
            for (int mf = 0; mf < 2; ++mf) {
                acc[mf][nf] = __builtin_amdgcn_mfma_f32_16x16x32_bf16(ah[mf], bh, acc[mf][nf], 0, 0, 0);
                acc[mf][nf] = __builtin_amdgcn_mfma_f32_16x16x32_bf16(al[mf], bh, acc[mf][nf], 0, 0, 0);
                acc[mf][nf] = __builtin_amdgcn_mfma_f32_16x16x32_bf16(ah[mf], bl, acc[mf][nf], 0, 0, 0);
            }
        }
        __syncthreads();
        p ^= 1;
    }

    // t_out write + stash tile to LDS for the fused output projection
    constexpr int TS = 258;  // f32 row stride (bank-spread)
    float* ts = (float*)SMp;
    #pragma unroll
    for (int mf = 0; mf < 2; ++mf) {
        #pragma unroll
        for (int i = 0; i < 4; ++i) {
            const size_t row = (size_t)row0 + mf * 16 + g * 4 + i;
            float* cp = tout + ((size_t)z * Lc + row) * HDc + wid * 64 + fr;
            #pragma unroll
            for (int nf = 0; nf < 4; ++nf) {
                cp[nf * 16] = acc[mf][nf][i];
                ts[(mf * 16 + g * 4 + i) * TS + wid * 64 + nf * 16 + fr] = acc[mf][nf][i];
            }
        }
    }
    __syncthreads();

    // out = t_out_tile @ WfcT^T + bfc  (K=256; each wave -> 16 out cols)
    const int ocol = wid * 16 + fr;
    f32x4 acc2[2] = {};
    #pragma unroll
    for (int kt2 = 0; kt2 < 8; ++kt2) {
        const int kk = kt2 * 32 + fk;
        const bf16x8 bh = *(const bf16x8*)(WfcTh + ocol * 256 + kk);
        const bf16x8 bl = *(const bf16x8*)(WfcTl + ocol * 256 + kk);
        #pragma unroll
        for (int mf = 0; mf < 2; ++mf) {
            const float* ap = ts + (mf * 16 + fr) * TS + kk;
            union { unsigned u[4]; bf16x8 v; } ahh, all_;
            split2(ap[0], ap[1], ahh.u[0], all_.u[0]);
            split2(ap[2], ap[3], ahh.u[1], all_.u[1]);
            split2(ap[4], ap[5], ahh.u[2], all_.u[2]);
            split2(ap[6], ap[7], ahh.u[3], all_.u[3]);
            acc2[mf] = __builtin_amdgcn_mfma_f32_16x16x32_bf16(ahh.v, bh, acc2[mf], 0, 0, 0);
            acc2[mf] = __builtin_amdgcn_mfma_f32_16x16x32_bf16(all_.v, bh, acc2[mf], 0, 0, 0);
            acc2[mf] = __builtin_amdgcn_mfma_f32_16x16x32_bf16(ahh.v, bl, acc2[mf], 0, 0, 0);
        }
    }
    const float bo = bfc[ocol];
    #pragma unroll
    for (int mf = 0; mf < 2; ++mf)
        #pragma unroll
        for (int i = 0; i < 4; ++i)
            outp[((size_t)z * Lc + row0 + mf * 16 + g * 4 + i) * Dc + ocol] = acc2[mf][i] + bo;
}

// 32x32 transpose + hi/lo split helper
__device__ __forceinline__ void tr32(const float* src, unsigned short* dh,
                                     unsigned short* dl, int R, int C,
                                     int r0, int c0, float (*tile)[33], int t)
{
    const int tc = t & 31, tr = t >> 5;
    #pragma unroll
    for (int rr = 0; rr < 32; rr += 8)
        tile[tr + rr][tc] = src[(size_t)(r0 + tr + rr) * C + c0 + tc];
    __syncthreads();
    #pragma unroll
    for (int rr = 0; rr < 32; rr += 8) {
        unsigned short h, l; split1(tile[tc][tr + rr], h, l);
        const size_t o = (size_t)(c0 + tr + rr) * R + r0 + tc;
        dh[o] = h; dl[o] = l;
    }
}

// all weight transposes + bias concat in one launch
__global__ __launch_bounds__(256) void prep_k(
    const float* __restrict__ W, const float* __restrict__ Wq,
    const float* __restrict__ Wk, const float* __restrict__ Wv,
    const float* __restrict__ Wfc, const float* __restrict__ bq,
    const float* __restrict__ bk, const float* __restrict__ bv,
    unsigned short* __restrict__ WTh, unsigned short* __restrict__ WTl,
    unsigned short* __restrict__ Wch, unsigned short* __restrict__ Wcl,
    unsigned short* __restrict__ WfcTh, unsigned short* __restrict__ WfcTl,
    float* __restrict__ bcat)
{
    __shared__ float tile[32][33];
    const int bx = blockIdx.x, by = blockIdx.y, t = threadIdx.x;
    if (by == 0) {
        if (bx >= 32) return;
        const int h = bx >> 3, tl = bx & 7;
        tr32(W + (size_t)h * Fc * Dc, WTh + (size_t)h * Dc * Fc,
             WTl + (size_t)h * Dc * Fc, Fc, Dc, (tl >> 1) * 32, (tl & 1) * 32, tile, t);
    } else if (by <= 3) {
        const float* s = (by == 1) ? Wq : (by == 2) ? Wk : Wv;
        const size_t off = (size_t)(by - 1) * HDc * HDc;
        tr32(s, Wch + off, Wcl + off, HDc, HDc, (bx >> 3) * 32, (bx & 7) * 32, tile, t);
    } else {
        if (bx < 16) {
            tr32(Wfc, WfcTh, WfcTl, HDc, Dc, (bx >> 1) * 32, (bx & 1) * 32, tile, t);
        } else if (bx == 16) {
            bcat[t] = bq[t]; bcat[256 + t] = bk[t]; bcat[512 + t] = bv[t];
        }
    }
}

extern "C" void kernel_launch(void* const* d_in, const int* in_sizes, int n_in,
                              void* d_out, int out_size, void* d_ws, size_t ws_size,
                              hipStream_t stream)
{
    const float* x   = (const float*)d_in[0];
    const float* W   = (const float*)d_in[1];
    const float* a1  = (const float*)d_in[2];
    const float* a2  = (const float*)d_in[3];
    const float* Wq  = (const float*)d_in[4];
    const float* bq  = (const float*)d_in[5];
    const float* Wk  = (const float*)d_in[6];
    const float* bk  = (const float*)d_in[7];
    const float* Wv  = (const float*)d_in[8];
    const float* bv  = (const float*)d_in[9];
    const float* Wfc = (const float*)d_in[10];
    const float* bfc = (const float*)d_in[11];

    float* outp    = (float*)d_out;
    float* gat_att = outp + (size_t)Bc * Lc * Dc;
    float* t_att   = gat_att + (size_t)Hc * Bc * Lc * Lc;
    float* t_out   = t_att + (size_t)Bc * Lc * Lc;

    constexpr size_t MB = 1024 * 1024;
    char* wsb = (char*)d_ws;
    // region 0 (0-16MB): WhT-hl -> VT-hl (WhT dead after gat_k)
    unsigned short* WhTh = (unsigned short*)wsb;
    unsigned short* WhTl = WhTh + (size_t)64 * 64 * 1024;
    unsigned short* VTh = WhTh; unsigned short* VTl = WhTl;
    // region 1 (16-32MB): gout-hl
    unsigned short* gouth = (unsigned short*)(wsb + 16 * MB);
    unsigned short* goutl = gouth + (size_t)Nrows * HDc;
    // region 2 (32-48MB): Q-hl
    unsigned short* Qh = (unsigned short*)(wsb + 32 * MB);
    unsigned short* Ql = Qh + (size_t)Nrows * HDc;
    // region 3 (48-64MB): K-hl
    unsigned short* Kh = (unsigned short*)(wsb + 48 * MB);
    unsigned short* Kl = Kh + (size_t)Nrows * HDc;
    // region 4 (64MB+): small buffers
    float* si  = (float*)(wsb + 64 * MB);
    float* sj  = si + Hc * Nrows;
    float* pstats = sj + Hc * Nrows;                  // [16][16][1024][2]
    unsigned short* WTh = (unsigned short*)(pstats + (size_t)Bc * 16 * Lc * 2);  // [4][64][128]
    unsigned short* WTl = WTh + Hc * Dc * Fc;
    unsigned short* Wch = WTl + Hc * Dc * Fc;         // [768][256]
    unsigned short* Wcl = Wch + 768 * HDc;
    unsigned short* WfcTh = Wcl + 768 * HDc;          // [64][256]
    unsigned short* WfcTl = WfcTh + Dc * HDc;
    float* bcat = (float*)(WfcTl + Dc * HDc);         // [768]

    const dim3 blk(256);

    // 0. weight prep (one launch)
    prep_k<<<dim3(64, 5), blk, 0, stream>>>(W, Wq, Wk, Wv, Wfc, bq, bk, bv,
        WTh, WTl, Wch, Wcl, WfcTh, WfcTl, bcat);

    // 1. WhT-hl = (x @ W[h]^T)^T + fused si/sj
    mm_k<128, 64, A_F32, E_WHT><<<dim3(Nrows / 128, 1, Hc), blk, 0, stream>>>(
        x, nullptr, nullptr, WTh, WTl, nullptr, nullptr,
        WhTh, WhTl, nullptr, nullptr, nullptr, nullptr,
        Fc, Fc, Fc, 0, 0LL, (long long)Dc * Fc, 0LL, 1.f, a1, a2, si, sj, nullptr);

    // 2. fused GAT (stats in-block): gat_att + gout-hl
    gat_k<<<dim3(Lc / 128, 1, 64), blk, 0, stream>>>(si, sj,
        WhTh, WhTl, gat_att, gouth, goutl);

    // 3. fused QKV projection (col-block on x for XCD A-panel sharing)
    mm_k<128, 128, A_HL, E_QKV><<<dim3(6, Nrows / 128, 1), blk, 0, stream>>>(
        nullptr, gouth, goutl, Wch, Wcl, bcat, nullptr,
        Qh, Ql, Kh, Kl, VTh, VTl,
        HDc, HDc, HDc, HDc, 0LL, 0LL, 0LL, 1.f, nullptr, nullptr, nullptr, nullptr, nullptr);

    // 4. raw scaled scores -> t_att region + partial row stats
    mm_k<128, 128, A_HL, E_STATS><<<dim3(8, 8, Bc), blk, 0, stream>>>(
        nullptr, Qh, Ql, Kh, Kl, nullptr, t_att,
        nullptr, nullptr, nullptr, nullptr, nullptr, nullptr,
        HDc, HDc, HDc, Lc, (long long)Lc * HDc, (long long)Lc * HDc,
        (long long)Lc * Lc, 0.0625f, nullptr, nullptr, nullptr, nullptr, pstats);

    // 5. PV: folded rstat + fused softmax + t_out + fused out-projection
    //    BM=32 -> 512 blocks -> 2 blocks/CU
    pv_k<<<dim3(32, 1, Bc), blk, 0, stream>>>(t_att, pstats, VTh, VTl,
        WfcTh, WfcTl, bfc, t_out, outp);
}

// Round 9
// 195.143 us; speedup vs baseline: 7.7028x; 1.2050x over previous
//
#include <hip/hip_runtime.h>

// TemporalGAT on MI355X — round 9: f16 2-term split MFMA (A = ah+al f16 pair
// ~22-bit mantissa; B = single f16, 11-bit). 2 MFMAs per fragment (was 3 bf16),
// B-side memory/LDS/staging halved. Structure otherwise round-8 (6 launches,
// XCD swizzle, fused epilogues, 2-phase pipelines).
// B=16, L=1024, F=128, H=4, D=64, HD=256, N=B*L=16384

constexpr int Bc = 16, Lc = 1024, Fc = 128, Hc = 4, Dc = 64, HDc = 256;
constexpr int Nrows = Bc * Lc;  // 16384
#define ALPHA_SLOPE 0.2f

typedef __attribute__((ext_vector_type(8))) _Float16 f16x8;
typedef __attribute__((ext_vector_type(4))) float f32x4;

enum { A_F32 = 0, A_HL = 1 };
enum { E_WHT = 2, E_STATS = 3, E_QKV = 4 };

__device__ __forceinline__ float lrelu(float x) { return x > 0.f ? x : ALPHA_SLOPE * x; }

__device__ __forceinline__ void gll16(const void* g, void* l) {
    __builtin_amdgcn_global_load_lds(
        (const __attribute__((address_space(1))) void*)g,
        (__attribute__((address_space(3))) void*)l, 16, 0, 0);
}

// f32 -> f16 conversions. A-operands: 2-term split (h + residual l).
// B-operands: single f16 (error budget: 2^-12 relative, see round notes).
__device__ __forceinline__ unsigned short cv1(float v) {
    union { _Float16 f; unsigned short u; } c; c.f = (_Float16)v; return c.u;
}
__device__ __forceinline__ void sp2(float a, float b, unsigned& h, unsigned& l) {
    const _Float16 ha = (_Float16)a, hb = (_Float16)b;
    union { _Float16 f[2]; unsigned u; } H, L;
    H.f[0] = ha; H.f[1] = hb;
    L.f[0] = (_Float16)(a - (float)ha);
    L.f[1] = (_Float16)(b - (float)hb);
    h = H.u; l = L.u;
}
__device__ __forceinline__ void sp1(float v, unsigned short& h, unsigned short& l) {
    const _Float16 hv = (_Float16)v;
    union { _Float16 f; unsigned short u; } H, L;
    H.f = hv; L.f = (_Float16)(v - (float)hv);
    h = H.u; l = L.u;
}

// ---------------------------------------------------------------------------
// MFMA GEMM, 2-phase double-buffered, XCD-swizzled: C = A[M,K] @ Bt[N,K]^T.
// A = f16 pair (or f32 reg-converted); B = single f16.
// ---------------------------------------------------------------------------
template <int BM, int BN, int AMODE, int EPI>
__global__ __launch_bounds__(256, 2) void mm_k(
    const float* __restrict__ Af,
    const unsigned short* __restrict__ Agh, const unsigned short* __restrict__ Agl,
    const unsigned short* __restrict__ Bg,
    const float* __restrict__ bias,
    float* __restrict__ Cf,
    unsigned short* __restrict__ Ch, unsigned short* __restrict__ Cl,
    unsigned short* __restrict__ Ch2, unsigned short* __restrict__ Ch3,
    int K, int lda, int ldb, int ldc,
    long long zA, long long zB, long long zC, float alpha,
    const float* __restrict__ a1, const float* __restrict__ a2,
    float* __restrict__ si, float* __restrict__ sj, float* __restrict__ pstats)
{
    constexpr int ABUF = BM * 32, BBUF = BN * 32;
    __shared__ __align__(16) unsigned short SM[4 * ABUF + 2 * BBUF];
    unsigned short* const Ah_s = SM;
    unsigned short* const Al_s = SM + 2 * ABUF;
    unsigned short* const Bf_s = SM + 4 * ABUF;

    constexpr bool SWAPXY = (EPI == E_QKV);

    // XCD-chunked bijective block remap (grid size % 8 == 0 for all users)
    const int nbx = gridDim.x, nby = gridDim.y;
    int lin = blockIdx.x + nbx * (blockIdx.y + nby * blockIdx.z);
    const int ntot = nbx * nby * gridDim.z;
    lin = (lin & 7) * (ntot >> 3) + (lin >> 3);
    const int bx = lin % nbx;
    const int rem = lin / nbx;
    const int by = rem % nby;
    const int z  = rem / nby;

    if (AMODE == A_F32) { Af += (size_t)z * zA; }
    else { Agh += (size_t)z * zA; Agl += (size_t)z * zA; }
    Bg += (size_t)z * zB;
    if (Cf) Cf += (size_t)z * zC;

    constexpr int WC = (BN == 64) ? 1 : 2, WR = 4 / WC;
    constexpr int WM = BM / WR, WN = BN / WC, MF = WM / 16, NF = WN / 16;
    const int row0 = (SWAPXY ? by : bx) * BM;
    const int col0 = (SWAPXY ? bx : by) * BN;
    const int t = threadIdx.x, lane = t & 63, wid = t >> 6;
    const int fr = lane & 15, g = lane >> 4, fk = g * 8;
    const int wrow = (wid / WC) * WM, wcol = (wid % WC) * WN;
    const int rsub = lane >> 2, cbyt = (lane & 3) * 16;

    f32x4 acc[MF][NF] = {};

    auto stageB = [&](int k0, int pp) {
        #pragma unroll
        for (int q = 0; q < BN / 64; ++q) {
            const int r = wid * (BN / 4) + q * 16;
            const size_t gb = ((size_t)(col0 + r + rsub) * ldb + k0) * 2 + cbyt;
            gll16((const char*)Bg + gb, (char*)(Bf_s + pp * BBUF) + (size_t)r * 64);
        }
    };
    auto stageA = [&](int k0, int pp) {
        if (AMODE == A_HL) {
            #pragma unroll
            for (int q = 0; q < BM / 64; ++q) {
                const int r = wid * (BM / 4) + q * 16;
                const size_t gb = ((size_t)(row0 + r + rsub) * lda + k0) * 2 + cbyt;
                gll16((const char*)Agh + gb, (char*)(Ah_s + pp * ABUF) + (size_t)r * 64);
                gll16((const char*)Agl + gb, (char*)(Al_s + pp * ABUF) + (size_t)r * 64);
            }
        } else {
            // f32 -> f16 pair reg-convert staging (BM == 128)
            const int r = t >> 1, h2 = t & 1;
            const float* srcA = Af + (size_t)(row0 + r) * lda + k0 + h2 * 16;
            const float4 v0 = ((const float4*)srcA)[0];
            const float4 v1 = ((const float4*)srcA)[1];
            const float4 v2 = ((const float4*)srcA)[2];
            const float4 v3 = ((const float4*)srcA)[3];
            unsigned hu[8], lu[8];
            sp2(v0.x, v0.y, hu[0], lu[0]); sp2(v0.z, v0.w, hu[1], lu[1]);
            sp2(v1.x, v1.y, hu[2], lu[2]); sp2(v1.z, v1.w, hu[3], lu[3]);
            sp2(v2.x, v2.y, hu[4], lu[4]); sp2(v2.z, v2.w, hu[5], lu[5]);
            sp2(v3.x, v3.y, hu[6], lu[6]); sp2(v3.z, v3.w, hu[7], lu[7]);
            uint4* dh = (uint4*)(Ah_s + pp * ABUF + r * 32 + h2 * 16);
            dh[0] = make_uint4(hu[0], hu[1], hu[2], hu[3]);
            dh[1] = make_uint4(hu[4], hu[5], hu[6], hu[7]);
            uint4* dl = (uint4*)(Al_s + pp * ABUF + r * 32 + h2 * 16);
            dl[0] = make_uint4(lu[0], lu[1], lu[2], lu[3]);
            dl[1] = make_uint4(lu[4], lu[5], lu[6], lu[7]);
        }
    };

    stageB(0, 0);
    stageA(0, 0);
    __syncthreads();

    const int NT = K / 32;
    int p = 0;
    for (int kt = 0; kt < NT; ++kt) {
        if (kt + 1 < NT) { stageB((kt + 1) * 32, p ^ 1); stageA((kt + 1) * 32, p ^ 1); }
        f16x8 ah[MF], al[MF];
        #pragma unroll
        for (int mf = 0; mf < MF; ++mf) {
            const int off = p * ABUF + (wrow + mf * 16 + fr) * 32 + fk;
            ah[mf] = *(const f16x8*)(Ah_s + off);
            al[mf] = *(const f16x8*)(Al_s + off);
        }
        #pragma unroll
        for (int nf = 0; nf < NF; ++nf) {
            const int off = p * BBUF + (wcol + nf * 16 + fr) * 32 + fk;
            const f16x8 bf = *(const f16x8*)(Bf_s + off);
            #pragma unroll
            for (int mf = 0; mf < MF; ++mf) {
                acc[mf][nf] = __builtin_amdgcn_mfma_f32_16x16x32_f16(ah[mf], bf, acc[mf][nf], 0, 0, 0);
                acc[mf][nf] = __builtin_amdgcn_mfma_f32_16x16x32_f16(al[mf], bf, acc[mf][nf], 0, 0, 0);
            }
        }
        __syncthreads();
        p ^= 1;
    }

    // ---- epilogues (C/D layout: col = lane&15, row = (lane>>4)*4 + i [m89])
    float* ts = (float*)SM;  // transpose scratch overlays staging (post-barrier)

    if (EPI == E_STATS) {
        #pragma unroll
        for (int mf = 0; mf < MF; ++mf) {
            #pragma unroll
            for (int i = 0; i < 4; ++i) {
                const size_t row = (size_t)row0 + wrow + mf * 16 + g * 4 + i;
                const size_t co = row * ldc + col0 + wcol + fr;
                #pragma unroll
                for (int nf = 0; nf < NF; ++nf) {
                    float v = acc[mf][nf][i] * alpha;
                    acc[mf][nf][i] = v;
                    Cf[co + nf * 16] = v;
                }
            }
        }
        const int ty = by * WC + (wid % WC);
        #pragma unroll
        for (int mf = 0; mf < MF; ++mf) {
            #pragma unroll
            for (int i = 0; i < 4; ++i) {
                float m = acc[mf][0][i], s;
                #pragma unroll
                for (int nf = 1; nf < NF; ++nf) m = fmaxf(m, acc[mf][nf][i]);
                s = 0.f;
                #pragma unroll
                for (int nf = 0; nf < NF; ++nf) s += __expf(acc[mf][nf][i] - m);
                #pragma unroll
                for (int ofs = 1; ofs < 16; ofs <<= 1) {
                    const float om = __shfl_xor(m, ofs, 64);
                    const float os = __shfl_xor(s, ofs, 64);
                    const float nm = fmaxf(m, om);
                    s = s * __expf(m - nm) + os * __expf(om - nm);
                    m = nm;
                }
                if (fr == 0) {
                    const size_t row = (size_t)row0 + wrow + mf * 16 + g * 4 + i;
                    float* pp = pstats + (((size_t)z * 16 + ty) * Lc + row) * 2;
                    pp[0] = m; pp[1] = s;
                }
            }
        }
    }

    if (EPI == E_QKV) {
        float bv_[NF];
        #pragma unroll
        for (int nf = 0; nf < NF; ++nf) bv_[nf] = bias[col0 + wcol + nf * 16 + fr];
        #pragma unroll
        for (int mf = 0; mf < MF; ++mf)
            #pragma unroll
            for (int i = 0; i < 4; ++i)
                #pragma unroll
                for (int nf = 0; nf < NF; ++nf) acc[mf][nf][i] += bv_[nf];

        if (col0 < 256) {
            // Q (cols 0-255): f16 pair write (A-operand of QK)
            #pragma unroll
            for (int mf = 0; mf < MF; ++mf) {
                #pragma unroll
                for (int i = 0; i < 4; ++i) {
                    const size_t row = (size_t)row0 + wrow + mf * 16 + g * 4 + i;
                    const size_t co = row * ldc + col0 + wcol + fr;
                    #pragma unroll
                    for (int nf = 0; nf < NF; ++nf) {
                        unsigned short hh16, ll16; sp1(acc[mf][nf][i], hh16, ll16);
                        Ch[co + nf * 16] = hh16; Cl[co + nf * 16] = ll16;
                    }
                }
            }
        } else if (col0 < 512) {
            // K (cols 256-511): single f16 write (B-operand of QK)
            const int cl0 = col0 & 255;
            #pragma unroll
            for (int mf = 0; mf < MF; ++mf) {
                #pragma unroll
                for (int i = 0; i < 4; ++i) {
                    const size_t row = (size_t)row0 + wrow + mf * 16 + g * 4 + i;
                    const size_t co = row * ldc + cl0 + wcol + fr;
                    #pragma unroll
                    for (int nf = 0; nf < NF; ++nf)
                        Ch2[co + nf * 16] = cv1(acc[mf][nf][i]);
                }
            }
        } else {
            // V (cols 512-767): transposed single-f16 write -> VT[b][d][l]
            const int bq_ = row0 >> 10, lg0 = row0 & 1023;
            #pragma unroll
            for (int hf = 0; hf < 2; ++hf) {
                if ((wid & 1) == hf) {
                    #pragma unroll
                    for (int mf = 0; mf < MF; ++mf)
                        #pragma unroll
                        for (int i = 0; i < 4; ++i) {
                            const int rr = wrow + mf * 16 + g * 4 + i;
                            #pragma unroll
                            for (int nf = 0; nf < NF; ++nf)
                                ts[rr * 65 + nf * 16 + fr] = acc[mf][nf][i];
                        }
                }
                __syncthreads();
                const int l = t & 127, db = (t >> 7) * 32;
                #pragma unroll
                for (int dd = 0; dd < 32; ++dd) {
                    const int dl = db + dd;
                    const size_t o = ((size_t)bq_ * 256 + (col0 - 512) + hf * 64 + dl) * 1024 + lg0 + l;
                    Ch3[o] = cv1(ts[l * 65 + dl]);
                }
                __syncthreads();
            }
        }
    }

    if (EPI == E_WHT) {
        // si/sj fused reductions (BN==64: each wave spans all 64 cols)
        float a1v[NF], a2v[NF];
        #pragma unroll
        for (int nf = 0; nf < NF; ++nf) {
            a1v[nf] = a1[(size_t)z * Dc + nf * 16 + fr];
            a2v[nf] = a2[(size_t)z * Dc + nf * 16 + fr];
        }
        #pragma unroll
        for (int mf = 0; mf < MF; ++mf) {
            #pragma unroll
            for (int i = 0; i < 4; ++i) {
                float p1 = 0.f, p2 = 0.f;
                #pragma unroll
                for (int nf = 0; nf < NF; ++nf) {
                    p1 = fmaf(acc[mf][nf][i], a1v[nf], p1);
                    p2 = fmaf(acc[mf][nf][i], a2v[nf], p2);
                }
                #pragma unroll
                for (int ofs = 1; ofs < 16; ofs <<= 1) {
                    p1 += __shfl_xor(p1, ofs, 64);
                    p2 += __shfl_xor(p2, ofs, 64);
                }
                if (fr == 0) {
                    const int row = row0 + wrow + mf * 16 + g * 4 + i;
                    si[(size_t)z * Nrows + row] = p1;
                    sj[(size_t)z * Nrows + row] = p2;
                }
            }
        }
        // transposed single-f16 write -> WhT[h*16+b][d][l] (B-operand of gat)
        #pragma unroll
        for (int mf = 0; mf < MF; ++mf)
            #pragma unroll
            for (int i = 0; i < 4; ++i) {
                const int rr = wrow + mf * 16 + g * 4 + i;
                #pragma unroll
                for (int nf = 0; nf < NF; ++nf)
                    ts[rr * 65 + nf * 16 + fr] = acc[mf][nf][i];
            }
        __syncthreads();
        const int bq_ = row0 >> 10, lg0 = row0 & 1023;
        const int l = t & 127, db = (t >> 7) * 32;
        #pragma unroll
        for (int dd = 0; dd < 32; ++dd) {
            const int d = db + dd;
            const size_t o = (((size_t)(z * 16 + bq_)) * 64 + d) * 1024 + lg0 + l;
            Ch[o] = cv1(ts[l * 65 + d]);
        }
    }
}

// ---------------------------------------------------------------------------
// Fused GAT, 2-phase, swizzled, in-block softmax stats. B = single f16.
// ---------------------------------------------------------------------------
__global__ __launch_bounds__(256, 3) void gat_k(
    const float* __restrict__ si, const float* __restrict__ sj,
    const unsigned short* __restrict__ WhTf,
    float* __restrict__ att, unsigned short* __restrict__ gouth,
    unsigned short* __restrict__ goutl)
{
    constexpr int BBUF = 64 * 32;
    __shared__ __align__(16) unsigned short SMg[2 * BBUF];
    __shared__ __align__(16) float sjs[Lc];
    __shared__ float redm[4];
    unsigned short* const Bf_s = SMg;

    // XCD-chunked remap over grid (8,1,64) = 512 blocks
    int lin = blockIdx.x + 8 * blockIdx.z;
    lin = (lin & 7) * 64 + (lin >> 3);
    const int bx = lin & 7, z = lin >> 3;

    const int row0 = bx * 128;
    const int t = threadIdx.x, lane = t & 63, wid = t >> 6;
    const int fr = lane & 15, g = lane >> 4, fk = g * 8;
    const int wrow = wid * 32;
    const int hh = z >> 4, bb = z & 15;
    const int rsub = lane >> 2, cbyt = (lane & 3) * 16;

    const unsigned short* WhTf_z = WhTf + (size_t)z * 64 * 1024;
    const float* sjz = sj + (size_t)z * 1024;
    float* attz = att + ((size_t)z * 1024 + row0) * 1024;

    auto stageB = [&](int j0, int pp) {
        const int r = wid * 16;
        const size_t gb = ((size_t)(r + rsub) * 1024 + j0) * 2 + cbyt;
        gll16((const char*)WhTf_z + gb, (char*)(Bf_s + pp * BBUF) + (size_t)r * 64);
    };

    stageB(0, 0);
    ((float4*)sjs)[t] = ((const float4*)sjz)[t];
    __syncthreads();

    // block-wide max of sj row
    {
        const float4 v = ((const float4*)sjs)[t];
        float m4 = fmaxf(fmaxf(v.x, v.y), fmaxf(v.z, v.w));
        #pragma unroll
        for (int ofs = 32; ofs >= 1; ofs >>= 1) m4 = fmaxf(m4, __shfl_xor(m4, ofs, 64));
        if (lane == 0) redm[wid] = m4;
    }
    __syncthreads();
    const float smax = fmaxf(fmaxf(redm[0], redm[1]), fmaxf(redm[2], redm[3]));

    float siv[2], mr[2], inv[2];
    #pragma unroll
    for (int mf = 0; mf < 2; ++mf) {
        const int r = row0 + wrow + mf * 16 + fr;
        const float sv = si[(size_t)hh * Nrows + bb * 1024 + r];
        siv[mf] = sv;
        mr[mf] = lrelu(sv + smax);
        float s = 0.f;
        const float4* sp = (const float4*)sjs + g * 64;
        #pragma unroll 4
        for (int c = 0; c < 64; ++c) {
            const float4 w = sp[c];
            s += __expf(lrelu(sv + w.x) - mr[mf]) + __expf(lrelu(sv + w.y) - mr[mf])
               + __expf(lrelu(sv + w.z) - mr[mf]) + __expf(lrelu(sv + w.w) - mr[mf]);
        }
        s += __shfl_xor(s, 16, 64);
        s += __shfl_xor(s, 32, 64);
        inv[mf] = 1.0f / s;
    }

    f32x4 acc[2][4] = {};
    int p = 0;
    for (int kt = 0; kt < 32; ++kt) {
        const int j0 = kt * 32;
        if (kt < 31) stageB(j0 + 32, p ^ 1);
        f16x8 ph[2], pl[2];
        #pragma unroll
        for (int mf = 0; mf < 2; ++mf) {
            const float4 s0 = ((const float4*)sjs)[(j0 >> 2) + g * 2];
            const float4 s1 = ((const float4*)sjs)[(j0 >> 2) + g * 2 + 1];
            float pr[8];
            pr[0] = __expf(lrelu(siv[mf] + s0.x) - mr[mf]) * inv[mf];
            pr[1] = __expf(lrelu(siv[mf] + s0.y) - mr[mf]) * inv[mf];
            pr[2] = __expf(lrelu(siv[mf] + s0.z) - mr[mf]) * inv[mf];
            pr[3] = __expf(lrelu(siv[mf] + s0.w) - mr[mf]) * inv[mf];
            pr[4] = __expf(lrelu(siv[mf] + s1.x) - mr[mf]) * inv[mf];
            pr[5] = __expf(lrelu(siv[mf] + s1.y) - mr[mf]) * inv[mf];
            pr[6] = __expf(lrelu(siv[mf] + s1.z) - mr[mf]) * inv[mf];
            pr[7] = __expf(lrelu(siv[mf] + s1.w) - mr[mf]) * inv[mf];
            float* ap = attz + (size_t)(wrow + mf * 16 + fr) * 1024 + j0 + fk;
            *(float4*)ap       = make_float4(pr[0], pr[1], pr[2], pr[3]);
            *(float4*)(ap + 4) = make_float4(pr[4], pr[5], pr[6], pr[7]);
            union { unsigned u[4]; f16x8 v; } uh, ul;
            sp2(pr[0], pr[1], uh.u[0], ul.u[0]);
            sp2(pr[2], pr[3], uh.u[1], ul.u[1]);
            sp2(pr[4], pr[5], uh.u[2], ul.u[2]);
            sp2(pr[6], pr[7], uh.u[3], ul.u[3]);
            ph[mf] = uh.v; pl[mf] = ul.v;
        }
        #pragma unroll
        for (int nf = 0; nf < 4; ++nf) {
            const int off = p * BBUF + (nf * 16 + fr) * 32 + fk;
            const f16x8 bf = *(const f16x8*)(Bf_s + off);
            #pragma unroll
            for (int mf = 0; mf < 2; ++mf) {
                acc[mf][nf] = __builtin_amdgcn_mfma_f32_16x16x32_f16(ph[mf], bf, acc[mf][nf], 0, 0, 0);
                acc[mf][nf] = __builtin_amdgcn_mfma_f32_16x16x32_f16(pl[mf], bf, acc[mf][nf], 0, 0, 0);
            }
        }
        __syncthreads();
        p ^= 1;
    }
    #pragma unroll
    for (int mf = 0; mf < 2; ++mf) {
        #pragma unroll
        for (int i = 0; i < 4; ++i) {
            const int row_l = wrow + mf * 16 + g * 4 + i;
            const size_t base = ((size_t)bb * 1024 + row0 + row_l) * 256 + hh * 64 + fr;
            #pragma unroll
            for (int nf = 0; nf < 4; ++nf) {
                unsigned short hh16, ll16; sp1(acc[mf][nf][i], hh16, ll16);
                gouth[base + nf * 16] = hh16;
                goutl[base + nf * 16] = ll16;
            }
        }
    }
}

// ---------------------------------------------------------------------------
// PV with fused softmax + folded rstat + fused output projection.
// BM=32, BN=256, grid (32,1,16); A = P f16 pair, B = VT single f16.
// ---------------------------------------------------------------------------
__global__ __launch_bounds__(256, 2) void pv_k(
    float* __restrict__ scores, const float* __restrict__ pstats,
    const unsigned short* __restrict__ VTf,
    const unsigned short* __restrict__ WfcTf, const float* __restrict__ bfc,
    float* __restrict__ tout, float* __restrict__ outp)
{
    constexpr int ABUF = 32 * 32, BBUF = 256 * 32;
    __shared__ __align__(16) unsigned short SMp[4 * ABUF + 2 * BBUF];  // 40 KB
    unsigned short* const Ah_s = SMp;
    unsigned short* const Al_s = SMp + 2 * ABUF;
    unsigned short* const Bf_s = SMp + 4 * ABUF;

    // XCD-chunked remap over grid (32,1,16) = 512 blocks
    int lin = blockIdx.x + 32 * blockIdx.z;
    lin = (lin & 7) * 64 + (lin >> 3);
    const int bx = lin & 31, z = lin >> 5;

    const int row0 = bx * 32;
    const int t = threadIdx.x, lane = t & 63, wid = t >> 6;
    const int fr = lane & 15, g = lane >> 4, fk = g * 8;
    const int rsub = lane >> 2, cbyt = (lane & 3) * 16;

    float* sc = scores + ((size_t)z * Lc + row0) * Lc;
    const unsigned short* VTf_z = VTf + (size_t)z * HDc * Lc;

    auto stageB = [&](int k0, int pp) {
        #pragma unroll
        for (int q = 0; q < 4; ++q) {
            const int r = q * 64 + wid * 16;
            const size_t gb = ((size_t)(r + rsub) * Lc + k0) * 2 + cbyt;
            gll16((const char*)VTf_z + gb, (char*)(Bf_s + pp * BBUF) + (size_t)r * 64);
        }
    };

    stageB(0, 0);  // get loads in flight before stats math

    // folded rstat: 8 lanes/row, 2 partials each + 3-step butterfly
    const int ar = t >> 3, cq = (t & 7) * 4;
    float m_ = -1e30f, s_ = 0.f;
    {
        const int q = t & 7;
        const float* pb = pstats + (((size_t)z * 16 + q * 2) * Lc + row0 + ar) * 2;
        #pragma unroll
        for (int j = 0; j < 2; ++j) {
            const float2 pp = *(const float2*)(pb + (size_t)j * Lc * 2);
            const float nm = fmaxf(m_, pp.x);
            s_ = s_ * __expf(m_ - nm) + pp.y * __expf(pp.x - nm);
            m_ = nm;
        }
        #pragma unroll
        for (int ofs = 1; ofs < 8; ofs <<= 1) {
            const float om = __shfl_xor(m_, ofs, 64);
            const float os = __shfl_xor(s_, ofs, 64);
            const float nm = fmaxf(m_, om);
            s_ = s_ * __expf(m_ - nm) + os * __expf(om - nm);
            m_ = nm;
        }
    }
    const float iv_ = 1.0f / s_;

    auto stageA = [&](int k0, int pp) {
        float* srcS = sc + (size_t)ar * Lc + k0 + cq;
        const float4 v0 = *(const float4*)srcS;
        float pr[4];
        pr[0] = __expf(v0.x - m_) * iv_; pr[1] = __expf(v0.y - m_) * iv_;
        pr[2] = __expf(v0.z - m_) * iv_; pr[3] = __expf(v0.w - m_) * iv_;
        *(float4*)srcS = make_float4(pr[0], pr[1], pr[2], pr[3]);
        unsigned hu[2], lu[2];
        sp2(pr[0], pr[1], hu[0], lu[0]); sp2(pr[2], pr[3], hu[1], lu[1]);
        *(uint2*)(Ah_s + pp * ABUF + ar * 32 + cq) = make_uint2(hu[0], hu[1]);
        *(uint2*)(Al_s + pp * ABUF + ar * 32 + cq) = make_uint2(lu[0], lu[1]);
    };

    f32x4 acc[2][4] = {};
    stageA(0, 0);
    __syncthreads();
    int p = 0;
    for (int kt = 0; kt < 32; ++kt) {
        if (kt < 31) { stageB((kt + 1) * 32, p ^ 1); stageA((kt + 1) * 32, p ^ 1); }
        f16x8 ah[2], al[2];
        #pragma unroll
        for (int mf = 0; mf < 2; ++mf) {
            const int off = p * ABUF + (mf * 16 + fr) * 32 + fk;
            ah[mf] = *(const f16x8*)(Ah_s + off);
            al[mf] = *(const f16x8*)(Al_s + off);
        }
        #pragma unroll
        for (int nf = 0; nf < 4; ++nf) {
            const int off = p * BBUF + (wid * 64 + nf * 16 + fr) * 32 + fk;
            const f16x8 bf = *(const f16x8*)(Bf_s + off);
            #pragma unroll
            for (int mf = 0; mf < 2; ++mf) {
                acc[mf][nf] = __builtin_amdgcn_mfma_f32_16x16x32_f16(ah[mf], bf, acc[mf][nf], 0, 0, 0);
                acc[mf][nf] = __builtin_amdgcn_mfma_f32_16x16x32_f16(al[mf], bf, acc[mf][nf], 0, 0, 0);
            }
        }
        __syncthreads();
        p ^= 1;
    }

    // t_out write + stash tile to LDS for the fused output projection
    constexpr int TS = 258;  // f32 row stride (bank-spread)
    float* ts = (float*)SMp;
    #pragma unroll
    for (int mf = 0; mf < 2; ++mf) {
        #pragma unroll
        for (int i = 0; i < 4; ++i) {
            const size_t row = (size_t)row0 + mf * 16 + g * 4 + i;
            float* cp = tout + ((size_t)z * Lc + row) * HDc + wid * 64 + fr;
            #pragma unroll
            for (int nf = 0; nf < 4; ++nf) {
                cp[nf * 16] = acc[mf][nf][i];
                ts[(mf * 16 + g * 4 + i) * TS + wid * 64 + nf * 16 + fr] = acc[mf][nf][i];
            }
        }
    }
    __syncthreads();

    // out = t_out_tile @ WfcT^T + bfc  (K=256; each wave -> 16 out cols)
    const int ocol = wid * 16 + fr;
    f32x4 acc2[2] = {};
    #pragma unroll
    for (int kt2 = 0; kt2 < 8; ++kt2) {
        const int kk = kt2 * 32 + fk;
        const f16x8 bf = *(const f16x8*)(WfcTf + ocol * 256 + kk);
        #pragma unroll
        for (int mf = 0; mf < 2; ++mf) {
            const float* ap = ts + (mf * 16 + fr) * TS + kk;
            union { unsigned u[4]; f16x8 v; } ahh, all_;
            sp2(ap[0], ap[1], ahh.u[0], all_.u[0]);
            sp2(ap[2], ap[3], ahh.u[1], all_.u[1]);
            sp2(ap[4], ap[5], ahh.u[2], all_.u[2]);
            sp2(ap[6], ap[7], ahh.u[3], all_.u[3]);
            acc2[mf] = __builtin_amdgcn_mfma_f32_16x16x32_f16(ahh.v, bf, acc2[mf], 0, 0, 0);
            acc2[mf] = __builtin_amdgcn_mfma_f32_16x16x32_f16(all_.v, bf, acc2[mf], 0, 0, 0);
        }
    }
    const float bo = bfc[ocol];
    #pragma unroll
    for (int mf = 0; mf < 2; ++mf)
        #pragma unroll
        for (int i = 0; i < 4; ++i)
            outp[((size_t)z * Lc + row0 + mf * 16 + g * 4 + i) * Dc + ocol] = acc2[mf][i] + bo;
}

// 32x32 transpose + single-f16 convert helper
__device__ __forceinline__ void tr32(const float* src, unsigned short* dh,
                                     int R, int C, int r0, int c0,
                                     float (*tile)[33], int t)
{
    const int tc = t & 31, tr = t >> 5;
    #pragma unroll
    for (int rr = 0; rr < 32; rr += 8)
        tile[tr + rr][tc] = src[(size_t)(r0 + tr + rr) * C + c0 + tc];
    __syncthreads();
    #pragma unroll
    for (int rr = 0; rr < 32; rr += 8) {
        const size_t o = (size_t)(c0 + tr + rr) * R + r0 + tc;
        dh[o] = cv1(tile[tc][tr + rr]);
    }
}

// all weight transposes (single f16) + bias concat in one launch
__global__ __launch_bounds__(256) void prep_k(
    const float* __restrict__ W, const float* __restrict__ Wq,
    const float* __restrict__ Wk, const float* __restrict__ Wv,
    const float* __restrict__ Wfc, const float* __restrict__ bq,
    const float* __restrict__ bk, const float* __restrict__ bv,
    unsigned short* __restrict__ WTf, unsigned short* __restrict__ Wcf,
    unsigned short* __restrict__ WfcTf, float* __restrict__ bcat)
{
    __shared__ float tile[32][33];
    const int bx = blockIdx.x, by = blockIdx.y, t = threadIdx.x;
    if (by == 0) {
        if (bx >= 32) return;
        const int h = bx >> 3, tl = bx & 7;
        tr32(W + (size_t)h * Fc * Dc, WTf + (size_t)h * Dc * Fc,
             Fc, Dc, (tl >> 1) * 32, (tl & 1) * 32, tile, t);
    } else if (by <= 3) {
        const float* s = (by == 1) ? Wq : (by == 2) ? Wk : Wv;
        const size_t off = (size_t)(by - 1) * HDc * HDc;
        tr32(s, Wcf + off, HDc, HDc, (bx >> 3) * 32, (bx & 7) * 32, tile, t);
    } else {
        if (bx < 16) {
            tr32(Wfc, WfcTf, HDc, Dc, (bx >> 1) * 32, (bx & 1) * 32, tile, t);
        } else if (bx == 16) {
            bcat[t] = bq[t]; bcat[256 + t] = bk[t]; bcat[512 + t] = bv[t];
        }
    }
}

extern "C" void kernel_launch(void* const* d_in, const int* in_sizes, int n_in,
                              void* d_out, int out_size, void* d_ws, size_t ws_size,
                              hipStream_t stream)
{
    const float* x   = (const float*)d_in[0];
    const float* W   = (const float*)d_in[1];
    const float* a1  = (const float*)d_in[2];
    const float* a2  = (const float*)d_in[3];
    const float* Wq  = (const float*)d_in[4];
    const float* bq  = (const float*)d_in[5];
    const float* Wk  = (const float*)d_in[6];
    const float* bk  = (const float*)d_in[7];
    const float* Wv  = (const float*)d_in[8];
    const float* bv  = (const float*)d_in[9];
    const float* Wfc = (const float*)d_in[10];
    const float* bfc = (const float*)d_in[11];

    float* outp    = (float*)d_out;
    float* gat_att = outp + (size_t)Bc * Lc * Dc;
    float* t_att   = gat_att + (size_t)Hc * Bc * Lc * Lc;
    float* t_out   = t_att + (size_t)Bc * Lc * Lc;

    constexpr size_t MB = 1024 * 1024;
    char* wsb = (char*)d_ws;
    // region 0 (0-8MB): WhT f16 -> VT f16 (WhT dead after gat_k)
    unsigned short* WhTf = (unsigned short*)wsb;
    unsigned short* VTf  = WhTf;
    // region 1 (8-24MB): gout f16 pair (A of QKV)
    unsigned short* gouth = (unsigned short*)(wsb + 8 * MB);
    unsigned short* goutl = gouth + (size_t)Nrows * HDc;
    // region 2 (24-40MB): Q f16 pair (A of QK)
    unsigned short* Qh = (unsigned short*)(wsb + 24 * MB);
    unsigned short* Ql = Qh + (size_t)Nrows * HDc;
    // region 3 (40-48MB): K single f16 (B of QK)
    unsigned short* Kf = (unsigned short*)(wsb + 40 * MB);
    // region 4 (48MB+): small buffers
    float* si  = (float*)(wsb + 48 * MB);
    float* sj  = si + Hc * Nrows;
    float* pstats = sj + Hc * Nrows;                  // [16][16][1024][2]
    unsigned short* WTf = (unsigned short*)(pstats + (size_t)Bc * 16 * Lc * 2);  // [4][64][128]
    unsigned short* Wcf = WTf + Hc * Dc * Fc;         // [768][256]
    unsigned short* WfcTf = Wcf + 768 * HDc;          // [64][256]
    float* bcat = (float*)(WfcTf + Dc * HDc);         // [768]

    const dim3 blk(256);

    // 0. weight prep (one launch)
    prep_k<<<dim3(64, 5), blk, 0, stream>>>(W, Wq, Wk, Wv, Wfc, bq, bk, bv,
        WTf, Wcf, WfcTf, bcat);

    // 1. WhT f16 = (x @ W[h]^T)^T + fused si/sj
    mm_k<128, 64, A_F32, E_WHT><<<dim3(Nrows / 128, 1, Hc), blk, 0, stream>>>(
        x, nullptr, nullptr, WTf, nullptr, nullptr,
        WhTf, nullptr, nullptr, nullptr,
        Fc, Fc, Fc, 0, 0LL, (long long)Dc * Fc, 0LL, 1.f, a1, a2, si, sj, nullptr);

    // 2. fused GAT (stats in-block): gat_att + gout f16 pair
    gat_k<<<dim3(Lc / 128, 1, 64), blk, 0, stream>>>(si, sj,
        WhTf, gat_att, gouth, goutl);

    // 3. fused QKV projection (col-block on x for XCD A-panel sharing)
    mm_k<128, 128, A_HL, E_QKV><<<dim3(6, Nrows / 128, 1), blk, 0, stream>>>(
        nullptr, gouth, goutl, Wcf, bcat, nullptr,
        Qh, Ql, Kf, VTf,
        HDc, HDc, HDc, HDc, 0LL, 0LL, 0LL, 1.f, nullptr, nullptr, nullptr, nullptr, nullptr);

    // 4. raw scaled scores -> t_att region + partial row stats
    mm_k<128, 128, A_HL, E_STATS><<<dim3(8, 8, Bc), blk, 0, stream>>>(
        nullptr, Qh, Ql, Kf, nullptr, t_att,
        nullptr, nullptr, nullptr, nullptr,
        HDc, HDc, HDc, Lc, (long long)Lc * HDc, (long long)Lc * HDc,
        (long long)Lc * Lc, 0.0625f, nullptr, nullptr, nullptr, nullptr, pstats);

    // 5. PV: folded rstat + fused softmax + t_out + fused out-projection
    pv_k<<<dim3(32, 1, Bc), blk, 0, stream>>>(t_att, pstats, VTf,
        WfcTf, bfc, t_out, outp);
}